// Round 6
// baseline (947.706 us; speedup 1.0000x reference)
//
#include <hip/hip_runtime.h>
#include <hip/hip_fp16.h>
#include <math.h>

#define DEV __device__ __forceinline__

DEV float fexp(float x){ return __expf(x); }
DEV float elu_(float x){ return x > 0.f ? x : fexp(x) - 1.f; }
DEV float sigm_(float x){ return 1.f/(1.f + fexp(-x)); }
DEV float tanh_(float x){ float e = fexp(2.f*x); return 1.f - 2.f/(e + 1.f); }
DEV unsigned bf16r(float x){ unsigned u = __float_as_uint(x);
  return (u + 0x7fffu + ((u>>16)&1u)) >> 16; }
DEV float blo(unsigned u){ return __uint_as_float(u << 16); }
DEV float bhi(unsigned u){ return __uint_as_float(u & 0xffff0000u); }
DEV float bl(unsigned short u){ return __uint_as_float(((unsigned)u) << 16); }

using frag  = __attribute__((ext_vector_type(8))) short;     // 8 bf16 (4 VGPRs)
using fragh = __attribute__((ext_vector_type(8))) _Float16;  // 8 f16  (4 VGPRs)
using f32x4 = __attribute__((ext_vector_type(4))) float;     // MFMA acc

// coherent (sc0 sc1 = device-coherent path) 16B load WITH completion wait
DEV uint4 cload16w(const void* p){
  uint4 r;
  asm volatile("global_load_dwordx4 %0, %1, off sc0 sc1\n\ts_waitcnt vmcnt(0)"
               : "=v"(r) : "v"(p) : "memory");
  return r;
}
// coherent 16B load, NO wait (caller does one s_waitcnt vmcnt(0) for the batch)
DEV uint4 cload16nw(const void* p){
  uint4 r;
  asm volatile("global_load_dwordx4 %0, %1, off sc0 sc1"
               : "=v"(r) : "v"(p) : "memory");
  return r;
}

// ---------------------------------------------------------------------------
// device pack helpers
// ---------------------------------------------------------------------------
DEV void d_packB(const float* __restrict__ W, short* __restrict__ Bp,
                 int KC, int Ng, int Ksrc, int N, int trans, int idx)
{
  if (idx >= KC*Ng*64) return;
  int lane = idx & 63;
  int g    = (idx >> 6) % Ng;
  int kc   = idx / (64*Ng);
  int n = g*16 + (lane & 15);
  int kb = kc*32 + ((lane >> 4) << 3);
  unsigned o[4];
#pragma unroll
  for (int jj = 0; jj < 4; ++jj) {
    int k0 = kb + 2*jj;
    float v0 = (k0   < Ksrc) ? (trans ? W[(size_t)n*Ksrc + k0]   : W[(size_t)(k0)*N + n])   : 0.f;
    float v1 = (k0+1 < Ksrc) ? (trans ? W[(size_t)n*Ksrc + k0+1] : W[(size_t)(k0+1)*N + n]) : 0.f;
    o[jj] = bf16r(v0) | (bf16r(v1) << 16);
  }
  *(uint4*)(Bp + (size_t)idx*8) = make_uint4(o[0], o[1], o[2], o[3]);
}

DEV void d_packImg(const float* __restrict__ image, short* __restrict__ Ap, int idx)
{
  int lane = idx & 63;
  int kc   = (idx >> 6) % 20;
  int mt   = idx / 1280;
  int row = mt*16 + (lane & 15);
  int b = row / 150, p = row % 150;
  int cb = kc*32 + ((lane >> 4) << 3);
  unsigned o[4];
#pragma unroll
  for (int jj = 0; jj < 4; ++jj) {
    float v0 = image[((size_t)b*640 + cb + 2*jj    )*150 + p];
    float v1 = image[((size_t)b*640 + cb + 2*jj + 1)*150 + p];
    o[jj] = bf16r(v0) | (bf16r(v1) << 16);
  }
  *(uint4*)(Ap + (size_t)idx*8) = make_uint4(o[0], o[1], o[2], o[3]);
}

DEV void d_packEmb(const float* __restrict__ embedW, const int* __restrict__ ques,
                   short* __restrict__ Ap, int idx)
{
  int lane = idx & 63;
  int kc   = (idx >> 6) % 10;
  int mt   = idx / 640;
  int row = mt*16 + (lane & 15);
  int q = ques[row];
  int kb = kc*32 + ((lane >> 4) << 3);
  unsigned o[4];
#pragma unroll
  for (int jj = 0; jj < 4; ++jj) {
    int k0 = kb + 2*jj;
    float v0 = (k0   < 300) ? embedW[(size_t)q*300 + k0]   : 0.f;
    float v1 = (k0+1 < 300) ? embedW[(size_t)q*300 + k0+1] : 0.f;
    o[jj] = bf16r(v0) | (bf16r(v1) << 16);
  }
  *(uint4*)(Ap + (size_t)idx*8) = make_uint4(o[0], o[1], o[2], o[3]);
}

// ---------------------------------------------------------------------------
// ONE dispatch for all independent pre-stage work
// [0,320) init  [320,1344) WhT f16 pack  [1344,1504) ic1w  [1504,1632) ic2w
// [1632,1760) i2mw  [1760,1920) Wi_f  [1920,2080) Wi_b  [2080,5080) img
// [5080,5380) emb  [5380,5892) t2m  [5892,7940) W2 bf16  [7940,12036) ansW bf16
// ---------------------------------------------------------------------------
__global__ __launch_bounds__(256)
void megapack_k(const float* __restrict__ c0, const float* __restrict__ c3ow,
                const float* __restrict__ c4ow, const float* __restrict__ aow,
                float* __restrict__ stack, float* __restrict__ pvecA,
                float* __restrict__ mem, float* __restrict__ cprev,
                float* __restrict__ swb, float* __restrict__ pl,
                const float* __restrict__ Whf, const float* __restrict__ Whb,
                unsigned* __restrict__ whT,
                float* __restrict__ hbufz, int* __restrict__ flagz,
                const float* __restrict__ ic1w, short* __restrict__ w1p,
                const float* __restrict__ ic2w, short* __restrict__ w2mp,
                const float* __restrict__ i2mw, short* __restrict__ w3mp,
                const float* __restrict__ Wif, short* __restrict__ wifp,
                const float* __restrict__ Wib, short* __restrict__ wibp,
                const float* __restrict__ image, short* __restrict__ imgP,
                const float* __restrict__ embedW, const int* __restrict__ ques,
                short* __restrict__ embp,
                const float* __restrict__ t2mw, unsigned* __restrict__ t2pp,
                const float* __restrict__ W2w, unsigned short* __restrict__ w2bp,
                const float* __restrict__ ansW, unsigned short* __restrict__ answp)
{
  const int bx = blockIdx.x, tid = threadIdx.x;
  if (bx < 320) {
    int idx = bx*256 + tid;
    int stride = 320*256;
    for (int i = idx; i < 64*150*8; i += stride) stack[i] = 0.f;
    for (int i = idx; i < 64*8;    i += stride) pvecA[i] = ((i & 7) == 0) ? 1.f : 0.f;
    for (int i = idx; i < 64*512;  i += stride) mem[i] = 0.f;
    for (int i = idx; i < 64*512;  i += stride) cprev[i] = c0[i & 511];
    for (int i = idx; i < 9*2*64*512; i += stride) pl[i] = 0.f;
    for (int i = idx; i < 32768;   i += stride) hbufz[i] = 0.f;  // hbuf (f16 pairs)
    if (idx < 256) flagz[idx] = 0;                               // sync flags
    if (idx < 8) {
      const float* ow = (idx < 4) ? (c3ow + idx*6)
                      : (idx < 6) ? (c4ow + (idx-4)*6)
                                  : (aow  + (idx-6)*6);
      float mx = ow[0];
      for (int m = 1; m < 6; ++m) mx = fmaxf(mx, ow[m]);
      float e[6]; float s = 0.f;
      for (int m = 0; m < 6; ++m) { e[m] = fexp(ow[m]-mx); s += e[m]; }
      for (int m = 0; m < 6; ++m) swb[idx*6+m] = e[m]/s;
    }
  } else if (bx < 1344) {
    // WhT: [d][zc 0..1023][k-pair 0..127] packed f16 pairs (transposed Wh)
    int idx = (bx-320)*256 + tid;
    int dd  = idx >> 17;
    int rem = idx & 131071;
    int kp  = rem >> 10;
    int zc  = rem & 1023;
    const float* Wh = dd ? Whb : Whf;
    __half2 hv = __floats2half2_rn(Wh[(size_t)(2*kp)*1024 + zc],
                                   Wh[(size_t)(2*kp+1)*1024 + zc]);
    whT[((size_t)dd << 17) + (zc << 7) + kp] = *(unsigned*)&hv;
  } else if (bx < 1504) {
    d_packB(ic1w, w1p, 20, 32, 640, 512, 1, (bx-1344)*256 + tid);
  } else if (bx < 1632) {
    d_packB(ic2w, w2mp, 16, 32, 512, 512, 1, (bx-1504)*256 + tid);
  } else if (bx < 1760) {
    d_packB(i2mw, w3mp, 16, 32, 512, 512, 1, (bx-1632)*256 + tid);
  } else if (bx < 1920) {
    d_packB(Wif, wifp, 10, 64, 300, 1024, 0, (bx-1760)*256 + tid);
  } else if (bx < 2080) {
    d_packB(Wib, wibp, 10, 64, 300, 1024, 0, (bx-1920)*256 + tid);
  } else if (bx < 5080) {
    d_packImg(image, imgP, (bx-2080)*256 + tid);
  } else if (bx < 5380) {
    d_packEmb(embedW, ques, embp, (bx-5080)*256 + tid);
  } else if (bx < 5892) {
    int idx = (bx-5380)*256 + tid;   // 512*256
    int k = idx >> 8, c = idx & 255;
    t2pp[idx] = bf16r(t2mw[(size_t)k*512 + c]) | (bf16r(t2mw[(size_t)k*512 + 256 + c]) << 16);
  } else if (bx < 7940) {
    int i = (bx-5892)*256 + tid;     // 524288
    w2bp[i] = (unsigned short)bf16r(W2w[i]);
  } else {
    int i = (bx-7940)*256 + tid;     // 1048576
    answp[i] = (unsigned short)bf16r(ansW[i]);
  }
}

// ---------------------------------------------------------------------------
// MFMA GEMM, dual problem sets via blockIdx.z.
// mode 0: fp32 row-major; mode 1: bf16 A-pack; mode 2: bf16 row-major
// ---------------------------------------------------------------------------
__global__ __launch_bounds__(256)
void gemmM_k(const short* __restrict__ ApA, const short* __restrict__ ApB,
             const short* __restrict__ BpA, const short* __restrict__ BpB,
             const float* __restrict__ biasA, const float* __restrict__ biasB,
             void* __restrict__ CoutA, void* __restrict__ CoutB,
             int KC, int Ng, int N, int mode, int act, int KCout)
{
  __shared__ float lds[4][16][68];
  const int z = blockIdx.z;
  const short* Ap = z ? ApB : ApA;
  const short* Bp = z ? BpB : BpA;
  const float* bias = z ? biasB : biasA;
  void* Cout = z ? CoutB : CoutA;
  const int tid = threadIdx.x, lane = tid & 63, w = tid >> 6;
  const int mt = blockIdx.y*4 + w;
  const int ncol0 = blockIdx.x*64;
  const short* Abase = Ap + (((size_t)mt*KC) << 9) + lane*8;
  const short* Bbase = Bp + (((size_t)blockIdx.x*4) << 9) + lane*8;
  f32x4 acc0 = {0.f,0.f,0.f,0.f}, acc1 = acc0, acc2 = acc0, acc3 = acc0;
#pragma unroll 2
  for (int kc = 0; kc < KC; ++kc) {
    frag a = *(const frag*)(Abase + ((size_t)kc << 9));
    const short* bk = Bbase + (((size_t)kc*Ng) << 9);
    frag b0 = *(const frag*)(bk);
    frag b1 = *(const frag*)(bk + 512);
    frag b2 = *(const frag*)(bk + 1024);
    frag b3 = *(const frag*)(bk + 1536);
    acc0 = __builtin_amdgcn_mfma_f32_16x16x32_bf16(a, b0, acc0, 0, 0, 0);
    acc1 = __builtin_amdgcn_mfma_f32_16x16x32_bf16(a, b1, acc1, 0, 0, 0);
    acc2 = __builtin_amdgcn_mfma_f32_16x16x32_bf16(a, b2, acc2, 0, 0, 0);
    acc3 = __builtin_amdgcn_mfma_f32_16x16x32_bf16(a, b3, acc3, 0, 0, 0);
  }
  {
    int colb = lane & 15, rowb = (lane >> 4)*4;
#pragma unroll
    for (int r = 0; r < 4; ++r) {
      lds[w][rowb+r][ 0+colb] = acc0[r];
      lds[w][rowb+r][16+colb] = acc1[r];
      lds[w][rowb+r][32+colb] = acc2[r];
      lds[w][rowb+r][48+colb] = acc3[r];
    }
  }
  __syncthreads();
  if (mode == 0) {
    float* C = (float*)Cout;
    int mloc = lane >> 2, q4 = lane & 3;
    size_t rowoff = (size_t)(mt*16 + mloc)*N + ncol0 + q4*16;
#pragma unroll
    for (int i = 0; i < 4; ++i) {
      float4 v = *(float4*)&lds[w][mloc][q4*16 + i*4];
      const float* bp = bias + ncol0 + q4*16 + i*4;
      v.x += bp[0]; v.y += bp[1]; v.z += bp[2]; v.w += bp[3];
      if (act) { v.x = elu_(v.x); v.y = elu_(v.y); v.z = elu_(v.z); v.w = elu_(v.w); }
      *(float4*)&C[rowoff + i*4] = v;
    }
  } else if (mode == 1) {
    short* C = (short*)Cout;
    int m = lane & 15, qb = (lane >> 4)*8;
#pragma unroll
    for (int h = 0; h < 2; ++h) {
      int nl = h*32 + qb;
      unsigned o[4];
#pragma unroll
      for (int jj = 0; jj < 4; ++jj) {
        float v0 = lds[w][m][nl + 2*jj]     + bias[ncol0 + nl + 2*jj];
        float v1 = lds[w][m][nl + 2*jj + 1] + bias[ncol0 + nl + 2*jj + 1];
        if (act) { v0 = elu_(v0); v1 = elu_(v1); }
        o[jj] = bf16r(v0) | (bf16r(v1) << 16);
      }
      *(uint4*)(C + (((size_t)mt*KCout + (ncol0 >> 5) + h) << 9) + lane*8)
          = make_uint4(o[0], o[1], o[2], o[3]);
    }
  } else {
    unsigned short* C = (unsigned short*)Cout;
    int row = lane >> 2, cb = (lane & 3)*16;
#pragma unroll
    for (int h = 0; h < 2; ++h) {
      unsigned o[4];
#pragma unroll
      for (int jj = 0; jj < 4; ++jj) {
        float v0 = lds[w][row][cb + h*8 + 2*jj]     + bias[ncol0 + cb + h*8 + 2*jj];
        float v1 = lds[w][row][cb + h*8 + 2*jj + 1] + bias[ncol0 + cb + h*8 + 2*jj + 1];
        if (act) { v0 = elu_(v0); v1 = elu_(v1); }
        o[jj] = bf16r(v0) | (bf16r(v1) << 16);
      }
      *(uint4*)&C[(size_t)(mt*16 + row)*N + ncol0 + cb + h*8]
          = make_uint4(o[0], o[1], o[2], o[3]);
    }
  }
}

// ---------------------------------------------------------------------------
// 64-row batch GEMM, K-split across waves
// ---------------------------------------------------------------------------
__global__ __launch_bounds__(512)
void gemm64b_k(const float* __restrict__ A1, long zA1, int K1log,
               const float* __restrict__ A2, int K2,
               const float* __restrict__ B, long zB,
               const float* __restrict__ bias, int zbias,
               float* __restrict__ C, long zC, int N, int act)
{
  const int K1 = 1 << K1log;
  const int Kt = K1 + K2;
  __shared__ __align__(16) float As[8][1024];
  __shared__ float part[8][8][64];
  const int tid = threadIdx.x;
  const int z = blockIdx.z;
  const int r0 = blockIdx.y*8;
  {
    const float* a1 = A1 + (size_t)z*zA1;
    const int nf4 = (8*K1) >> 2;
    for (int e4 = tid; e4 < nf4; e4 += 512) {
      int r = e4 >> (K1log-2);
      int k4 = (e4 & ((K1>>2)-1)) << 2;
      *(float4*)&As[r][k4] = *(const float4*)&a1[(size_t)(r0+r)*K1 + k4];
    }
    if (K2 > 0) {
      for (int e4 = tid; e4 < 1024; e4 += 512) {
        int r = e4 >> 7;
        int k4 = (e4 & 127) << 2;
        *(float4*)&As[r][K1+k4] = *(const float4*)&A2[(size_t)(r0+r)*512 + k4];
      }
    }
  }
  __syncthreads();
  const int lane = tid & 63, w = tid >> 6;
  const int n = blockIdx.x*64 + lane;
  const bool nv = n < N;
  const int kseg = Kt >> 3;
  const int k0 = w*kseg;
  const float* Bp = B + (size_t)z*zB + (size_t)k0*N + (nv ? n : 0);
  float acc[8] = {0,0,0,0,0,0,0,0};
#pragma unroll 8
  for (int kk = 0; kk < kseg; ++kk) {
    float bv = nv ? Bp[(size_t)kk*N] : 0.f;
    int k = k0 + kk;
#pragma unroll
    for (int r = 0; r < 8; ++r) acc[r] += As[r][k]*bv;
  }
#pragma unroll
  for (int r = 0; r < 8; ++r) part[w][r][lane] = acc[r];
  __syncthreads();
  {
    int r = tid >> 6, c = tid & 63;
    int nn = blockIdx.x*64 + c;
    if (nn < N) {
      float s = 0.f;
#pragma unroll
      for (int w2 = 0; w2 < 8; ++w2) s += part[w2][r][c];
      s += bias ? bias[(size_t)z*zbias + nn] : 0.f;
      if (act == 1) s = elu_(s);
      C[(size_t)z*zC + (size_t)(r0+r)*N + nn] = s;
    }
  }
}

// ---------------------------------------------------------------------------
// MFMA bidirectional masked LSTM (round-4 protocol: LDS-resident weights,
// per-step flag sync over coherent atomics + pipelined sc0sc1 h loads).
// ---------------------------------------------------------------------------
__global__ __launch_bounds__(256)
void lstmM_k(const float* __restrict__ xWf, const float* __restrict__ xWb,
             const unsigned* __restrict__ whT, const int* __restrict__ qlen,
             unsigned long long* __restrict__ hbuf, int* __restrict__ flags,
             float* __restrict__ lstm_out, float* __restrict__ qout)
{
  const int bx = blockIdx.x;
  const int d = bx & 1, g = (bx >> 1) & 3, n = bx >> 3;
  const int tid = threadIdx.x, lane = tid & 63, w = tid >> 6;
  const int q = lane >> 4, cl = lane & 15;
  __shared__ __align__(16) unsigned short Wl[65536];   // 128 KiB

#pragma unroll 4
  for (int rb = 0; rb < 32; ++rb) {
    int lcrow = rb*8 + (tid >> 5);
    int gt = lcrow >> 6, c = lcrow & 63;
    int zc = gt*256 + n*64 + c;
    uint4 v = *(const uint4*)(whT + (((size_t)d*1024 + zc) << 7) + ((tid & 31) << 2));
    int byteoff = (lcrow << 9) + ((((tid & 31) << 4)) ^ ((lcrow & 7) << 4));
    *(uint4*)((char*)Wl + byteoff) = v;
  }

  const float* xW = d ? xWb : xWf;
  const int b   = g*16 + cl;                 // this lane's batch
  const int c4  = w*16 + q*4;                // local col base within slice
  const int hc4 = n*64 + c4;                 // global h-col base (4 consecutive)
  const int len = qlen[b];
  float cst[4] = {0.f,0.f,0.f,0.f}, hst[4] = {0.f,0.f,0.f,0.f};
  int* flg = flags + ((d*4 + g) << 2);       // 4 flags for this (d,g) group
  const int bofs = (cl & 7) << 4;
  __syncthreads();

  for (int ss = 0; ss < 30; ++ss) {
    const int s = d ? (29 - ss) : ss;
    const float* xr = xW + (size_t)b*30720 + (size_t)s*1024 + hc4;
    f32x4 xwv[4];
#pragma unroll
    for (int gt = 0; gt < 4; ++gt) xwv[gt] = *(const f32x4*)(xr + gt*256);

    if (ss > 0) {
      for (;;) {
        uint4 f4 = cload16w(flg);   // all 4 flags in ONE coherent 16B load
        if ((int)f4.x >= ss && (int)f4.y >= ss &&
            (int)f4.z >= ss && (int)f4.w >= ss) break;
      }
      __builtin_amdgcn_sched_barrier(0);
    }
    // B = h^T from hbuf: 8 pipelined coherent 16B loads, ONE vmcnt wait
    const char* hbr = (const char*)(hbuf + ((size_t)(((ss & 1)*2 + d)*4 + g) << 9))
                    + (cl << 9) + (q << 4);
    union { uint4 u; fragh f; } hv[8];
#pragma unroll
    for (int ks = 0; ks < 8; ++ks) hv[ks].u = cload16nw(hbr + (ks << 6));
    asm volatile("s_waitcnt vmcnt(0)" ::: "memory");
    __builtin_amdgcn_sched_barrier(0);

    f32x4 acc0 = {0.f,0.f,0.f,0.f}, acc1 = acc0, acc2 = acc0, acc3 = acc0;
#pragma unroll
    for (int ks = 0; ks < 8; ++ks) {
      const int kb = ((ks << 6) + (q << 4)) ^ bofs;
      const char* wb = (const char*)Wl + ((w*16 + cl) << 9) + kb;
      fragh a0 = *(const fragh*)(wb);
      fragh a1 = *(const fragh*)(wb + (64 << 9));
      fragh a2 = *(const fragh*)(wb + (128 << 9));
      fragh a3 = *(const fragh*)(wb + (192 << 9));
      acc0 = __builtin_amdgcn_mfma_f32_16x16x32_f16(a0, hv[ks].f, acc0, 0, 0, 0);
      acc1 = __builtin_amdgcn_mfma_f32_16x16x32_f16(a1, hv[ks].f, acc1, 0, 0, 0);
      acc2 = __builtin_amdgcn_mfma_f32_16x16x32_f16(a2, hv[ks].f, acc2, 0, 0, 0);
      acc3 = __builtin_amdgcn_mfma_f32_16x16x32_f16(a3, hv[ks].f, acc3, 0, 0, 0);
    }
    const bool m = s < len;
    f32x4 lo4;
    float hvv[4];
#pragma unroll
    for (int r = 0; r < 4; ++r) {
      float iv = acc0[r] + xwv[0][r];
      float fv = acc1[r] + xwv[1][r];
      float gv = acc2[r] + xwv[2][r];
      float o_ = acc3[r] + xwv[3][r];
      float cn = sigm_(fv)*cst[r] + sigm_(iv)*tanh_(gv);
      float hn = sigm_(o_)*tanh_(cn);
      float hk = m ? hn : hst[r];
      cst[r] = m ? cn : cst[r];
      hst[r] = hk;
      hvv[r] = hk;
      lo4[r] = m ? hn : 0.f;
    }
    unsigned long long* hbw = hbuf + ((size_t)((((ss & 1) ^ 1)*2 + d)*4 + g) << 9);
    union { unsigned long long u; __half2 h2[2]; } hp;
    hp.h2[0] = __floats2half2_rn(hvv[0], hvv[1]);
    hp.h2[1] = __floats2half2_rn(hvv[2], hvv[3]);
    __hip_atomic_store(hbw + cl*64 + (hc4 >> 2), hp.u,
                       __ATOMIC_RELAXED, __HIP_MEMORY_SCOPE_AGENT);
    *(f32x4*)(lstm_out + (((size_t)b*30 + s) << 9) + (d << 8) + hc4) = lo4;
    asm volatile("s_waitcnt vmcnt(0)" ::: "memory");
    __syncthreads();
    if (tid == 0)
      __hip_atomic_store(&flg[n], ss + 1, __ATOMIC_RELAXED, __HIP_MEMORY_SCOPE_AGENT);
  }
  *(f32x4*)(qout + ((size_t)b << 9) + (d << 8) + hc4) =
      f32x4{hst[0], hst[1], hst[2], hst[3]};
}

// ---------------------------------------------------------------------------
// fused u-GEMV + kc + attn + tmap — 1024 threads.
// u = [tmp1(t) | cprev] @ W2 (bf16 B) computed in-block (replaces ansu3 z=2).
// ---------------------------------------------------------------------------
__global__ __launch_bounds__(1024)
void kcattn3_k(const float* __restrict__ tmp1, const float* __restrict__ cprevB,
               const unsigned short* __restrict__ w2bp, const float* __restrict__ W2b,
               const float* __restrict__ Wmod,
               const float* __restrict__ lstm_out, const float* __restrict__ W3,
               const unsigned* __restrict__ t2pp, const float* __restrict__ t2mb,
               float* __restrict__ woutAll, float* __restrict__ imp_part,
               float* __restrict__ cout, float* __restrict__ tmapv, int t)
{
  int b = blockIdx.x;
  int tid = threadIdx.x;
  int lane = tid & 63, wave = tid >> 6;   // 16 waves
  __shared__ float A2s[1024];
  __shared__ float ush[512];
  __shared__ float upart[512];
  __shared__ float sC[512];
  __shared__ float cpart[512];
  __shared__ float tpart[4][512];
  __shared__ float wl[9];
  __shared__ float sc[32], at[32];
  // load A = [tmp1 | cprev]
  if (tid < 512) A2s[tid] = tmp1[b*512 + tid];
  else           A2s[tid] = cprevB[b*512 + (tid - 512)];
  __syncthreads();
  // u GEMV: col = tid&511, k-half = tid>>9 (bf16 W2, 2-way k-split)
  {
    int col = tid & 511, kh = tid >> 9;
    const unsigned short* wp = w2bp + ((size_t)kh*512)*512 + col;
    const float* av = A2s + kh*512;
    float acc = 0.f;
#pragma unroll 8
    for (int k = 0; k < 512; ++k) acc += av[k]*bl(wp[(size_t)k*512]);
    if (kh) upart[col] = acc;
    __syncthreads();
    if (!kh) ush[col] = acc + upart[col] + W2b[col];
  }
  __syncthreads();
  // attention scores (16 waves cover s = wave, wave+16)
  for (int s = wave; s < 30; s += 16) {
    float acc = 0.f;
    const float* lo = lstm_out + ((size_t)b*30 + s)*512;
#pragma unroll
    for (int h = lane; h < 512; h += 64) acc += lo[h]*ush[h]*W3[h];
#pragma unroll
    for (int off = 32; off; off >>= 1) acc += __shfl_down(acc, off);
    if (lane == 0) sc[s] = acc;
  }
  // kernel-choice logits (waves 0..8, one m each)
  if (wave < 9) {
    float acc = 0.f;
#pragma unroll
    for (int k = lane; k < 512; k += 64) acc += ush[k]*Wmod[k*9+wave];
#pragma unroll
    for (int off = 32; off; off >>= 1) acc += __shfl_down(acc, off);
    if (lane == 0) wl[wave] = acc;
  }
  __syncthreads();
  if (tid == 0) {
    float mx = wl[0];
    for (int m = 1; m < 9; ++m) mx = fmaxf(mx, wl[m]);
    float s = 0.f;
    for (int m = 0; m < 9; ++m) s += fexp(wl[m]-mx);
    float ls = logf(s);
    float ent = 0.f;
    for (int m = 0; m < 9; ++m) {
      float l = wl[m]-mx-ls;
      float w = fexp(l);
      woutAll[t*576 + b*9 + m] = w;
      ent -= w*l;
    }
    imp_part[t*64+b] = ent;
  }
  if (wave == 1) {
    float v = (lane < 30) ? sc[lane] : -3.4e38f;
    float mx = v;
#pragma unroll
    for (int off = 32; off; off >>= 1) mx = fmaxf(mx, __shfl_xor(mx, off));
    float e = (lane < 30) ? fexp(v-mx) : 0.f;
    float ssum = e;
#pragma unroll
    for (int off = 32; off; off >>= 1) ssum += __shfl_xor(ssum, off);
    if (lane < 30) at[lane] = e/ssum;
  }
  __syncthreads();
  // context: 2-way s-split per h
  {
    int h = tid & 511, seg = tid >> 9;
    float acc = 0.f;
    int s0 = seg ? 15 : 0, s1 = seg ? 30 : 15;
    for (int s = s0; s < s1; ++s) acc += at[s]*lstm_out[((size_t)b*30 + s)*512 + h];
    if (seg) cpart[h] = acc;
    __syncthreads();
    if (!seg) {
      float tot = acc + cpart[h];
      cout[b*512+h] = tot;
      sC[h] = tot;
    }
  }
  __syncthreads();
  // tmap = c @ t2m + b  (pair-packed bf16; 4-way k-split)
  {
    int c2 = tid & 255, ks = tid >> 8;   // ks in 0..3
    float a0 = 0.f, a1 = 0.f;
    const unsigned* tp = t2pp + c2;
#pragma unroll 8
    for (int k = ks*128; k < ks*128 + 128; ++k) {
      float cv = sC[k];
      unsigned wv2 = tp[(size_t)k*256];
      a0 += cv*blo(wv2);
      a1 += cv*bhi(wv2);
    }
    tpart[ks][c2]       = a0;
    tpart[ks][256 + c2] = a1;
  }
  __syncthreads();
  if (tid < 512) {
    float v = tpart[0][tid] + tpart[1][tid] + tpart[2][tid] + tpart[3][tid];
    tmapv[b*512 + tid] = v + t2mb[tid];
  }
}

// ---------------------------------------------------------------------------
// fused modules + pooled partials (atomicAdd into per-t pl buffer) + stack
// update + pvec ping-pong.  grid (64 b, 19 pb).
// ---------------------------------------------------------------------------
__global__ __launch_bounds__(256)
void modules2_k(const unsigned short* __restrict__ imapB, const float* __restrict__ tmapv,
                float* __restrict__ stack, const float* __restrict__ pvecIn,
                float* __restrict__ pvecOut,
                const float* __restrict__ swb, const float* __restrict__ c3w,
                const float* __restrict__ c3b, const float* __restrict__ c4w,
                const float* __restrict__ c4b, const float* __restrict__ wmod,
                float* __restrict__ plt)
{
  int b  = blockIdx.x;
  int pb = blockIdx.y;
  int lane = threadIdx.x & 63, wave = threadIdx.x >> 6;
  __shared__ float sT[512];
  __shared__ float pv[8], pd[8], wm[9];
  __shared__ float wpart[4][2][512];
  for (int j = threadIdx.x; j < 512; j += 256) sT[j] = tmapv[b*512 + j];
  if (threadIdx.x < 8) pv[threadIdx.x] = pvecIn[b*8+threadIdx.x];
  if (threadIdx.x >= 64 && threadIdx.x < 73) wm[threadIdx.x-64] = wmod[b*9 + threadIdx.x-64];
  __syncthreads();
  if (threadIdx.x < 8) {
    int l = threadIdx.x;
    pd[l] = (l < 7 ? pv[l+1] : 0.f) + (l == 0 ? pv[0] : 0.f);
  }
  __syncthreads();
  if (pb == 0 && threadIdx.x < 8) {
    int l = threadIdx.x;
    float WP = wm[0]+wm[1]+wm[2]+wm[3] + wm[6] + wm[8];
    float WD = wm[4]+wm[5] + wm[7];
    pvecOut[b*8+l] = WP*pv[l] + WD*pd[l];
  }

  float W[8][6];
#pragma unroll
  for (int m = 0; m < 8; ++m)
#pragma unroll
    for (int i = 0; i < 6; ++i) W[m][i] = swb[m*6+i];
  float W03 = wm[0]+wm[1]+wm[2]+wm[3];
  float W45 = wm[4]+wm[5];

  float acc6[8], acc7[8];
#pragma unroll
  for (int i = 0; i < 8; ++i) { acc6[i] = 0.f; acc7[i] = 0.f; }

  for (int pi = 0; pi < 2; ++pi) {
    int p = pb*8 + wave*2 + pi;
    if (p < 150) {
      const float* st = stack + ((size_t)b*150 + p)*8;
      float a = 0.f, av2 = 0.f;
#pragma unroll
      for (int l = 0; l < 8; ++l) { float v = st[l]; a += v*pv[l]; av2 += v*pd[l]; }
      float part[6] = {0,0,0,0,0,0};
#pragma unroll 2
      for (int i = 0; i < 8; ++i) {
        int d = i*64 + lane;
        float x = bl(imapB[((size_t)b*150 + p)*512 + d]);
        float t = sT[d];
#pragma unroll
        for (int m = 0; m < 4; ++m) {
          float c1 = W[m][0]*t + W[m][1] + W[m][4] + (W[m][2] + W[m][3]*t)*a;
          float c0 = W[m][1]*t + W[m][5]*t*a;
          part[m] += elu_(c1*x + c0) * c3w[m*512+d];
        }
#pragma unroll
        for (int m = 0; m < 2; ++m) {
          float c1 = W[4+m][0]*t + W[4+m][1] + W[4+m][2]*a + W[4+m][3]*av2
                   + W[4+m][4]*a*av2 + W[4+m][5]*t*(a+av2);
          part[4+m] += elu_(c1*x + W[4+m][1]*t) * c4w[m*512+d];
        }
        float c16 = W[6][0]*t + W[6][1] + W[6][4] + (W[6][2] + W[6][3]*t)*a;
        float c06 = W[6][1]*t + W[6][5]*t*a;
        acc6[i] += elu_(c16*x + c06);
        float c17 = W[7][0]*t + W[7][1] + W[7][2]*a + W[7][3]*av2
                  + W[7][4]*a*av2 + W[7][5]*t*(a+av2);
        acc7[i] += elu_(c17*x + W[7][1]*t);
      }
#pragma unroll
      for (int m = 0; m < 6; ++m) {
#pragma unroll
        for (int off = 32; off; off >>= 1) part[m] += __shfl_down(part[m], off);
        part[m] = __shfl(part[m], 0);
      }
      float r3  = wm[0]*(part[0]+c3b[0]) + wm[1]*(part[1]+c3b[1])
                + wm[2]*(part[2]+c3b[2]) + wm[3]*(part[3]+c3b[3]);
      float r45 = wm[4]*(part[4]+c4b[0]) + wm[5]*(part[5]+c4b[1]);
      if (lane < 8) {
        int l = lane;
        size_t idx = ((size_t)b*150 + p)*8 + l;
        stack[idx] = stack[idx]*(1.f - W03*pv[l] - W45*pd[l])
                   + pv[l]*r3 + pd[l]*r45;
      }
    }
  }
#pragma unroll
  for (int i = 0; i < 8; ++i) {
    wpart[wave][0][i*64+lane] = acc6[i];
    wpart[wave][1][i*64+lane] = acc7[i];
  }
  __syncthreads();
  for (int e = threadIdx.x; e < 1024; e += 256) {
    int which = e >> 9, d = e & 511;
    float s = wpart[0][which][d] + wpart[1][which][d]
            + wpart[2][which][d] + wpart[3][which][d];
    atomicAdd(&plt[(size_t)which*32768 + b*512 + d], s * (1.f/150.f));
  }
}

// ---------------------------------------------------------------------------
// batched m67 GEMMs for ALL t: grid (8 colchunks, 8 rowchunks, 18).
// z = t*2+zz: m67t[z] = [pl[t][zz] | tmapv[t]] @ ansW[zz] + ansb[zz]
// ---------------------------------------------------------------------------
__global__ __launch_bounds__(512)
void ansall_k(const float* __restrict__ plt, const float* __restrict__ tmapv,
              const unsigned short* __restrict__ answp, const float* __restrict__ ansb,
              float* __restrict__ m67o)
{
  const int z = blockIdx.z;          // 0..17
  const int t = z >> 1, zz = z & 1;
  __shared__ __align__(16) float As[8][1024];
  __shared__ float part[8][8][64];
  const int tid = threadIdx.x;
  const int r0 = blockIdx.y*8;
  const int nc0 = blockIdx.x*64;
  const int lane = tid & 63, w = tid >> 6;

  for (int e4 = tid; e4 < 1024; e4 += 512) {
    int r = e4 >> 7, k4 = (e4 & 127) << 2;
    *(float4*)&As[r][k4]     = *(const float4*)&plt[(size_t)z*32768 + (size_t)(r0+r)*512 + k4];
    *(float4*)&As[r][512+k4] = *(const float4*)&tmapv[(size_t)t*32768 + (size_t)(r0+r)*512 + k4];
  }
  __syncthreads();
  {
    const unsigned short* Bp = answp + (size_t)zz*524288
                             + (size_t)(w*128)*512 + nc0 + lane;
    float acc[8] = {0,0,0,0,0,0,0,0};
    int k0 = w*128;
#pragma unroll 8
    for (int kk = 0; kk < 128; ++kk) {
      float bv = bl(Bp[(size_t)kk*512]);
#pragma unroll
      for (int r = 0; r < 8; ++r) acc[r] += As[r][k0+kk]*bv;
    }
#pragma unroll
    for (int r = 0; r < 8; ++r) part[w][r][lane] = acc[r];
  }
  __syncthreads();
  {
    int r = tid >> 6, c = tid & 63;
    float s = 0.f;
#pragma unroll
    for (int w2 = 0; w2 < 8; ++w2) s += part[w2][r][c];
    m67o[(size_t)z*32768 + (size_t)(r0+r)*512 + nc0 + c] = s + ansb[zz*512 + nc0 + c];
  }
}

// ---------------------------------------------------------------------------
// final mem: mem_8 = sum_t coef_t*(w6_t*m6_t + w7_t*m7_t),
// coef_t = prod_{s>t} (1-w6_s-w7_s).  (mem_init = 0)
// ---------------------------------------------------------------------------
__global__ __launch_bounds__(512)
void memfin_k(const float* __restrict__ woutAll, const float* __restrict__ m67t,
              float* __restrict__ memb)
{
  int b = blockIdx.x;
  int tid = threadIdx.x;
  __shared__ float w6s[9], w7s[9], coef[9];
  if (tid < 9)       w6s[tid] = woutAll[tid*576 + b*9 + 6];
  else if (tid < 18) w7s[tid-9] = woutAll[(tid-9)*576 + b*9 + 7];
  __syncthreads();
  if (tid == 0) {
    float c = 1.f;
    for (int t = 8; t >= 0; --t) { coef[t] = c; c *= (1.f - w6s[t] - w7s[t]); }
  }
  __syncthreads();
  float acc = 0.f;
#pragma unroll
  for (int t = 0; t < 9; ++t) {
    float m6 = m67t[(((size_t)t*2 + 0)*64 + b)*512 + tid];
    float m7 = m67t[(((size_t)t*2 + 1)*64 + b)*512 + tid];
    acc += coef[t]*(w6s[t]*m6 + w7s[t]*m7);
  }
  memb[b*512 + tid] = acc;
}

// ---------------------------------------------------------------------------
__global__ __launch_bounds__(256)
void imp_k(const float* __restrict__ part, float* __restrict__ out)
{
  int lane = threadIdx.x & 63, wave = threadIdx.x >> 6;
  float acc = 0.f;
  for (int i = threadIdx.x; i < 576; i += 256) acc += part[i];
#pragma unroll
  for (int off = 32; off; off >>= 1) acc += __shfl_down(acc, off);
  __shared__ float red[4];
  if (lane == 0) red[wave] = acc;
  __syncthreads();
  if (threadIdx.x == 0) out[0] = red[0]+red[1]+red[2]+red[3];
}

// ---------------------------------------------------------------------------
extern "C" void kernel_launch(void* const* d_in, const int* in_sizes, int n_in,
                              void* d_out, int out_size, void* d_ws, size_t ws_size,
                              hipStream_t stream)
{
  (void)in_sizes; (void)n_in; (void)out_size; (void)ws_size;
  const float* image = (const float*)d_in[0];
  const int*   ques  = (const int*)d_in[1];
  const int*   qlen  = (const int*)d_in[2];
  const float* embedW= (const float*)d_in[3];
  const float* Wi_f  = (const float*)d_in[4];
  const float* Wh_f  = (const float*)d_in[5];
  const float* b_f   = (const float*)d_in[6];
  const float* Wi_b  = (const float*)d_in[7];
  const float* Wh_b  = (const float*)d_in[8];
  const float* b_b   = (const float*)d_in[9];
  const float* W1    = (const float*)d_in[10];
  const float* b1    = (const float*)d_in[11];
  const float* W2w   = (const float*)d_in[12];
  const float* W2b   = (const float*)d_in[13];
  const float* W3    = (const float*)d_in[14];
  const float* c0    = (const float*)d_in[15];
  const float* Wmod  = (const float*)d_in[16];
  const float* ic1w  = (const float*)d_in[17];
  const float* ic1b  = (const float*)d_in[18];
  const float* ic2w  = (const float*)d_in[19];
  const float* ic2b  = (const float*)d_in[20];
  const float* i2mw  = (const float*)d_in[21];
  const float* i2mb  = (const float*)d_in[22];
  const float* t2mw  = (const float*)d_in[23];
  const float* t2mb  = (const float*)d_in[24];
  const float* c3ow  = (const float*)d_in[25];
  const float* c3cw  = (const float*)d_in[26];
  const float* c3cb  = (const float*)d_in[27];
  const float* c4ow  = (const float*)d_in[28];
  const float* c4cw  = (const float*)d_in[29];
  const float* c4cb  = (const float*)d_in[30];
  const float* aow   = (const float*)d_in[31];
  const float* ansW  = (const float*)d_in[32];
  const float* ansb  = (const float*)d_in[33];
  const float* o1w   = (const float*)d_in[34];
  const float* o1b   = (const float*)d_in[35];
  const float* o2w   = (const float*)d_in[36];
  const float* o2b   = (const float*)d_in[37];
  float* out = (float*)d_out;
  float* ws  = (float*)d_ws;

  size_t off = 0;
  auto alloc = [&](size_t n){ float* p = ws + off; off += n; return p; };
  short* imgP  = (short*)alloc(600ull*20*64*8/2);
  short* X1p   = (short*)alloc(600ull*16*64*8/2);
  short* X2p   = (short*)alloc(600ull*16*64*8/2);
  short* w1p   = (short*)alloc(20*32*64*8/2);
  short* w2mp  = (short*)alloc(16*32*64*8/2);
  short* w3mp  = (short*)alloc(16*32*64*8/2);
  short* wifp  = (short*)alloc(10*64*64*8/2);
  short* wibp  = (short*)alloc(10*64*64*8/2);
  short* embp  = (short*)alloc(120ull*10*64*8/2);
  unsigned short* imapB = (unsigned short*)alloc(9600ull*512/2);
  unsigned* t2pp = (unsigned*)alloc(512*256);
  unsigned short* w2bp  = (unsigned short*)alloc(524288/2);
  unsigned short* answp = (unsigned short*)alloc(1048576/2);
  float* xWfb  = alloc(64ull*30*1024);
  float* xWbb  = alloc(64ull*30*1024);
  float* lout  = alloc(64ull*30*512);
  float* qbuf  = alloc(64*512);
  float* stck  = alloc(64*150*8);
  float* pvecA = alloc(64*8);
  float* pvecB = alloc(64*8);
  float* memb  = alloc(64*512);
  float* cprev = alloc(64*512);
  float* tmp1a = alloc(9ull*64*512);
  float* wmwA  = alloc(9*64*9);
  float* impp  = alloc(9*64);
  float* swb   = alloc(48);
  float* pl    = alloc(9ull*2*64*512);
  float* m67t  = alloc(9ull*2*64*512);
  float* tmapv = alloc(9ull*64*512);
  float* h1b   = alloc(64*1024);
  unsigned* whT = (unsigned*)alloc(2ull*1024*128);       // f16-pair packed Wh^T
  float* hbufW  = alloc(32768);                          // 2 ping x 2 d x 4 g x 16 x 256 f16
  int*   flagsI = (int*)alloc(256);                      // step sync flags

  // one dispatch: init + ALL independent packs (incl. f16 WhT, bf16 W2/ansW)
  megapack_k<<<12036, 256, 0, stream>>>(
      c0, c3ow, c4ow, aow, stck, pvecA, memb, cprev, swb, pl,
      Wh_f, Wh_b, whT, hbufW, flagsI,
      ic1w, w1p, ic2w, w2mp, i2mw, w3mp, Wi_f, wifp, Wi_b, wibp,
      image, imgP, embedW, ques, embp, t2mw, t2pp,
      W2w, w2bp, ansW, answp);

  // conv chain (MFMA); conv3 -> bf16 row-major imapB
  gemmM_k<<<dim3(8,150,1), 256, 0, stream>>>(imgP, imgP, w1p, w1p, ic1b, ic1b,
                                             X1p, X1p, 20, 32, 512, 1, 1, 16);
  gemmM_k<<<dim3(8,150,1), 256, 0, stream>>>(X1p, X1p, w2mp, w2mp, ic2b, ic2b,
                                             X2p, X2p, 16, 32, 512, 1, 0, 16);
  gemmM_k<<<dim3(8,150,1), 256, 0, stream>>>(X2p, X2p, w3mp, w3mp, i2mb, i2mb,
                                             imapB, imapB, 16, 32, 512, 2, 0, 0);
  // both embed GEMMs in one launch
  gemmM_k<<<dim3(16,30,2), 256, 0, stream>>>(embp, embp, wifp, wibp, b_f, b_b,
                                             xWfb, xWbb, 10, 64, 1024, 0, 0, 0);

  // MFMA LSTM: 32 persistent blocks, LDS weights, round-4 flag protocol
  lstmM_k<<<32, 256, 0, stream>>>(xWfb, xWbb, whT, qlen,
                                  (unsigned long long*)hbufW, flagsI, lout, qbuf);

  // tmp1all[t] = q @ W1[t] + b1 (all 9 t)
  gemm64b_k<<<dim3(8,8,9), 512, 0, stream>>>(
      qbuf, 0, 9, (const float*)nullptr, 0,
      W1, 262144, b1, 0, tmp1a, 32768, 512, 0);

  for (int t = 0; t < 9; ++t) {
    float* pvIn  = (t & 1) ? pvecB : pvecA;
    float* pvOut = (t & 1) ? pvecA : pvecB;
    kcattn3_k<<<64, 1024, 0, stream>>>(
        tmp1a + (size_t)t*32768, cprev, w2bp, W2b,
        Wmod, lout, W3, t2pp, t2mb,
        wmwA, impp, cprev, tmapv + (size_t)t*32768, t);
    modules2_k<<<dim3(64,19), 256, 0, stream>>>(
        imapB, tmapv + (size_t)t*32768, stck, pvIn, pvOut, swb,
        c3cw, c3cb, c4cw, c4cb,
        wmwA + (size_t)t*576, pl + (size_t)t*65536);
  }

  // all 18 m67 GEMMs in ONE dispatch (off the sequential critical path)
  ansall_k<<<dim3(8,8,18), 512, 0, stream>>>(pl, tmapv, answp, ansb, m67t);

  // final mem blend, then h1 = elu([q, mem] @ out1 + b); logits = h1 @ out2 + b
  memfin_k<<<64, 512, 0, stream>>>(wmwA, m67t, memb);
  gemm64b_k<<<dim3(16,8,1), 512, 0, stream>>>(
      qbuf, 0, 9, memb, 512, o1w, 0, o1b, 0, h1b, 0, 1024, 1);
  gemm64b_k<<<dim3(1,8,1), 512, 0, stream>>>(
      h1b, 0, 10, (const float*)nullptr, 0, o2w, 0, o2b, 0, out, 0, 32, 0);
  imp_k<<<1, 256, 0, stream>>>(impp, out + 2048);
}

// Round 7
// 904.937 us; speedup vs baseline: 1.0473x; 1.0473x over previous
//
#include <hip/hip_runtime.h>
#include <hip/hip_fp16.h>
#include <math.h>

#define DEV __device__ __forceinline__

DEV float fexp(float x){ return __expf(x); }
DEV float elu_(float x){ return x > 0.f ? x : fexp(x) - 1.f; }
DEV float sigm_(float x){ return 1.f/(1.f + fexp(-x)); }
DEV float tanh_(float x){ float e = fexp(2.f*x); return 1.f - 2.f/(e + 1.f); }
DEV unsigned bf16r(float x){ unsigned u = __float_as_uint(x);
  return (u + 0x7fffu + ((u>>16)&1u)) >> 16; }
DEV float blo(unsigned u){ return __uint_as_float(u << 16); }
DEV float bhi(unsigned u){ return __uint_as_float(u & 0xffff0000u); }
DEV float bl(unsigned short u){ return __uint_as_float(((unsigned)u) << 16); }

using frag  = __attribute__((ext_vector_type(8))) short;     // 8 bf16 (4 VGPRs)
using fragh = __attribute__((ext_vector_type(8))) _Float16;  // 8 f16  (4 VGPRs)
using f32x4 = __attribute__((ext_vector_type(4))) float;     // MFMA acc

// coherent (sc0 sc1 = device-coherent path) 16B load WITH completion wait
DEV uint4 cload16w(const void* p){
  uint4 r;
  asm volatile("global_load_dwordx4 %0, %1, off sc0 sc1\n\ts_waitcnt vmcnt(0)"
               : "=v"(r) : "v"(p) : "memory");
  return r;
}
// coherent 16B load, NO wait (caller does one s_waitcnt vmcnt(0) for the batch)
DEV uint4 cload16nw(const void* p){
  uint4 r;
  asm volatile("global_load_dwordx4 %0, %1, off sc0 sc1"
               : "=v"(r) : "v"(p) : "memory");
  return r;
}

// ---------------------------------------------------------------------------
// device pack helpers
// ---------------------------------------------------------------------------
DEV void d_packB(const float* __restrict__ W, short* __restrict__ Bp,
                 int KC, int Ng, int Ksrc, int N, int trans, int idx)
{
  if (idx >= KC*Ng*64) return;
  int lane = idx & 63;
  int g    = (idx >> 6) % Ng;
  int kc   = idx / (64*Ng);
  int n = g*16 + (lane & 15);
  int kb = kc*32 + ((lane >> 4) << 3);
  unsigned o[4];
#pragma unroll
  for (int jj = 0; jj < 4; ++jj) {
    int k0 = kb + 2*jj;
    float v0 = (k0   < Ksrc) ? (trans ? W[(size_t)n*Ksrc + k0]   : W[(size_t)(k0)*N + n])   : 0.f;
    float v1 = (k0+1 < Ksrc) ? (trans ? W[(size_t)n*Ksrc + k0+1] : W[(size_t)(k0+1)*N + n]) : 0.f;
    o[jj] = bf16r(v0) | (bf16r(v1) << 16);
  }
  *(uint4*)(Bp + (size_t)idx*8) = make_uint4(o[0], o[1], o[2], o[3]);
}

DEV void d_packImg(const float* __restrict__ image, short* __restrict__ Ap, int idx)
{
  int lane = idx & 63;
  int kc   = (idx >> 6) % 20;
  int mt   = idx / 1280;
  int row = mt*16 + (lane & 15);
  int b = row / 150, p = row % 150;
  int cb = kc*32 + ((lane >> 4) << 3);
  unsigned o[4];
#pragma unroll
  for (int jj = 0; jj < 4; ++jj) {
    float v0 = image[((size_t)b*640 + cb + 2*jj    )*150 + p];
    float v1 = image[((size_t)b*640 + cb + 2*jj + 1)*150 + p];
    o[jj] = bf16r(v0) | (bf16r(v1) << 16);
  }
  *(uint4*)(Ap + (size_t)idx*8) = make_uint4(o[0], o[1], o[2], o[3]);
}

DEV void d_packEmb(const float* __restrict__ embedW, const int* __restrict__ ques,
                   short* __restrict__ Ap, int idx)
{
  int lane = idx & 63;
  int kc   = (idx >> 6) % 10;
  int mt   = idx / 640;
  int row = mt*16 + (lane & 15);
  int q = ques[row];
  int kb = kc*32 + ((lane >> 4) << 3);
  unsigned o[4];
#pragma unroll
  for (int jj = 0; jj < 4; ++jj) {
    int k0 = kb + 2*jj;
    float v0 = (k0   < 300) ? embedW[(size_t)q*300 + k0]   : 0.f;
    float v1 = (k0+1 < 300) ? embedW[(size_t)q*300 + k0+1] : 0.f;
    o[jj] = bf16r(v0) | (bf16r(v1) << 16);
  }
  *(uint4*)(Ap + (size_t)idx*8) = make_uint4(o[0], o[1], o[2], o[3]);
}

// ---------------------------------------------------------------------------
// ONE dispatch for all independent pre-stage work
// ---------------------------------------------------------------------------
__global__ __launch_bounds__(256)
void megapack_k(const float* __restrict__ c0, const float* __restrict__ c3ow,
                const float* __restrict__ c4ow, const float* __restrict__ aow,
                float* __restrict__ stack, float* __restrict__ pvecA,
                float* __restrict__ mem, float* __restrict__ cprev,
                float* __restrict__ swb, float* __restrict__ pl,
                const float* __restrict__ Whf, const float* __restrict__ Whb,
                unsigned* __restrict__ whT,
                float* __restrict__ hbufz, int* __restrict__ flagz,
                const float* __restrict__ ic1w, short* __restrict__ w1p,
                const float* __restrict__ ic2w, short* __restrict__ w2mp,
                const float* __restrict__ i2mw, short* __restrict__ w3mp,
                const float* __restrict__ Wif, short* __restrict__ wifp,
                const float* __restrict__ Wib, short* __restrict__ wibp,
                const float* __restrict__ image, short* __restrict__ imgP,
                const float* __restrict__ embedW, const int* __restrict__ ques,
                short* __restrict__ embp,
                const float* __restrict__ t2mw, unsigned* __restrict__ t2pp,
                const float* __restrict__ W2w, unsigned short* __restrict__ w2bp,
                const float* __restrict__ ansW, unsigned short* __restrict__ answp)
{
  const int bx = blockIdx.x, tid = threadIdx.x;
  if (bx < 320) {
    int idx = bx*256 + tid;
    int stride = 320*256;
    for (int i = idx; i < 64*150*8; i += stride) stack[i] = 0.f;
    for (int i = idx; i < 64*8;    i += stride) pvecA[i] = ((i & 7) == 0) ? 1.f : 0.f;
    for (int i = idx; i < 64*512;  i += stride) mem[i] = 0.f;
    for (int i = idx; i < 64*512;  i += stride) cprev[i] = c0[i & 511];
    for (int i = idx; i < 9*2*64*512; i += stride) pl[i] = 0.f;
    for (int i = idx; i < 32768;   i += stride) hbufz[i] = 0.f;  // hbuf (f16 pairs)
    if (idx < 256) flagz[idx] = 0;                               // sync flags
    if (idx < 8) {
      const float* ow = (idx < 4) ? (c3ow + idx*6)
                      : (idx < 6) ? (c4ow + (idx-4)*6)
                                  : (aow  + (idx-6)*6);
      float mx = ow[0];
      for (int m = 1; m < 6; ++m) mx = fmaxf(mx, ow[m]);
      float e[6]; float s = 0.f;
      for (int m = 0; m < 6; ++m) { e[m] = fexp(ow[m]-mx); s += e[m]; }
      for (int m = 0; m < 6; ++m) swb[idx*6+m] = e[m]/s;
    }
  } else if (bx < 1344) {
    // WhT: [d][zc 0..1023][k-pair 0..127] packed f16 pairs (transposed Wh)
    int idx = (bx-320)*256 + tid;
    int dd  = idx >> 17;
    int rem = idx & 131071;
    int kp  = rem >> 10;
    int zc  = rem & 1023;
    const float* Wh = dd ? Whb : Whf;
    __half2 hv = __floats2half2_rn(Wh[(size_t)(2*kp)*1024 + zc],
                                   Wh[(size_t)(2*kp+1)*1024 + zc]);
    whT[((size_t)dd << 17) + (zc << 7) + kp] = *(unsigned*)&hv;
  } else if (bx < 1504) {
    d_packB(ic1w, w1p, 20, 32, 640, 512, 1, (bx-1344)*256 + tid);
  } else if (bx < 1632) {
    d_packB(ic2w, w2mp, 16, 32, 512, 512, 1, (bx-1504)*256 + tid);
  } else if (bx < 1760) {
    d_packB(i2mw, w3mp, 16, 32, 512, 512, 1, (bx-1632)*256 + tid);
  } else if (bx < 1920) {
    d_packB(Wif, wifp, 10, 64, 300, 1024, 0, (bx-1760)*256 + tid);
  } else if (bx < 2080) {
    d_packB(Wib, wibp, 10, 64, 300, 1024, 0, (bx-1920)*256 + tid);
  } else if (bx < 5080) {
    d_packImg(image, imgP, (bx-2080)*256 + tid);
  } else if (bx < 5380) {
    d_packEmb(embedW, ques, embp, (bx-5080)*256 + tid);
  } else if (bx < 5892) {
    int idx = (bx-5380)*256 + tid;   // 512*256
    int k = idx >> 8, c = idx & 255;
    t2pp[idx] = bf16r(t2mw[(size_t)k*512 + c]) | (bf16r(t2mw[(size_t)k*512 + 256 + c]) << 16);
  } else if (bx < 7940) {
    int i = (bx-5892)*256 + tid;     // 524288
    w2bp[i] = (unsigned short)bf16r(W2w[i]);
  } else {
    int i = (bx-7940)*256 + tid;     // 1048576
    answp[i] = (unsigned short)bf16r(ansW[i]);
  }
}

// ---------------------------------------------------------------------------
// MFMA GEMM, dual problem sets via blockIdx.z.
// mode 0: fp32 row-major; mode 1: bf16 A-pack; mode 2: bf16 row-major
// ---------------------------------------------------------------------------
__global__ __launch_bounds__(256)
void gemmM_k(const short* __restrict__ ApA, const short* __restrict__ ApB,
             const short* __restrict__ BpA, const short* __restrict__ BpB,
             const float* __restrict__ biasA, const float* __restrict__ biasB,
             void* __restrict__ CoutA, void* __restrict__ CoutB,
             int KC, int Ng, int N, int mode, int act, int KCout)
{
  __shared__ float lds[4][16][68];
  const int z = blockIdx.z;
  const short* Ap = z ? ApB : ApA;
  const short* Bp = z ? BpB : BpA;
  const float* bias = z ? biasB : biasA;
  void* Cout = z ? CoutB : CoutA;
  const int tid = threadIdx.x, lane = tid & 63, w = tid >> 6;
  const int mt = blockIdx.y*4 + w;
  const int ncol0 = blockIdx.x*64;
  const short* Abase = Ap + (((size_t)mt*KC) << 9) + lane*8;
  const short* Bbase = Bp + (((size_t)blockIdx.x*4) << 9) + lane*8;
  f32x4 acc0 = {0.f,0.f,0.f,0.f}, acc1 = acc0, acc2 = acc0, acc3 = acc0;
#pragma unroll 2
  for (int kc = 0; kc < KC; ++kc) {
    frag a = *(const frag*)(Abase + ((size_t)kc << 9));
    const short* bk = Bbase + (((size_t)kc*Ng) << 9);
    frag b0 = *(const frag*)(bk);
    frag b1 = *(const frag*)(bk + 512);
    frag b2 = *(const frag*)(bk + 1024);
    frag b3 = *(const frag*)(bk + 1536);
    acc0 = __builtin_amdgcn_mfma_f32_16x16x32_bf16(a, b0, acc0, 0, 0, 0);
    acc1 = __builtin_amdgcn_mfma_f32_16x16x32_bf16(a, b1, acc1, 0, 0, 0);
    acc2 = __builtin_amdgcn_mfma_f32_16x16x32_bf16(a, b2, acc2, 0, 0, 0);
    acc3 = __builtin_amdgcn_mfma_f32_16x16x32_bf16(a, b3, acc3, 0, 0, 0);
  }
  {
    int colb = lane & 15, rowb = (lane >> 4)*4;
#pragma unroll
    for (int r = 0; r < 4; ++r) {
      lds[w][rowb+r][ 0+colb] = acc0[r];
      lds[w][rowb+r][16+colb] = acc1[r];
      lds[w][rowb+r][32+colb] = acc2[r];
      lds[w][rowb+r][48+colb] = acc3[r];
    }
  }
  __syncthreads();
  if (mode == 0) {
    float* C = (float*)Cout;
    int mloc = lane >> 2, q4 = lane & 3;
    size_t rowoff = (size_t)(mt*16 + mloc)*N + ncol0 + q4*16;
#pragma unroll
    for (int i = 0; i < 4; ++i) {
      float4 v = *(float4*)&lds[w][mloc][q4*16 + i*4];
      const float* bp = bias + ncol0 + q4*16 + i*4;
      v.x += bp[0]; v.y += bp[1]; v.z += bp[2]; v.w += bp[3];
      if (act) { v.x = elu_(v.x); v.y = elu_(v.y); v.z = elu_(v.z); v.w = elu_(v.w); }
      *(float4*)&C[rowoff + i*4] = v;
    }
  } else if (mode == 1) {
    short* C = (short*)Cout;
    int m = lane & 15, qb = (lane >> 4)*8;
#pragma unroll
    for (int h = 0; h < 2; ++h) {
      int nl = h*32 + qb;
      unsigned o[4];
#pragma unroll
      for (int jj = 0; jj < 4; ++jj) {
        float v0 = lds[w][m][nl + 2*jj]     + bias[ncol0 + nl + 2*jj];
        float v1 = lds[w][m][nl + 2*jj + 1] + bias[ncol0 + nl + 2*jj + 1];
        if (act) { v0 = elu_(v0); v1 = elu_(v1); }
        o[jj] = bf16r(v0) | (bf16r(v1) << 16);
      }
      *(uint4*)(C + (((size_t)mt*KCout + (ncol0 >> 5) + h) << 9) + lane*8)
          = make_uint4(o[0], o[1], o[2], o[3]);
    }
  } else {
    unsigned short* C = (unsigned short*)Cout;
    int row = lane >> 2, cb = (lane & 3)*16;
#pragma unroll
    for (int h = 0; h < 2; ++h) {
      unsigned o[4];
#pragma unroll
      for (int jj = 0; jj < 4; ++jj) {
        float v0 = lds[w][row][cb + h*8 + 2*jj]     + bias[ncol0 + cb + h*8 + 2*jj];
        float v1 = lds[w][row][cb + h*8 + 2*jj + 1] + bias[ncol0 + cb + h*8 + 2*jj + 1];
        if (act) { v0 = elu_(v0); v1 = elu_(v1); }
        o[jj] = bf16r(v0) | (bf16r(v1) << 16);
      }
      *(uint4*)&C[(size_t)(mt*16 + row)*N + ncol0 + cb + h*8]
          = make_uint4(o[0], o[1], o[2], o[3]);
    }
  }
}

// ---------------------------------------------------------------------------
// 64-row batch GEMM, K-split across waves
// ---------------------------------------------------------------------------
__global__ __launch_bounds__(512)
void gemm64b_k(const float* __restrict__ A1, long zA1, int K1log,
               const float* __restrict__ A2, int K2,
               const float* __restrict__ B, long zB,
               const float* __restrict__ bias, int zbias,
               float* __restrict__ C, long zC, int N, int act)
{
  const int K1 = 1 << K1log;
  const int Kt = K1 + K2;
  __shared__ __align__(16) float As[8][1024];
  __shared__ float part[8][8][64];
  const int tid = threadIdx.x;
  const int z = blockIdx.z;
  const int r0 = blockIdx.y*8;
  {
    const float* a1 = A1 + (size_t)z*zA1;
    const int nf4 = (8*K1) >> 2;
    for (int e4 = tid; e4 < nf4; e4 += 512) {
      int r = e4 >> (K1log-2);
      int k4 = (e4 & ((K1>>2)-1)) << 2;
      *(float4*)&As[r][k4] = *(const float4*)&a1[(size_t)(r0+r)*K1 + k4];
    }
    if (K2 > 0) {
      for (int e4 = tid; e4 < 1024; e4 += 512) {
        int r = e4 >> 7;
        int k4 = (e4 & 127) << 2;
        *(float4*)&As[r][K1+k4] = *(const float4*)&A2[(size_t)(r0+r)*512 + k4];
      }
    }
  }
  __syncthreads();
  const int lane = tid & 63, w = tid >> 6;
  const int n = blockIdx.x*64 + lane;
  const bool nv = n < N;
  const int kseg = Kt >> 3;
  const int k0 = w*kseg;
  const float* Bp = B + (size_t)z*zB + (size_t)k0*N + (nv ? n : 0);
  float acc[8] = {0,0,0,0,0,0,0,0};
#pragma unroll 8
  for (int kk = 0; kk < kseg; ++kk) {
    float bv = nv ? Bp[(size_t)kk*N] : 0.f;
    int k = k0 + kk;
#pragma unroll
    for (int r = 0; r < 8; ++r) acc[r] += As[r][k]*bv;
  }
#pragma unroll
  for (int r = 0; r < 8; ++r) part[w][r][lane] = acc[r];
  __syncthreads();
  {
    int r = tid >> 6, c = tid & 63;
    int nn = blockIdx.x*64 + c;
    if (nn < N) {
      float s = 0.f;
#pragma unroll
      for (int w2 = 0; w2 < 8; ++w2) s += part[w2][r][c];
      s += bias ? bias[(size_t)z*zbias + nn] : 0.f;
      if (act == 1) s = elu_(s);
      C[(size_t)z*zC + (size_t)(r0+r)*N + nn] = s;
    }
  }
}

// ---------------------------------------------------------------------------
// MFMA bidirectional masked LSTM (round-4 protocol: LDS-resident weights,
// per-step flag sync over coherent atomics + pipelined sc0sc1 h loads).
// ---------------------------------------------------------------------------
__global__ __launch_bounds__(256)
void lstmM_k(const float* __restrict__ xWf, const float* __restrict__ xWb,
             const unsigned* __restrict__ whT, const int* __restrict__ qlen,
             unsigned long long* __restrict__ hbuf, int* __restrict__ flags,
             float* __restrict__ lstm_out, float* __restrict__ qout)
{
  const int bx = blockIdx.x;
  const int d = bx & 1, g = (bx >> 1) & 3, n = bx >> 3;
  const int tid = threadIdx.x, lane = tid & 63, w = tid >> 6;
  const int q = lane >> 4, cl = lane & 15;
  __shared__ __align__(16) unsigned short Wl[65536];   // 128 KiB

#pragma unroll 4
  for (int rb = 0; rb < 32; ++rb) {
    int lcrow = rb*8 + (tid >> 5);
    int gt = lcrow >> 6, c = lcrow & 63;
    int zc = gt*256 + n*64 + c;
    uint4 v = *(const uint4*)(whT + (((size_t)d*1024 + zc) << 7) + ((tid & 31) << 2));
    int byteoff = (lcrow << 9) + ((((tid & 31) << 4)) ^ ((lcrow & 7) << 4));
    *(uint4*)((char*)Wl + byteoff) = v;
  }

  const float* xW = d ? xWb : xWf;
  const int b   = g*16 + cl;                 // this lane's batch
  const int c4  = w*16 + q*4;                // local col base within slice
  const int hc4 = n*64 + c4;                 // global h-col base (4 consecutive)
  const int len = qlen[b];
  float cst[4] = {0.f,0.f,0.f,0.f}, hst[4] = {0.f,0.f,0.f,0.f};
  int* flg = flags + ((d*4 + g) << 2);       // 4 flags for this (d,g) group
  const int bofs = (cl & 7) << 4;
  __syncthreads();

  for (int ss = 0; ss < 30; ++ss) {
    const int s = d ? (29 - ss) : ss;
    const float* xr = xW + (size_t)b*30720 + (size_t)s*1024 + hc4;
    f32x4 xwv[4];
#pragma unroll
    for (int gt = 0; gt < 4; ++gt) xwv[gt] = *(const f32x4*)(xr + gt*256);

    if (ss > 0) {
      for (;;) {
        uint4 f4 = cload16w(flg);   // all 4 flags in ONE coherent 16B load
        if ((int)f4.x >= ss && (int)f4.y >= ss &&
            (int)f4.z >= ss && (int)f4.w >= ss) break;
      }
      __builtin_amdgcn_sched_barrier(0);
    }
    // B = h^T from hbuf: 8 pipelined coherent 16B loads, ONE vmcnt wait
    const char* hbr = (const char*)(hbuf + ((size_t)(((ss & 1)*2 + d)*4 + g) << 9))
                    + (cl << 9) + (q << 4);
    union { uint4 u; fragh f; } hv[8];
#pragma unroll
    for (int ks = 0; ks < 8; ++ks) hv[ks].u = cload16nw(hbr + (ks << 6));
    asm volatile("s_waitcnt vmcnt(0)" ::: "memory");
    __builtin_amdgcn_sched_barrier(0);

    f32x4 acc0 = {0.f,0.f,0.f,0.f}, acc1 = acc0, acc2 = acc0, acc3 = acc0;
#pragma unroll
    for (int ks = 0; ks < 8; ++ks) {
      const int kb = ((ks << 6) + (q << 4)) ^ bofs;
      const char* wb = (const char*)Wl + ((w*16 + cl) << 9) + kb;
      fragh a0 = *(const fragh*)(wb);
      fragh a1 = *(const fragh*)(wb + (64 << 9));
      fragh a2 = *(const fragh*)(wb + (128 << 9));
      fragh a3 = *(const fragh*)(wb + (192 << 9));
      acc0 = __builtin_amdgcn_mfma_f32_16x16x32_f16(a0, hv[ks].f, acc0, 0, 0, 0);
      acc1 = __builtin_amdgcn_mfma_f32_16x16x32_f16(a1, hv[ks].f, acc1, 0, 0, 0);
      acc2 = __builtin_amdgcn_mfma_f32_16x16x32_f16(a2, hv[ks].f, acc2, 0, 0, 0);
      acc3 = __builtin_amdgcn_mfma_f32_16x16x32_f16(a3, hv[ks].f, acc3, 0, 0, 0);
    }
    const bool m = s < len;
    f32x4 lo4;
    float hvv[4];
#pragma unroll
    for (int r = 0; r < 4; ++r) {
      float iv = acc0[r] + xwv[0][r];
      float fv = acc1[r] + xwv[1][r];
      float gv = acc2[r] + xwv[2][r];
      float o_ = acc3[r] + xwv[3][r];
      float cn = sigm_(fv)*cst[r] + sigm_(iv)*tanh_(gv);
      float hn = sigm_(o_)*tanh_(cn);
      float hk = m ? hn : hst[r];
      cst[r] = m ? cn : cst[r];
      hst[r] = hk;
      hvv[r] = hk;
      lo4[r] = m ? hn : 0.f;
    }
    unsigned long long* hbw = hbuf + ((size_t)((((ss & 1) ^ 1)*2 + d)*4 + g) << 9);
    union { unsigned long long u; __half2 h2[2]; } hp;
    hp.h2[0] = __floats2half2_rn(hvv[0], hvv[1]);
    hp.h2[1] = __floats2half2_rn(hvv[2], hvv[3]);
    __hip_atomic_store(hbw + cl*64 + (hc4 >> 2), hp.u,
                       __ATOMIC_RELAXED, __HIP_MEMORY_SCOPE_AGENT);
    *(f32x4*)(lstm_out + (((size_t)b*30 + s) << 9) + (d << 8) + hc4) = lo4;
    asm volatile("s_waitcnt vmcnt(0)" ::: "memory");
    __syncthreads();
    if (tid == 0)
      __hip_atomic_store(&flg[n], ss + 1, __ATOMIC_RELAXED, __HIP_MEMORY_SCOPE_AGENT);
  }
  *(f32x4*)(qout + ((size_t)b << 9) + (d << 8) + hc4) =
      f32x4{hst[0], hst[1], hst[2], hst[3]};
}

// ---------------------------------------------------------------------------
// fused kc + attn + tmap — 1024 threads (round-4 version, reads precomputed u)
// ---------------------------------------------------------------------------
__global__ __launch_bounds__(1024)
void kcattn3_k(const float* __restrict__ u, const float* __restrict__ Wmod,
               const float* __restrict__ lstm_out, const float* __restrict__ W3,
               const unsigned* __restrict__ t2pp, const float* __restrict__ t2mb,
               float* __restrict__ woutAll, float* __restrict__ imp_part,
               float* __restrict__ cout, float* __restrict__ tmapv, int t)
{
  int b = blockIdx.x;
  int tid = threadIdx.x;
  int lane = tid & 63, wave = tid >> 6;   // 16 waves
  __shared__ float ush[512];
  __shared__ float sC[512];
  __shared__ float cpart[512];
  __shared__ float tpart[4][512];
  __shared__ float wl[9];
  __shared__ float sc[32], at[32];
  if (tid < 512) ush[tid] = u[b*512 + tid];
  __syncthreads();
  // attention scores (16 waves cover s = wave, wave+16)
  for (int s = wave; s < 30; s += 16) {
    float acc = 0.f;
    const float* lo = lstm_out + ((size_t)b*30 + s)*512;
#pragma unroll
    for (int h = lane; h < 512; h += 64) acc += lo[h]*ush[h]*W3[h];
#pragma unroll
    for (int off = 32; off; off >>= 1) acc += __shfl_down(acc, off);
    if (lane == 0) sc[s] = acc;
  }
  // kernel-choice logits (waves 0..8, one m each)
  if (wave < 9) {
    float acc = 0.f;
#pragma unroll
    for (int k = lane; k < 512; k += 64) acc += ush[k]*Wmod[k*9+wave];
#pragma unroll
    for (int off = 32; off; off >>= 1) acc += __shfl_down(acc, off);
    if (lane == 0) wl[wave] = acc;
  }
  __syncthreads();
  if (tid == 0) {
    float mx = wl[0];
    for (int m = 1; m < 9; ++m) mx = fmaxf(mx, wl[m]);
    float s = 0.f;
    for (int m = 0; m < 9; ++m) s += fexp(wl[m]-mx);
    float ls = logf(s);
    float ent = 0.f;
    for (int m = 0; m < 9; ++m) {
      float l = wl[m]-mx-ls;
      float w = fexp(l);
      woutAll[t*576 + b*9 + m] = w;
      ent -= w*l;
    }
    imp_part[t*64+b] = ent;
  }
  if (wave == 1) {
    float v = (lane < 30) ? sc[lane] : -3.4e38f;
    float mx = v;
#pragma unroll
    for (int off = 32; off; off >>= 1) mx = fmaxf(mx, __shfl_xor(mx, off));
    float e = (lane < 30) ? fexp(v-mx) : 0.f;
    float ssum = e;
#pragma unroll
    for (int off = 32; off; off >>= 1) ssum += __shfl_xor(ssum, off);
    if (lane < 30) at[lane] = e/ssum;
  }
  __syncthreads();
  // context: 2-way s-split per h
  {
    int h = tid & 511, seg = tid >> 9;
    float acc = 0.f;
    int s0 = seg ? 15 : 0, s1 = seg ? 30 : 15;
    for (int s = s0; s < s1; ++s) acc += at[s]*lstm_out[((size_t)b*30 + s)*512 + h];
    if (seg) cpart[h] = acc;
    __syncthreads();
    if (!seg) {
      float tot = acc + cpart[h];
      cout[b*512+h] = tot;
      sC[h] = tot;
    }
  }
  __syncthreads();
  // tmap = c @ t2m + b  (pair-packed bf16; 4-way k-split)
  {
    int c2 = tid & 255, ks = tid >> 8;   // ks in 0..3
    float a0 = 0.f, a1 = 0.f;
    const unsigned* tp = t2pp + c2;
#pragma unroll 8
    for (int k = ks*128; k < ks*128 + 128; ++k) {
      float cv = sC[k];
      unsigned wv2 = tp[(size_t)k*256];
      a0 += cv*blo(wv2);
      a1 += cv*bhi(wv2);
    }
    tpart[ks][c2]       = a0;
    tpart[ks][256 + c2] = a1;
  }
  __syncthreads();
  if (tid < 512) {
    float v = tpart[0][tid] + tpart[1][tid] + tpart[2][tid] + tpart[3][tid];
    tmapv[b*512 + tid] = v + t2mb[tid];
  }
}

// ---------------------------------------------------------------------------
// fused modules + pooled partials + stack update + pvec ping-pong
// PLUS (blockIdx.y==19): next-t u-GEMM, 64 blocks, proper 4-way k-split —
// runs concurrently with the 1216 modules blocks (round-6 lesson: the fused
// work must keep its parallel decomposition; 64-block full-K GEMV was 7.8us).
// grid (64 b, 20).
// ---------------------------------------------------------------------------
__global__ __launch_bounds__(256)
void modu_k(const unsigned short* __restrict__ imapB, const float* __restrict__ tmapv,
            float* __restrict__ stack, const float* __restrict__ pvecIn,
            float* __restrict__ pvecOut,
            const float* __restrict__ swb, const float* __restrict__ c3w,
            const float* __restrict__ c3b, const float* __restrict__ c4w,
            const float* __restrict__ c4b, const float* __restrict__ wmod,
            float* __restrict__ plt,
            const float* __restrict__ tmp1n, const float* __restrict__ cprevB,
            const unsigned short* __restrict__ w2bp, const float* __restrict__ W2b,
            float* __restrict__ ubuf, int do_u)
{
  int pb = blockIdx.y;
  int lane = threadIdx.x & 63, wave = threadIdx.x >> 6;
  __shared__ float sT[512];
  __shared__ float pv[8], pd[8], wm[9];
  __shared__ float wpart[4][2][512];
  if (pb == 19) {
    // ---- u(t+1) = [tmp1n | cprev] @ W2(bf16) + W2b ----
    if (!do_u) return;
    const int x = blockIdx.x;
    const int r0 = (x >> 3) * 8, nc0 = (x & 7) * 64;
    const int kg0 = wave * 256;                         // global W2 row base
    const float* src = (wave < 2) ? tmp1n : cprevB;
    const int kb2 = (wave & 1) * 256;                   // base within src
    float acc[8] = {0,0,0,0,0,0,0,0};
    const unsigned short* Bp = w2bp + (size_t)kg0*512 + nc0 + lane;
    const float* As0 = src + (size_t)r0*512 + kb2;
#pragma unroll 4
    for (int kk = 0; kk < 256; ++kk) {
      float bv = bl(Bp[(size_t)kk*512]);
#pragma unroll
      for (int r = 0; r < 8; ++r) acc[r] += As0[(size_t)r*512 + kk] * bv;
    }
    float (*prt)[8][64] = (float(*)[8][64])wpart;       // 8KB slice of wpart
#pragma unroll
    for (int r = 0; r < 8; ++r) prt[wave][r][lane] = acc[r];
    __syncthreads();
    {
      int r = threadIdx.x >> 6, c = lane;
#pragma unroll
      for (int p2 = 0; p2 < 2; ++p2) {
        int rr = r + p2*4;
        float s2 = prt[0][rr][c] + prt[1][rr][c] + prt[2][rr][c] + prt[3][rr][c];
        ubuf[(size_t)(r0 + rr)*512 + nc0 + c] = s2 + W2b[nc0 + c];
      }
    }
    return;
  }
  int b = blockIdx.x;
  for (int j = threadIdx.x; j < 512; j += 256) sT[j] = tmapv[b*512 + j];
  if (threadIdx.x < 8) pv[threadIdx.x] = pvecIn[b*8+threadIdx.x];
  if (threadIdx.x >= 64 && threadIdx.x < 73) wm[threadIdx.x-64] = wmod[b*9 + threadIdx.x-64];
  __syncthreads();
  if (threadIdx.x < 8) {
    int l = threadIdx.x;
    pd[l] = (l < 7 ? pv[l+1] : 0.f) + (l == 0 ? pv[0] : 0.f);
  }
  __syncthreads();
  if (pb == 0 && threadIdx.x < 8) {
    int l = threadIdx.x;
    float WP = wm[0]+wm[1]+wm[2]+wm[3] + wm[6] + wm[8];
    float WD = wm[4]+wm[5] + wm[7];
    pvecOut[b*8+l] = WP*pv[l] + WD*pd[l];
  }

  float W[8][6];
#pragma unroll
  for (int m = 0; m < 8; ++m)
#pragma unroll
    for (int i = 0; i < 6; ++i) W[m][i] = swb[m*6+i];
  float W03 = wm[0]+wm[1]+wm[2]+wm[3];
  float W45 = wm[4]+wm[5];

  float acc6[8], acc7[8];
#pragma unroll
  for (int i = 0; i < 8; ++i) { acc6[i] = 0.f; acc7[i] = 0.f; }

  for (int pi = 0; pi < 2; ++pi) {
    int p = pb*8 + wave*2 + pi;
    if (p < 150) {
      const float* st = stack + ((size_t)b*150 + p)*8;
      float a = 0.f, av2 = 0.f;
#pragma unroll
      for (int l = 0; l < 8; ++l) { float v = st[l]; a += v*pv[l]; av2 += v*pd[l]; }
      float part[6] = {0,0,0,0,0,0};
#pragma unroll 2
      for (int i = 0; i < 8; ++i) {
        int d = i*64 + lane;
        float x = bl(imapB[((size_t)b*150 + p)*512 + d]);
        float t = sT[d];
#pragma unroll
        for (int m = 0; m < 4; ++m) {
          float c1 = W[m][0]*t + W[m][1] + W[m][4] + (W[m][2] + W[m][3]*t)*a;
          float c0 = W[m][1]*t + W[m][5]*t*a;
          part[m] += elu_(c1*x + c0) * c3w[m*512+d];
        }
#pragma unroll
        for (int m = 0; m < 2; ++m) {
          float c1 = W[4+m][0]*t + W[4+m][1] + W[4+m][2]*a + W[4+m][3]*av2
                   + W[4+m][4]*a*av2 + W[4+m][5]*t*(a+av2);
          part[4+m] += elu_(c1*x + W[4+m][1]*t) * c4w[m*512+d];
        }
        float c16 = W[6][0]*t + W[6][1] + W[6][4] + (W[6][2] + W[6][3]*t)*a;
        float c06 = W[6][1]*t + W[6][5]*t*a;
        acc6[i] += elu_(c16*x + c06);
        float c17 = W[7][0]*t + W[7][1] + W[7][2]*a + W[7][3]*av2
                  + W[7][4]*a*av2 + W[7][5]*t*(a+av2);
        acc7[i] += elu_(c17*x + W[7][1]*t);
      }
#pragma unroll
      for (int m = 0; m < 6; ++m) {
#pragma unroll
        for (int off = 32; off; off >>= 1) part[m] += __shfl_down(part[m], off);
        part[m] = __shfl(part[m], 0);
      }
      float r3  = wm[0]*(part[0]+c3b[0]) + wm[1]*(part[1]+c3b[1])
                + wm[2]*(part[2]+c3b[2]) + wm[3]*(part[3]+c3b[3]);
      float r45 = wm[4]*(part[4]+c4b[0]) + wm[5]*(part[5]+c4b[1]);
      if (lane < 8) {
        int l = lane;
        size_t idx = ((size_t)b*150 + p)*8 + l;
        stack[idx] = stack[idx]*(1.f - W03*pv[l] - W45*pd[l])
                   + pv[l]*r3 + pd[l]*r45;
      }
    }
  }
#pragma unroll
  for (int i = 0; i < 8; ++i) {
    wpart[wave][0][i*64+lane] = acc6[i];
    wpart[wave][1][i*64+lane] = acc7[i];
  }
  __syncthreads();
  for (int e = threadIdx.x; e < 1024; e += 256) {
    int which = e >> 9, d = e & 511;
    float s = wpart[0][which][d] + wpart[1][which][d]
            + wpart[2][which][d] + wpart[3][which][d];
    atomicAdd(&plt[(size_t)which*32768 + b*512 + d], s * (1.f/150.f));
  }
}

// ---------------------------------------------------------------------------
// batched m67 GEMMs for ALL t: grid (8 colchunks, 8 rowchunks, 18).
// z = t*2+zz: m67t[z] = [pl[t][zz] | tmapv[t]] @ ansW[zz] + ansb[zz]
// ---------------------------------------------------------------------------
__global__ __launch_bounds__(512)
void ansall_k(const float* __restrict__ plt, const float* __restrict__ tmapv,
              const unsigned short* __restrict__ answp, const float* __restrict__ ansb,
              float* __restrict__ m67o)
{
  const int z = blockIdx.z;          // 0..17
  const int t = z >> 1, zz = z & 1;
  __shared__ __align__(16) float As[8][1024];
  __shared__ float part[8][8][64];
  const int tid = threadIdx.x;
  const int r0 = blockIdx.y*8;
  const int nc0 = blockIdx.x*64;
  const int lane = tid & 63, w = tid >> 6;

  for (int e4 = tid; e4 < 1024; e4 += 512) {
    int r = e4 >> 7, k4 = (e4 & 127) << 2;
    *(float4*)&As[r][k4]     = *(const float4*)&plt[(size_t)z*32768 + (size_t)(r0+r)*512 + k4];
    *(float4*)&As[r][512+k4] = *(const float4*)&tmapv[(size_t)t*32768 + (size_t)(r0+r)*512 + k4];
  }
  __syncthreads();
  {
    const unsigned short* Bp = answp + (size_t)zz*524288
                             + (size_t)(w*128)*512 + nc0 + lane;
    float acc[8] = {0,0,0,0,0,0,0,0};
    int k0 = w*128;
#pragma unroll 8
    for (int kk = 0; kk < 128; ++kk) {
      float bv = bl(Bp[(size_t)kk*512]);
#pragma unroll
      for (int r = 0; r < 8; ++r) acc[r] += As[r][k0+kk]*bv;
    }
#pragma unroll
    for (int r = 0; r < 8; ++r) part[w][r][lane] = acc[r];
  }
  __syncthreads();
  {
    int r = tid >> 6, c = tid & 63;
    float s = 0.f;
#pragma unroll
    for (int w2 = 0; w2 < 8; ++w2) s += part[w2][r][c];
    m67o[(size_t)z*32768 + (size_t)(r0+r)*512 + nc0 + c] = s + ansb[zz*512 + nc0 + c];
  }
}

// ---------------------------------------------------------------------------
// final mem: mem_8 = sum_t coef_t*(w6_t*m6_t + w7_t*m7_t),
// coef_t = prod_{s>t} (1-w6_s-w7_s).  (mem_init = 0)
// ---------------------------------------------------------------------------
__global__ __launch_bounds__(512)
void memfin_k(const float* __restrict__ woutAll, const float* __restrict__ m67t,
              float* __restrict__ memb)
{
  int b = blockIdx.x;
  int tid = threadIdx.x;
  __shared__ float w6s[9], w7s[9], coef[9];
  if (tid < 9)       w6s[tid] = woutAll[tid*576 + b*9 + 6];
  else if (tid < 18) w7s[tid-9] = woutAll[(tid-9)*576 + b*9 + 7];
  __syncthreads();
  if (tid == 0) {
    float c = 1.f;
    for (int t = 8; t >= 0; --t) { coef[t] = c; c *= (1.f - w6s[t] - w7s[t]); }
  }
  __syncthreads();
  float acc = 0.f;
#pragma unroll
  for (int t = 0; t < 9; ++t) {
    float m6 = m67t[(((size_t)t*2 + 0)*64 + b)*512 + tid];
    float m7 = m67t[(((size_t)t*2 + 1)*64 + b)*512 + tid];
    acc += coef[t]*(w6s[t]*m6 + w7s[t]*m7);
  }
  memb[b*512 + tid] = acc;
}

// ---------------------------------------------------------------------------
__global__ __launch_bounds__(256)
void imp_k(const float* __restrict__ part, float* __restrict__ out)
{
  int lane = threadIdx.x & 63, wave = threadIdx.x >> 6;
  float acc = 0.f;
  for (int i = threadIdx.x; i < 576; i += 256) acc += part[i];
#pragma unroll
  for (int off = 32; off; off >>= 1) acc += __shfl_down(acc, off);
  __shared__ float red[4];
  if (lane == 0) red[wave] = acc;
  __syncthreads();
  if (threadIdx.x == 0) out[0] = red[0]+red[1]+red[2]+red[3];
}

// ---------------------------------------------------------------------------
extern "C" void kernel_launch(void* const* d_in, const int* in_sizes, int n_in,
                              void* d_out, int out_size, void* d_ws, size_t ws_size,
                              hipStream_t stream)
{
  (void)in_sizes; (void)n_in; (void)out_size; (void)ws_size;
  const float* image = (const float*)d_in[0];
  const int*   ques  = (const int*)d_in[1];
  const int*   qlen  = (const int*)d_in[2];
  const float* embedW= (const float*)d_in[3];
  const float* Wi_f  = (const float*)d_in[4];
  const float* Wh_f  = (const float*)d_in[5];
  const float* b_f   = (const float*)d_in[6];
  const float* Wi_b  = (const float*)d_in[7];
  const float* Wh_b  = (const float*)d_in[8];
  const float* b_b   = (const float*)d_in[9];
  const float* W1    = (const float*)d_in[10];
  const float* b1    = (const float*)d_in[11];
  const float* W2w   = (const float*)d_in[12];
  const float* W2b   = (const float*)d_in[13];
  const float* W3    = (const float*)d_in[14];
  const float* c0    = (const float*)d_in[15];
  const float* Wmod  = (const float*)d_in[16];
  const float* ic1w  = (const float*)d_in[17];
  const float* ic1b  = (const float*)d_in[18];
  const float* ic2w  = (const float*)d_in[19];
  const float* ic2b  = (const float*)d_in[20];
  const float* i2mw  = (const float*)d_in[21];
  const float* i2mb  = (const float*)d_in[22];
  const float* t2mw  = (const float*)d_in[23];
  const float* t2mb  = (const float*)d_in[24];
  const float* c3ow  = (const float*)d_in[25];
  const float* c3cw  = (const float*)d_in[26];
  const float* c3cb  = (const float*)d_in[27];
  const float* c4ow  = (const float*)d_in[28];
  const float* c4cw  = (const float*)d_in[29];
  const float* c4cb  = (const float*)d_in[30];
  const float* aow   = (const float*)d_in[31];
  const float* ansW  = (const float*)d_in[32];
  const float* ansb  = (const float*)d_in[33];
  const float* o1w   = (const float*)d_in[34];
  const float* o1b   = (const float*)d_in[35];
  const float* o2w   = (const float*)d_in[36];
  const float* o2b   = (const float*)d_in[37];
  float* out = (float*)d_out;
  float* ws  = (float*)d_ws;

  size_t off = 0;
  auto alloc = [&](size_t n){ float* p = ws + off; off += n; return p; };
  short* imgP  = (short*)alloc(600ull*20*64*8/2);
  short* X1p   = (short*)alloc(600ull*16*64*8/2);
  short* X2p   = (short*)alloc(600ull*16*64*8/2);
  short* w1p   = (short*)alloc(20*32*64*8/2);
  short* w2mp  = (short*)alloc(16*32*64*8/2);
  short* w3mp  = (short*)alloc(16*32*64*8/2);
  short* wifp  = (short*)alloc(10*64*64*8/2);
  short* wibp  = (short*)alloc(10*64*64*8/2);
  short* embp  = (short*)alloc(120ull*10*64*8/2);
  unsigned short* imapB = (unsigned short*)alloc(9600ull*512/2);
  unsigned* t2pp = (unsigned*)alloc(512*256);
  unsigned short* w2bp  = (unsigned short*)alloc(524288/2);
  unsigned short* answp = (unsigned short*)alloc(1048576/2);
  float* xWfb  = alloc(64ull*30*1024);
  float* xWbb  = alloc(64ull*30*1024);
  float* lout  = alloc(64ull*30*512);
  float* qbuf  = alloc(64*512);
  float* stck  = alloc(64*150*8);
  float* pvecA = alloc(64*8);
  float* pvecB = alloc(64*8);
  float* memb  = alloc(64*512);
  float* cprev = alloc(64*512);
  float* tmp1a = alloc(9ull*64*512);
  float* ubuf  = alloc(64*512);
  float* wmwA  = alloc(9*64*9);
  float* impp  = alloc(9*64);
  float* swb   = alloc(48);
  float* pl    = alloc(9ull*2*64*512);
  float* m67t  = alloc(9ull*2*64*512);
  float* tmapv = alloc(9ull*64*512);
  float* h1b   = alloc(64*1024);
  unsigned* whT = (unsigned*)alloc(2ull*1024*128);       // f16-pair packed Wh^T
  float* hbufW  = alloc(32768);                          // 2 ping x 2 d x 4 g x 16 x 256 f16
  int*   flagsI = (int*)alloc(256);                      // step sync flags

  // one dispatch: init + ALL independent packs (incl. f16 WhT, bf16 W2/ansW)
  megapack_k<<<12036, 256, 0, stream>>>(
      c0, c3ow, c4ow, aow, stck, pvecA, memb, cprev, swb, pl,
      Wh_f, Wh_b, whT, hbufW, flagsI,
      ic1w, w1p, ic2w, w2mp, i2mw, w3mp, Wi_f, wifp, Wi_b, wibp,
      image, imgP, embedW, ques, embp, t2mw, t2pp,
      W2w, w2bp, ansW, answp);

  // conv chain (MFMA); conv3 -> bf16 row-major imapB
  gemmM_k<<<dim3(8,150,1), 256, 0, stream>>>(imgP, imgP, w1p, w1p, ic1b, ic1b,
                                             X1p, X1p, 20, 32, 512, 1, 1, 16);
  gemmM_k<<<dim3(8,150,1), 256, 0, stream>>>(X1p, X1p, w2mp, w2mp, ic2b, ic2b,
                                             X2p, X2p, 16, 32, 512, 1, 0, 16);
  gemmM_k<<<dim3(8,150,1), 256, 0, stream>>>(X2p, X2p, w3mp, w3mp, i2mb, i2mb,
                                             imapB, imapB, 16, 32, 512, 2, 0, 0);
  // both embed GEMMs in one launch
  gemmM_k<<<dim3(16,30,2), 256, 0, stream>>>(embp, embp, wifp, wibp, b_f, b_b,
                                             xWfb, xWbb, 10, 64, 1024, 0, 0, 0);

  // MFMA LSTM: 32 persistent blocks, LDS weights, round-4 flag protocol
  lstmM_k<<<32, 256, 0, stream>>>(xWfb, xWbb, whT, qlen,
                                  (unsigned long long*)hbufW, flagsI, lout, qbuf);

  // tmp1all[t] = q @ W1[t] + b1 (all 9 t)
  gemm64b_k<<<dim3(8,8,9), 512, 0, stream>>>(
      qbuf, 0, 9, (const float*)nullptr, 0,
      W1, 262144, b1, 0, tmp1a, 32768, 512, 0);
  // u for t=0 (fp32 W2)
  gemm64b_k<<<dim3(8,8,1), 512, 0, stream>>>(
      tmp1a, 0, 9, cprev, 512, W2w, 0, W2b, 0, ubuf, 0, 512, 0);

  for (int t = 0; t < 9; ++t) {
    float* pvIn  = (t & 1) ? pvecB : pvecA;
    float* pvOut = (t & 1) ? pvecA : pvecB;
    kcattn3_k<<<64, 1024, 0, stream>>>(ubuf, Wmod, lout, W3, t2pp, t2mb,
                                       wmwA, impp, cprev,
                                       tmapv + (size_t)t*32768, t);
    modu_k<<<dim3(64,20), 256, 0, stream>>>(
        imapB, tmapv + (size_t)t*32768, stck, pvIn, pvOut, swb,
        c3cw, c3cb, c4cw, c4cb,
        wmwA + (size_t)t*576, pl + (size_t)t*65536,
        tmp1a + (size_t)(t < 8 ? t+1 : 0)*32768, cprev, w2bp, W2b, ubuf,
        (t < 8) ? 1 : 0);
  }

  // all 18 m67 GEMMs in ONE dispatch (off the sequential critical path)
  ansall_k<<<dim3(8,8,18), 512, 0, stream>>>(pl, tmapv, answp, ansb, m67t);

  // final mem blend, then h1 = elu([q, mem] @ out1 + b); logits = h1 @ out2 + b
  memfin_k<<<64, 512, 0, stream>>>(wmwA, m67t, memb);
  gemm64b_k<<<dim3(16,8,1), 512, 0, stream>>>(
      qbuf, 0, 9, memb, 512, o1w, 0, o1b, 0, h1b, 0, 1024, 1);
  gemm64b_k<<<dim3(1,8,1), 512, 0, stream>>>(
      h1b, 0, 10, (const float*)nullptr, 0, o2w, 0, o2b, 0, out, 0, 32, 0);
  imp_k<<<1, 256, 0, stream>>>(impp, out + 2048);
}

// Round 8
// 833.579 us; speedup vs baseline: 1.1369x; 1.0856x over previous
//
#include <hip/hip_runtime.h>
#include <hip/hip_fp16.h>
#include <math.h>

#define DEV __device__ __forceinline__

DEV float fexp(float x){ return __expf(x); }
DEV float elu_(float x){ return x > 0.f ? x : fexp(x) - 1.f; }
DEV float sigm_(float x){ return 1.f/(1.f + fexp(-x)); }
DEV float tanh_(float x){ float e = fexp(2.f*x); return 1.f - 2.f/(e + 1.f); }
DEV unsigned bf16r(float x){ unsigned u = __float_as_uint(x);
  return (u + 0x7fffu + ((u>>16)&1u)) >> 16; }
DEV float blo(unsigned u){ return __uint_as_float(u << 16); }
DEV float bhi(unsigned u){ return __uint_as_float(u & 0xffff0000u); }
DEV float bl(unsigned short u){ return __uint_as_float(((unsigned)u) << 16); }

using frag  = __attribute__((ext_vector_type(8))) short;     // 8 bf16 (4 VGPRs)
using fragh = __attribute__((ext_vector_type(8))) _Float16;  // 8 f16  (4 VGPRs)
using f32x4 = __attribute__((ext_vector_type(4))) float;     // MFMA acc

// coherent (sc0 sc1 = device-coherent path) 16B load WITH completion wait
DEV uint4 cload16w(const void* p){
  uint4 r;
  asm volatile("global_load_dwordx4 %0, %1, off sc0 sc1\n\ts_waitcnt vmcnt(0)"
               : "=v"(r) : "v"(p) : "memory");
  return r;
}
// coherent 16B load, NO wait (caller does one s_waitcnt vmcnt(0) for the batch)
DEV uint4 cload16nw(const void* p){
  uint4 r;
  asm volatile("global_load_dwordx4 %0, %1, off sc0 sc1"
               : "=v"(r) : "v"(p) : "memory");
  return r;
}

// ---------------------------------------------------------------------------
// device pack helpers
// ---------------------------------------------------------------------------
DEV void d_packB(const float* __restrict__ W, short* __restrict__ Bp,
                 int KC, int Ng, int Ksrc, int N, int trans, int idx)
{
  if (idx >= KC*Ng*64) return;
  int lane = idx & 63;
  int g    = (idx >> 6) % Ng;
  int kc   = idx / (64*Ng);
  int n = g*16 + (lane & 15);
  int kb = kc*32 + ((lane >> 4) << 3);
  unsigned o[4];
#pragma unroll
  for (int jj = 0; jj < 4; ++jj) {
    int k0 = kb + 2*jj;
    float v0 = (k0   < Ksrc) ? (trans ? W[(size_t)n*Ksrc + k0]   : W[(size_t)(k0)*N + n])   : 0.f;
    float v1 = (k0+1 < Ksrc) ? (trans ? W[(size_t)n*Ksrc + k0+1] : W[(size_t)(k0+1)*N + n]) : 0.f;
    o[jj] = bf16r(v0) | (bf16r(v1) << 16);
  }
  *(uint4*)(Bp + (size_t)idx*8) = make_uint4(o[0], o[1], o[2], o[3]);
}

DEV void d_packImg(const float* __restrict__ image, short* __restrict__ Ap, int idx)
{
  int lane = idx & 63;
  int kc   = (idx >> 6) % 20;
  int mt   = idx / 1280;
  int row = mt*16 + (lane & 15);
  int b = row / 150, p = row % 150;
  int cb = kc*32 + ((lane >> 4) << 3);
  unsigned o[4];
#pragma unroll
  for (int jj = 0; jj < 4; ++jj) {
    float v0 = image[((size_t)b*640 + cb + 2*jj    )*150 + p];
    float v1 = image[((size_t)b*640 + cb + 2*jj + 1)*150 + p];
    o[jj] = bf16r(v0) | (bf16r(v1) << 16);
  }
  *(uint4*)(Ap + (size_t)idx*8) = make_uint4(o[0], o[1], o[2], o[3]);
}

DEV void d_packEmb(const float* __restrict__ embedW, const int* __restrict__ ques,
                   short* __restrict__ Ap, int idx)
{
  int lane = idx & 63;
  int kc   = (idx >> 6) % 10;
  int mt   = idx / 640;
  int row = mt*16 + (lane & 15);
  int q = ques[row];
  int kb = kc*32 + ((lane >> 4) << 3);
  unsigned o[4];
#pragma unroll
  for (int jj = 0; jj < 4; ++jj) {
    int k0 = kb + 2*jj;
    float v0 = (k0   < 300) ? embedW[(size_t)q*300 + k0]   : 0.f;
    float v1 = (k0+1 < 300) ? embedW[(size_t)q*300 + k0+1] : 0.f;
    o[jj] = bf16r(v0) | (bf16r(v1) << 16);
  }
  *(uint4*)(Ap + (size_t)idx*8) = make_uint4(o[0], o[1], o[2], o[3]);
}

// ---------------------------------------------------------------------------
// ONE dispatch for all independent pre-stage work
// ---------------------------------------------------------------------------
__global__ __launch_bounds__(256)
void megapack_k(const float* __restrict__ c0, const float* __restrict__ c3ow,
                const float* __restrict__ c4ow, const float* __restrict__ aow,
                float* __restrict__ stack, float* __restrict__ pvecA,
                float* __restrict__ mem, float* __restrict__ cprev,
                float* __restrict__ swb, float* __restrict__ pl,
                const float* __restrict__ Whf, const float* __restrict__ Whb,
                unsigned* __restrict__ whT,
                float* __restrict__ hbufz, int* __restrict__ flagz,
                const float* __restrict__ ic1w, short* __restrict__ w1p,
                const float* __restrict__ ic2w, short* __restrict__ w2mp,
                const float* __restrict__ i2mw, short* __restrict__ w3mp,
                const float* __restrict__ Wif, short* __restrict__ wifp,
                const float* __restrict__ Wib, short* __restrict__ wibp,
                const float* __restrict__ image, short* __restrict__ imgP,
                const float* __restrict__ embedW, const int* __restrict__ ques,
                short* __restrict__ embp,
                const float* __restrict__ t2mw, unsigned* __restrict__ t2pp,
                const float* __restrict__ W2w, unsigned short* __restrict__ w2bp,
                const float* __restrict__ ansW, unsigned short* __restrict__ answp)
{
  const int bx = blockIdx.x, tid = threadIdx.x;
  if (bx < 320) {
    int idx = bx*256 + tid;
    int stride = 320*256;
    for (int i = idx; i < 64*150*8; i += stride) stack[i] = 0.f;
    for (int i = idx; i < 64*8;    i += stride) pvecA[i] = ((i & 7) == 0) ? 1.f : 0.f;
    for (int i = idx; i < 64*512;  i += stride) mem[i] = 0.f;
    for (int i = idx; i < 64*512;  i += stride) cprev[i] = c0[i & 511];
    for (int i = idx; i < 9*2*64*512; i += stride) pl[i] = 0.f;
    for (int i = idx; i < 32768;   i += stride) hbufz[i] = 0.f;  // hbuf (f16 pairs)
    if (idx < 256) flagz[idx] = 0;                               // sync flags
    if (idx < 8) {
      const float* ow = (idx < 4) ? (c3ow + idx*6)
                      : (idx < 6) ? (c4ow + (idx-4)*6)
                                  : (aow  + (idx-6)*6);
      float mx = ow[0];
      for (int m = 1; m < 6; ++m) mx = fmaxf(mx, ow[m]);
      float e[6]; float s = 0.f;
      for (int m = 0; m < 6; ++m) { e[m] = fexp(ow[m]-mx); s += e[m]; }
      for (int m = 0; m < 6; ++m) swb[idx*6+m] = e[m]/s;
    }
  } else if (bx < 1344) {
    // WhT: [d][zc 0..1023][k-pair 0..127] packed f16 pairs (transposed Wh)
    int idx = (bx-320)*256 + tid;
    int dd  = idx >> 17;
    int rem = idx & 131071;
    int kp  = rem >> 10;
    int zc  = rem & 1023;
    const float* Wh = dd ? Whb : Whf;
    __half2 hv = __floats2half2_rn(Wh[(size_t)(2*kp)*1024 + zc],
                                   Wh[(size_t)(2*kp+1)*1024 + zc]);
    whT[((size_t)dd << 17) + (zc << 7) + kp] = *(unsigned*)&hv;
  } else if (bx < 1504) {
    d_packB(ic1w, w1p, 20, 32, 640, 512, 1, (bx-1344)*256 + tid);
  } else if (bx < 1632) {
    d_packB(ic2w, w2mp, 16, 32, 512, 512, 1, (bx-1504)*256 + tid);
  } else if (bx < 1760) {
    d_packB(i2mw, w3mp, 16, 32, 512, 512, 1, (bx-1632)*256 + tid);
  } else if (bx < 1920) {
    d_packB(Wif, wifp, 10, 64, 300, 1024, 0, (bx-1760)*256 + tid);
  } else if (bx < 2080) {
    d_packB(Wib, wibp, 10, 64, 300, 1024, 0, (bx-1920)*256 + tid);
  } else if (bx < 5080) {
    d_packImg(image, imgP, (bx-2080)*256 + tid);
  } else if (bx < 5380) {
    d_packEmb(embedW, ques, embp, (bx-5080)*256 + tid);
  } else if (bx < 5892) {
    int idx = (bx-5380)*256 + tid;   // 512*256
    int k = idx >> 8, c = idx & 255;
    t2pp[idx] = bf16r(t2mw[(size_t)k*512 + c]) | (bf16r(t2mw[(size_t)k*512 + 256 + c]) << 16);
  } else if (bx < 7940) {
    int i = (bx-5892)*256 + tid;     // 524288
    w2bp[i] = (unsigned short)bf16r(W2w[i]);
  } else {
    int i = (bx-7940)*256 + tid;     // 1048576
    answp[i] = (unsigned short)bf16r(ansW[i]);
  }
}

// ---------------------------------------------------------------------------
// MFMA GEMM, dual problem sets via blockIdx.z.
// mode 0: fp32 row-major; mode 1: bf16 A-pack; mode 2: bf16 row-major
// ---------------------------------------------------------------------------
__global__ __launch_bounds__(256)
void gemmM_k(const short* __restrict__ ApA, const short* __restrict__ ApB,
             const short* __restrict__ BpA, const short* __restrict__ BpB,
             const float* __restrict__ biasA, const float* __restrict__ biasB,
             void* __restrict__ CoutA, void* __restrict__ CoutB,
             int KC, int Ng, int N, int mode, int act, int KCout)
{
  __shared__ float lds[4][16][68];
  const int z = blockIdx.z;
  const short* Ap = z ? ApB : ApA;
  const short* Bp = z ? BpB : BpA;
  const float* bias = z ? biasB : biasA;
  void* Cout = z ? CoutB : CoutA;
  const int tid = threadIdx.x, lane = tid & 63, w = tid >> 6;
  const int mt = blockIdx.y*4 + w;
  const int ncol0 = blockIdx.x*64;
  const short* Abase = Ap + (((size_t)mt*KC) << 9) + lane*8;
  const short* Bbase = Bp + (((size_t)blockIdx.x*4) << 9) + lane*8;
  f32x4 acc0 = {0.f,0.f,0.f,0.f}, acc1 = acc0, acc2 = acc0, acc3 = acc0;
#pragma unroll 2
  for (int kc = 0; kc < KC; ++kc) {
    frag a = *(const frag*)(Abase + ((size_t)kc << 9));
    const short* bk = Bbase + (((size_t)kc*Ng) << 9);
    frag b0 = *(const frag*)(bk);
    frag b1 = *(const frag*)(bk + 512);
    frag b2 = *(const frag*)(bk + 1024);
    frag b3 = *(const frag*)(bk + 1536);
    acc0 = __builtin_amdgcn_mfma_f32_16x16x32_bf16(a, b0, acc0, 0, 0, 0);
    acc1 = __builtin_amdgcn_mfma_f32_16x16x32_bf16(a, b1, acc1, 0, 0, 0);
    acc2 = __builtin_amdgcn_mfma_f32_16x16x32_bf16(a, b2, acc2, 0, 0, 0);
    acc3 = __builtin_amdgcn_mfma_f32_16x16x32_bf16(a, b3, acc3, 0, 0, 0);
  }
  {
    int colb = lane & 15, rowb = (lane >> 4)*4;
#pragma unroll
    for (int r = 0; r < 4; ++r) {
      lds[w][rowb+r][ 0+colb] = acc0[r];
      lds[w][rowb+r][16+colb] = acc1[r];
      lds[w][rowb+r][32+colb] = acc2[r];
      lds[w][rowb+r][48+colb] = acc3[r];
    }
  }
  __syncthreads();
  if (mode == 0) {
    float* C = (float*)Cout;
    int mloc = lane >> 2, q4 = lane & 3;
    size_t rowoff = (size_t)(mt*16 + mloc)*N + ncol0 + q4*16;
#pragma unroll
    for (int i = 0; i < 4; ++i) {
      float4 v = *(float4*)&lds[w][mloc][q4*16 + i*4];
      const float* bp = bias + ncol0 + q4*16 + i*4;
      v.x += bp[0]; v.y += bp[1]; v.z += bp[2]; v.w += bp[3];
      if (act) { v.x = elu_(v.x); v.y = elu_(v.y); v.z = elu_(v.z); v.w = elu_(v.w); }
      *(float4*)&C[rowoff + i*4] = v;
    }
  } else if (mode == 1) {
    short* C = (short*)Cout;
    int m = lane & 15, qb = (lane >> 4)*8;
#pragma unroll
    for (int h = 0; h < 2; ++h) {
      int nl = h*32 + qb;
      unsigned o[4];
#pragma unroll
      for (int jj = 0; jj < 4; ++jj) {
        float v0 = lds[w][m][nl + 2*jj]     + bias[ncol0 + nl + 2*jj];
        float v1 = lds[w][m][nl + 2*jj + 1] + bias[ncol0 + nl + 2*jj + 1];
        if (act) { v0 = elu_(v0); v1 = elu_(v1); }
        o[jj] = bf16r(v0) | (bf16r(v1) << 16);
      }
      *(uint4*)(C + (((size_t)mt*KCout + (ncol0 >> 5) + h) << 9) + lane*8)
          = make_uint4(o[0], o[1], o[2], o[3]);
    }
  } else {
    unsigned short* C = (unsigned short*)Cout;
    int row = lane >> 2, cb = (lane & 3)*16;
#pragma unroll
    for (int h = 0; h < 2; ++h) {
      unsigned o[4];
#pragma unroll
      for (int jj = 0; jj < 4; ++jj) {
        float v0 = lds[w][row][cb + h*8 + 2*jj]     + bias[ncol0 + cb + h*8 + 2*jj];
        float v1 = lds[w][row][cb + h*8 + 2*jj + 1] + bias[ncol0 + cb + h*8 + 2*jj + 1];
        if (act) { v0 = elu_(v0); v1 = elu_(v1); }
        o[jj] = bf16r(v0) | (bf16r(v1) << 16);
      }
      *(uint4*)&C[(size_t)(mt*16 + row)*N + ncol0 + cb + h*8]
          = make_uint4(o[0], o[1], o[2], o[3]);
    }
  }
}

// ---------------------------------------------------------------------------
// 64-row batch GEMM, K-split across waves
// ---------------------------------------------------------------------------
__global__ __launch_bounds__(512)
void gemm64b_k(const float* __restrict__ A1, long zA1, int K1log,
               const float* __restrict__ A2, int K2,
               const float* __restrict__ B, long zB,
               const float* __restrict__ bias, int zbias,
               float* __restrict__ C, long zC, int N, int act)
{
  const int K1 = 1 << K1log;
  const int Kt = K1 + K2;
  __shared__ __align__(16) float As[8][1024];
  __shared__ float part[8][8][64];
  const int tid = threadIdx.x;
  const int z = blockIdx.z;
  const int r0 = blockIdx.y*8;
  {
    const float* a1 = A1 + (size_t)z*zA1;
    const int nf4 = (8*K1) >> 2;
    for (int e4 = tid; e4 < nf4; e4 += 512) {
      int r = e4 >> (K1log-2);
      int k4 = (e4 & ((K1>>2)-1)) << 2;
      *(float4*)&As[r][k4] = *(const float4*)&a1[(size_t)(r0+r)*K1 + k4];
    }
    if (K2 > 0) {
      for (int e4 = tid; e4 < 1024; e4 += 512) {
        int r = e4 >> 7;
        int k4 = (e4 & 127) << 2;
        *(float4*)&As[r][K1+k4] = *(const float4*)&A2[(size_t)(r0+r)*512 + k4];
      }
    }
  }
  __syncthreads();
  const int lane = tid & 63, w = tid >> 6;
  const int n = blockIdx.x*64 + lane;
  const bool nv = n < N;
  const int kseg = Kt >> 3;
  const int k0 = w*kseg;
  const float* Bp = B + (size_t)z*zB + (size_t)k0*N + (nv ? n : 0);
  float acc[8] = {0,0,0,0,0,0,0,0};
#pragma unroll 8
  for (int kk = 0; kk < kseg; ++kk) {
    float bv = nv ? Bp[(size_t)kk*N] : 0.f;
    int k = k0 + kk;
#pragma unroll
    for (int r = 0; r < 8; ++r) acc[r] += As[r][k]*bv;
  }
#pragma unroll
  for (int r = 0; r < 8; ++r) part[w][r][lane] = acc[r];
  __syncthreads();
  {
    int r = tid >> 6, c = tid & 63;
    int nn = blockIdx.x*64 + c;
    if (nn < N) {
      float s = 0.f;
#pragma unroll
      for (int w2 = 0; w2 < 8; ++w2) s += part[w2][r][c];
      s += bias ? bias[(size_t)z*zbias + nn] : 0.f;
      if (act == 1) s = elu_(s);
      C[(size_t)z*zC + (size_t)(r0+r)*N + nn] = s;
    }
  }
}

// ---------------------------------------------------------------------------
// MFMA bidirectional masked LSTM (round-4 protocol: LDS-resident weights,
// per-step flag sync over coherent atomics + pipelined sc0sc1 h loads).
// ---------------------------------------------------------------------------
__global__ __launch_bounds__(256)
void lstmM_k(const float* __restrict__ xWf, const float* __restrict__ xWb,
             const unsigned* __restrict__ whT, const int* __restrict__ qlen,
             unsigned long long* __restrict__ hbuf, int* __restrict__ flags,
             float* __restrict__ lstm_out, float* __restrict__ qout)
{
  const int bx = blockIdx.x;
  const int d = bx & 1, g = (bx >> 1) & 3, n = bx >> 3;
  const int tid = threadIdx.x, lane = tid & 63, w = tid >> 6;
  const int q = lane >> 4, cl = lane & 15;
  __shared__ __align__(16) unsigned short Wl[65536];   // 128 KiB

#pragma unroll 4
  for (int rb = 0; rb < 32; ++rb) {
    int lcrow = rb*8 + (tid >> 5);
    int gt = lcrow >> 6, c = lcrow & 63;
    int zc = gt*256 + n*64 + c;
    uint4 v = *(const uint4*)(whT + (((size_t)d*1024 + zc) << 7) + ((tid & 31) << 2));
    int byteoff = (lcrow << 9) + ((((tid & 31) << 4)) ^ ((lcrow & 7) << 4));
    *(uint4*)((char*)Wl + byteoff) = v;
  }

  const float* xW = d ? xWb : xWf;
  const int b   = g*16 + cl;                 // this lane's batch
  const int c4  = w*16 + q*4;                // local col base within slice
  const int hc4 = n*64 + c4;                 // global h-col base (4 consecutive)
  const int len = qlen[b];
  float cst[4] = {0.f,0.f,0.f,0.f}, hst[4] = {0.f,0.f,0.f,0.f};
  int* flg = flags + ((d*4 + g) << 2);       // 4 flags for this (d,g) group
  const int bofs = (cl & 7) << 4;
  __syncthreads();

  for (int ss = 0; ss < 30; ++ss) {
    const int s = d ? (29 - ss) : ss;
    const float* xr = xW + (size_t)b*30720 + (size_t)s*1024 + hc4;
    f32x4 xwv[4];
#pragma unroll
    for (int gt = 0; gt < 4; ++gt) xwv[gt] = *(const f32x4*)(xr + gt*256);

    if (ss > 0) {
      for (;;) {
        uint4 f4 = cload16w(flg);   // all 4 flags in ONE coherent 16B load
        if ((int)f4.x >= ss && (int)f4.y >= ss &&
            (int)f4.z >= ss && (int)f4.w >= ss) break;
      }
      __builtin_amdgcn_sched_barrier(0);
    }
    // B = h^T from hbuf: 8 pipelined coherent 16B loads, ONE vmcnt wait
    const char* hbr = (const char*)(hbuf + ((size_t)(((ss & 1)*2 + d)*4 + g) << 9))
                    + (cl << 9) + (q << 4);
    union { uint4 u; fragh f; } hv[8];
#pragma unroll
    for (int ks = 0; ks < 8; ++ks) hv[ks].u = cload16nw(hbr + (ks << 6));
    asm volatile("s_waitcnt vmcnt(0)" ::: "memory");
    __builtin_amdgcn_sched_barrier(0);

    f32x4 acc0 = {0.f,0.f,0.f,0.f}, acc1 = acc0, acc2 = acc0, acc3 = acc0;
#pragma unroll
    for (int ks = 0; ks < 8; ++ks) {
      const int kb = ((ks << 6) + (q << 4)) ^ bofs;
      const char* wb = (const char*)Wl + ((w*16 + cl) << 9) + kb;
      fragh a0 = *(const fragh*)(wb);
      fragh a1 = *(const fragh*)(wb + (64 << 9));
      fragh a2 = *(const fragh*)(wb + (128 << 9));
      fragh a3 = *(const fragh*)(wb + (192 << 9));
      acc0 = __builtin_amdgcn_mfma_f32_16x16x32_f16(a0, hv[ks].f, acc0, 0, 0, 0);
      acc1 = __builtin_amdgcn_mfma_f32_16x16x32_f16(a1, hv[ks].f, acc1, 0, 0, 0);
      acc2 = __builtin_amdgcn_mfma_f32_16x16x32_f16(a2, hv[ks].f, acc2, 0, 0, 0);
      acc3 = __builtin_amdgcn_mfma_f32_16x16x32_f16(a3, hv[ks].f, acc3, 0, 0, 0);
    }
    const bool m = s < len;
    f32x4 lo4;
    float hvv[4];
#pragma unroll
    for (int r = 0; r < 4; ++r) {
      float iv = acc0[r] + xwv[0][r];
      float fv = acc1[r] + xwv[1][r];
      float gv = acc2[r] + xwv[2][r];
      float o_ = acc3[r] + xwv[3][r];
      float cn = sigm_(fv)*cst[r] + sigm_(iv)*tanh_(gv);
      float hn = sigm_(o_)*tanh_(cn);
      float hk = m ? hn : hst[r];
      cst[r] = m ? cn : cst[r];
      hst[r] = hk;
      hvv[r] = hk;
      lo4[r] = m ? hn : 0.f;
    }
    unsigned long long* hbw = hbuf + ((size_t)((((ss & 1) ^ 1)*2 + d)*4 + g) << 9);
    union { unsigned long long u; __half2 h2[2]; } hp;
    hp.h2[0] = __floats2half2_rn(hvv[0], hvv[1]);
    hp.h2[1] = __floats2half2_rn(hvv[2], hvv[3]);
    __hip_atomic_store(hbw + cl*64 + (hc4 >> 2), hp.u,
                       __ATOMIC_RELAXED, __HIP_MEMORY_SCOPE_AGENT);
    *(f32x4*)(lstm_out + (((size_t)b*30 + s) << 9) + (d << 8) + hc4) = lo4;
    asm volatile("s_waitcnt vmcnt(0)" ::: "memory");
    __syncthreads();
    if (tid == 0)
      __hip_atomic_store(&flg[n], ss + 1, __ATOMIC_RELAXED, __HIP_MEMORY_SCOPE_AGENT);
  }
  *(f32x4*)(qout + ((size_t)b << 9) + (d << 8) + hc4) =
      f32x4{hst[0], hst[1], hst[2], hst[3]};
}

// ---------------------------------------------------------------------------
// fused kc + attn + tmap — 1024 threads (round-4 version, reads precomputed u)
// ---------------------------------------------------------------------------
__global__ __launch_bounds__(1024)
void kcattn3_k(const float* __restrict__ u, const float* __restrict__ Wmod,
               const float* __restrict__ lstm_out, const float* __restrict__ W3,
               const unsigned* __restrict__ t2pp, const float* __restrict__ t2mb,
               float* __restrict__ woutAll, float* __restrict__ imp_part,
               float* __restrict__ cout, float* __restrict__ tmapv, int t)
{
  int b = blockIdx.x;
  int tid = threadIdx.x;
  int lane = tid & 63, wave = tid >> 6;   // 16 waves
  __shared__ float ush[512];
  __shared__ float sC[512];
  __shared__ float cpart[512];
  __shared__ float tpart[4][512];
  __shared__ float wl[9];
  __shared__ float sc[32], at[32];
  if (tid < 512) ush[tid] = u[b*512 + tid];
  __syncthreads();
  // attention scores (16 waves cover s = wave, wave+16)
  for (int s = wave; s < 30; s += 16) {
    float acc = 0.f;
    const float* lo = lstm_out + ((size_t)b*30 + s)*512;
#pragma unroll
    for (int h = lane; h < 512; h += 64) acc += lo[h]*ush[h]*W3[h];
#pragma unroll
    for (int off = 32; off; off >>= 1) acc += __shfl_down(acc, off);
    if (lane == 0) sc[s] = acc;
  }
  // kernel-choice logits (waves 0..8, one m each)
  if (wave < 9) {
    float acc = 0.f;
#pragma unroll
    for (int k = lane; k < 512; k += 64) acc += ush[k]*Wmod[k*9+wave];
#pragma unroll
    for (int off = 32; off; off >>= 1) acc += __shfl_down(acc, off);
    if (lane == 0) wl[wave] = acc;
  }
  __syncthreads();
  if (tid == 0) {
    float mx = wl[0];
    for (int m = 1; m < 9; ++m) mx = fmaxf(mx, wl[m]);
    float s = 0.f;
    for (int m = 0; m < 9; ++m) s += fexp(wl[m]-mx);
    float ls = logf(s);
    float ent = 0.f;
    for (int m = 0; m < 9; ++m) {
      float l = wl[m]-mx-ls;
      float w = fexp(l);
      woutAll[t*576 + b*9 + m] = w;
      ent -= w*l;
    }
    imp_part[t*64+b] = ent;
  }
  if (wave == 1) {
    float v = (lane < 30) ? sc[lane] : -3.4e38f;
    float mx = v;
#pragma unroll
    for (int off = 32; off; off >>= 1) mx = fmaxf(mx, __shfl_xor(mx, off));
    float e = (lane < 30) ? fexp(v-mx) : 0.f;
    float ssum = e;
#pragma unroll
    for (int off = 32; off; off >>= 1) ssum += __shfl_xor(ssum, off);
    if (lane < 30) at[lane] = e/ssum;
  }
  __syncthreads();
  // context: 2-way s-split per h
  {
    int h = tid & 511, seg = tid >> 9;
    float acc = 0.f;
    int s0 = seg ? 15 : 0, s1 = seg ? 30 : 15;
    for (int s = s0; s < s1; ++s) acc += at[s]*lstm_out[((size_t)b*30 + s)*512 + h];
    if (seg) cpart[h] = acc;
    __syncthreads();
    if (!seg) {
      float tot = acc + cpart[h];
      cout[b*512+h] = tot;
      sC[h] = tot;
    }
  }
  __syncthreads();
  // tmap = c @ t2m + b  (pair-packed bf16; 4-way k-split)
  {
    int c2 = tid & 255, ks = tid >> 8;   // ks in 0..3
    float a0 = 0.f, a1 = 0.f;
    const unsigned* tp = t2pp + c2;
#pragma unroll 8
    for (int k = ks*128; k < ks*128 + 128; ++k) {
      float cv = sC[k];
      unsigned wv2 = tp[(size_t)k*256];
      a0 += cv*blo(wv2);
      a1 += cv*bhi(wv2);
    }
    tpart[ks][c2]       = a0;
    tpart[ks][256 + c2] = a1;
  }
  __syncthreads();
  if (tid < 512) {
    float v = tpart[0][tid] + tpart[1][tid] + tpart[2][tid] + tpart[3][tid];
    tmapv[b*512 + tid] = v + t2mb[tid];
  }
}

// ---------------------------------------------------------------------------
// fused modules + pooled partials + stack update + pvec ping-pong
// PLUS (blockIdx.y==19): next-t u-GEMM, 64 blocks, LDS-STAGED A (round-7
// lesson: global-broadcast A reads in the inner loop cost ~10us/block).
// Shared memory is a union of the two branches' needs (40KB -> 4 blk/CU).
// grid (64, 20).
// ---------------------------------------------------------------------------
__global__ __launch_bounds__(256)
void modu_k(const unsigned short* __restrict__ imapB, const float* __restrict__ tmapv,
            float* __restrict__ stack, const float* __restrict__ pvecIn,
            float* __restrict__ pvecOut,
            const float* __restrict__ swb, const float* __restrict__ c3w,
            const float* __restrict__ c3b, const float* __restrict__ c4w,
            const float* __restrict__ c4b, const float* __restrict__ wmod,
            float* __restrict__ plt,
            const float* __restrict__ tmp1n, const float* __restrict__ cprevB,
            const unsigned short* __restrict__ w2bp, const float* __restrict__ W2b,
            float* __restrict__ ubuf, int do_u)
{
  __shared__ union {
    struct { float sT[512]; float pv[8], pd[8], wm[9]; float wpart[4][2][512]; } m;
    struct { __align__(16) float As[8][1024]; float part[4][8][64]; } u;
  } sm;
  int pb = blockIdx.y;
  int lane = threadIdx.x & 63, wave = threadIdx.x >> 6;
  if (pb == 19) {
    // ---- u(t+1) = [tmp1n | cprev] @ W2(bf16) + W2b, A staged in LDS ----
    if (!do_u) return;
    const int x = blockIdx.x;
    const int r0 = (x >> 3) * 8, nc0 = (x & 7) * 64;
    for (int e4 = threadIdx.x; e4 < 2048; e4 += 256) {
      int r = e4 >> 8;
      int k4 = (e4 & 255) << 2;
      float4 v = (k4 < 512)
          ? *(const float4*)&tmp1n [(size_t)(r0+r)*512 + k4]
          : *(const float4*)&cprevB[(size_t)(r0+r)*512 + (k4 - 512)];
      *(float4*)&sm.u.As[r][k4] = v;
    }
    __syncthreads();
    const int k0 = wave * 256;
    const unsigned short* Bp = w2bp + (size_t)k0*512 + nc0 + lane;
    float acc[8] = {0,0,0,0,0,0,0,0};
#pragma unroll 4
    for (int kk = 0; kk < 256; ++kk) {
      float bv = bl(Bp[(size_t)kk*512]);
#pragma unroll
      for (int r = 0; r < 8; ++r) acc[r] += sm.u.As[r][k0+kk] * bv;
    }
#pragma unroll
    for (int r = 0; r < 8; ++r) sm.u.part[wave][r][lane] = acc[r];
    __syncthreads();
    {
      int r = threadIdx.x >> 6, c = lane;
#pragma unroll
      for (int p2 = 0; p2 < 2; ++p2) {
        int rr = r + p2*4;
        float s2 = sm.u.part[0][rr][c] + sm.u.part[1][rr][c]
                 + sm.u.part[2][rr][c] + sm.u.part[3][rr][c];
        ubuf[(size_t)(r0 + rr)*512 + nc0 + c] = s2 + W2b[nc0 + c];
      }
    }
    return;
  }
  int b = blockIdx.x;
  for (int j = threadIdx.x; j < 512; j += 256) sm.m.sT[j] = tmapv[b*512 + j];
  if (threadIdx.x < 8) sm.m.pv[threadIdx.x] = pvecIn[b*8+threadIdx.x];
  if (threadIdx.x >= 64 && threadIdx.x < 73) sm.m.wm[threadIdx.x-64] = wmod[b*9 + threadIdx.x-64];
  __syncthreads();
  if (threadIdx.x < 8) {
    int l = threadIdx.x;
    sm.m.pd[l] = (l < 7 ? sm.m.pv[l+1] : 0.f) + (l == 0 ? sm.m.pv[0] : 0.f);
  }
  __syncthreads();
  if (pb == 0 && threadIdx.x < 8) {
    int l = threadIdx.x;
    float WP = sm.m.wm[0]+sm.m.wm[1]+sm.m.wm[2]+sm.m.wm[3] + sm.m.wm[6] + sm.m.wm[8];
    float WD = sm.m.wm[4]+sm.m.wm[5] + sm.m.wm[7];
    pvecOut[b*8+l] = WP*sm.m.pv[l] + WD*sm.m.pd[l];
  }

  float W[8][6];
#pragma unroll
  for (int m = 0; m < 8; ++m)
#pragma unroll
    for (int i = 0; i < 6; ++i) W[m][i] = swb[m*6+i];
  float W03 = sm.m.wm[0]+sm.m.wm[1]+sm.m.wm[2]+sm.m.wm[3];
  float W45 = sm.m.wm[4]+sm.m.wm[5];

  float acc6[8], acc7[8];
#pragma unroll
  for (int i = 0; i < 8; ++i) { acc6[i] = 0.f; acc7[i] = 0.f; }

  for (int pi = 0; pi < 2; ++pi) {
    int p = pb*8 + wave*2 + pi;
    if (p < 150) {
      const float* st = stack + ((size_t)b*150 + p)*8;
      float a = 0.f, av2 = 0.f;
#pragma unroll
      for (int l = 0; l < 8; ++l) { float v = st[l]; a += v*sm.m.pv[l]; av2 += v*sm.m.pd[l]; }
      float part[6] = {0,0,0,0,0,0};
#pragma unroll 2
      for (int i = 0; i < 8; ++i) {
        int d = i*64 + lane;
        float x = bl(imapB[((size_t)b*150 + p)*512 + d]);
        float t = sm.m.sT[d];
#pragma unroll
        for (int m = 0; m < 4; ++m) {
          float c1 = W[m][0]*t + W[m][1] + W[m][4] + (W[m][2] + W[m][3]*t)*a;
          float c0 = W[m][1]*t + W[m][5]*t*a;
          part[m] += elu_(c1*x + c0) * c3w[m*512+d];
        }
#pragma unroll
        for (int m = 0; m < 2; ++m) {
          float c1 = W[4+m][0]*t + W[4+m][1] + W[4+m][2]*a + W[4+m][3]*av2
                   + W[4+m][4]*a*av2 + W[4+m][5]*t*(a+av2);
          part[4+m] += elu_(c1*x + W[4+m][1]*t) * c4w[m*512+d];
        }
        float c16 = W[6][0]*t + W[6][1] + W[6][4] + (W[6][2] + W[6][3]*t)*a;
        float c06 = W[6][1]*t + W[6][5]*t*a;
        acc6[i] += elu_(c16*x + c06);
        float c17 = W[7][0]*t + W[7][1] + W[7][2]*a + W[7][3]*av2
                  + W[7][4]*a*av2 + W[7][5]*t*(a+av2);
        acc7[i] += elu_(c17*x + W[7][1]*t);
      }
#pragma unroll
      for (int m = 0; m < 6; ++m) {
#pragma unroll
        for (int off = 32; off; off >>= 1) part[m] += __shfl_down(part[m], off);
        part[m] = __shfl(part[m], 0);
      }
      float r3  = sm.m.wm[0]*(part[0]+c3b[0]) + sm.m.wm[1]*(part[1]+c3b[1])
                + sm.m.wm[2]*(part[2]+c3b[2]) + sm.m.wm[3]*(part[3]+c3b[3]);
      float r45 = sm.m.wm[4]*(part[4]+c4b[0]) + sm.m.wm[5]*(part[5]+c4b[1]);
      if (lane < 8) {
        int l = lane;
        size_t idx = ((size_t)b*150 + p)*8 + l;
        stack[idx] = stack[idx]*(1.f - W03*sm.m.pv[l] - W45*sm.m.pd[l])
                   + sm.m.pv[l]*r3 + sm.m.pd[l]*r45;
      }
    }
  }
#pragma unroll
  for (int i = 0; i < 8; ++i) {
    sm.m.wpart[wave][0][i*64+lane] = acc6[i];
    sm.m.wpart[wave][1][i*64+lane] = acc7[i];
  }
  __syncthreads();
  for (int e = threadIdx.x; e < 1024; e += 256) {
    int which = e >> 9, d = e & 511;
    float s = sm.m.wpart[0][which][d] + sm.m.wpart[1][which][d]
            + sm.m.wpart[2][which][d] + sm.m.wpart[3][which][d];
    atomicAdd(&plt[(size_t)which*32768 + b*512 + d], s * (1.f/150.f));
  }
}

// ---------------------------------------------------------------------------
// batched m67 GEMMs for ALL t: grid (8 colchunks, 8 rowchunks, 18).
// z = t*2+zz: m67t[z] = [pl[t][zz] | tmapv[t]] @ ansW[zz] + ansb[zz]
// ---------------------------------------------------------------------------
__global__ __launch_bounds__(512)
void ansall_k(const float* __restrict__ plt, const float* __restrict__ tmapv,
              const unsigned short* __restrict__ answp, const float* __restrict__ ansb,
              float* __restrict__ m67o)
{
  const int z = blockIdx.z;          // 0..17
  const int t = z >> 1, zz = z & 1;
  __shared__ __align__(16) float As[8][1024];
  __shared__ float part[8][8][64];
  const int tid = threadIdx.x;
  const int r0 = blockIdx.y*8;
  const int nc0 = blockIdx.x*64;
  const int lane = tid & 63, w = tid >> 6;

  for (int e4 = tid; e4 < 1024; e4 += 512) {
    int r = e4 >> 7, k4 = (e4 & 127) << 2;
    *(float4*)&As[r][k4]     = *(const float4*)&plt[(size_t)z*32768 + (size_t)(r0+r)*512 + k4];
    *(float4*)&As[r][512+k4] = *(const float4*)&tmapv[(size_t)t*32768 + (size_t)(r0+r)*512 + k4];
  }
  __syncthreads();
  {
    const unsigned short* Bp = answp + (size_t)zz*524288
                             + (size_t)(w*128)*512 + nc0 + lane;
    float acc[8] = {0,0,0,0,0,0,0,0};
    int k0 = w*128;
#pragma unroll 8
    for (int kk = 0; kk < 128; ++kk) {
      float bv = bl(Bp[(size_t)kk*512]);
#pragma unroll
      for (int r = 0; r < 8; ++r) acc[r] += As[r][k0+kk]*bv;
    }
#pragma unroll
    for (int r = 0; r < 8; ++r) part[w][r][lane] = acc[r];
  }
  __syncthreads();
  {
    int r = tid >> 6, c = tid & 63;
    float s = 0.f;
#pragma unroll
    for (int w2 = 0; w2 < 8; ++w2) s += part[w2][r][c];
    m67o[(size_t)z*32768 + (size_t)(r0+r)*512 + nc0 + c] = s + ansb[zz*512 + nc0 + c];
  }
}

// ---------------------------------------------------------------------------
// final mem: mem_8 = sum_t coef_t*(w6_t*m6_t + w7_t*m7_t),
// coef_t = prod_{s>t} (1-w6_s-w7_s).  (mem_init = 0)
// ---------------------------------------------------------------------------
__global__ __launch_bounds__(512)
void memfin_k(const float* __restrict__ woutAll, const float* __restrict__ m67t,
              float* __restrict__ memb)
{
  int b = blockIdx.x;
  int tid = threadIdx.x;
  __shared__ float w6s[9], w7s[9], coef[9];
  if (tid < 9)       w6s[tid] = woutAll[tid*576 + b*9 + 6];
  else if (tid < 18) w7s[tid-9] = woutAll[(tid-9)*576 + b*9 + 7];
  __syncthreads();
  if (tid == 0) {
    float c = 1.f;
    for (int t = 8; t >= 0; --t) { coef[t] = c; c *= (1.f - w6s[t] - w7s[t]); }
  }
  __syncthreads();
  float acc = 0.f;
#pragma unroll
  for (int t = 0; t < 9; ++t) {
    float m6 = m67t[(((size_t)t*2 + 0)*64 + b)*512 + tid];
    float m7 = m67t[(((size_t)t*2 + 1)*64 + b)*512 + tid];
    acc += coef[t]*(w6s[t]*m6 + w7s[t]*m7);
  }
  memb[b*512 + tid] = acc;
}

// ---------------------------------------------------------------------------
__global__ __launch_bounds__(256)
void imp_k(const float* __restrict__ part, float* __restrict__ out)
{
  int lane = threadIdx.x & 63, wave = threadIdx.x >> 6;
  float acc = 0.f;
  for (int i = threadIdx.x; i < 576; i += 256) acc += part[i];
#pragma unroll
  for (int off = 32; off; off >>= 1) acc += __shfl_down(acc, off);
  __shared__ float red[4];
  if (lane == 0) red[wave] = acc;
  __syncthreads();
  if (threadIdx.x == 0) out[0] = red[0]+red[1]+red[2]+red[3];
}

// ---------------------------------------------------------------------------
extern "C" void kernel_launch(void* const* d_in, const int* in_sizes, int n_in,
                              void* d_out, int out_size, void* d_ws, size_t ws_size,
                              hipStream_t stream)
{
  (void)in_sizes; (void)n_in; (void)out_size; (void)ws_size;
  const float* image = (const float*)d_in[0];
  const int*   ques  = (const int*)d_in[1];
  const int*   qlen  = (const int*)d_in[2];
  const float* embedW= (const float*)d_in[3];
  const float* Wi_f  = (const float*)d_in[4];
  const float* Wh_f  = (const float*)d_in[5];
  const float* b_f   = (const float*)d_in[6];
  const float* Wi_b  = (const float*)d_in[7];
  const float* Wh_b  = (const float*)d_in[8];
  const float* b_b   = (const float*)d_in[9];
  const float* W1    = (const float*)d_in[10];
  const float* b1    = (const float*)d_in[11];
  const float* W2w   = (const float*)d_in[12];
  const float* W2b   = (const float*)d_in[13];
  const float* W3    = (const float*)d_in[14];
  const float* c0    = (const float*)d_in[15];
  const float* Wmod  = (const float*)d_in[16];
  const float* ic1w  = (const float*)d_in[17];
  const float* ic1b  = (const float*)d_in[18];
  const float* ic2w  = (const float*)d_in[19];
  const float* ic2b  = (const float*)d_in[20];
  const float* i2mw  = (const float*)d_in[21];
  const float* i2mb  = (const float*)d_in[22];
  const float* t2mw  = (const float*)d_in[23];
  const float* t2mb  = (const float*)d_in[24];
  const float* c3ow  = (const float*)d_in[25];
  const float* c3cw  = (const float*)d_in[26];
  const float* c3cb  = (const float*)d_in[27];
  const float* c4ow  = (const float*)d_in[28];
  const float* c4cw  = (const float*)d_in[29];
  const float* c4cb  = (const float*)d_in[30];
  const float* aow   = (const float*)d_in[31];
  const float* ansW  = (const float*)d_in[32];
  const float* ansb  = (const float*)d_in[33];
  const float* o1w   = (const float*)d_in[34];
  const float* o1b   = (const float*)d_in[35];
  const float* o2w   = (const float*)d_in[36];
  const float* o2b   = (const float*)d_in[37];
  float* out = (float*)d_out;
  float* ws  = (float*)d_ws;

  size_t off = 0;
  auto alloc = [&](size_t n){ float* p = ws + off; off += n; return p; };
  short* imgP  = (short*)alloc(600ull*20*64*8/2);
  short* X1p   = (short*)alloc(600ull*16*64*8/2);
  short* X2p   = (short*)alloc(600ull*16*64*8/2);
  short* w1p   = (short*)alloc(20*32*64*8/2);
  short* w2mp  = (short*)alloc(16*32*64*8/2);
  short* w3mp  = (short*)alloc(16*32*64*8/2);
  short* wifp  = (short*)alloc(10*64*64*8/2);
  short* wibp  = (short*)alloc(10*64*64*8/2);
  short* embp  = (short*)alloc(120ull*10*64*8/2);
  unsigned short* imapB = (unsigned short*)alloc(9600ull*512/2);
  unsigned* t2pp = (unsigned*)alloc(512*256);
  unsigned short* w2bp  = (unsigned short*)alloc(524288/2);
  unsigned short* answp = (unsigned short*)alloc(1048576/2);
  float* xWfb  = alloc(64ull*30*1024);
  float* xWbb  = alloc(64ull*30*1024);
  float* lout  = alloc(64ull*30*512);
  float* qbuf  = alloc(64*512);
  float* stck  = alloc(64*150*8);
  float* pvecA = alloc(64*8);
  float* pvecB = alloc(64*8);
  float* memb  = alloc(64*512);
  float* cprev = alloc(64*512);
  float* tmp1a = alloc(9ull*64*512);
  float* ubuf  = alloc(64*512);
  float* wmwA  = alloc(9*64*9);
  float* impp  = alloc(9*64);
  float* swb   = alloc(48);
  float* pl    = alloc(9ull*2*64*512);
  float* m67t  = alloc(9ull*2*64*512);
  float* tmapv = alloc(9ull*64*512);
  float* h1b   = alloc(64*1024);
  unsigned* whT = (unsigned*)alloc(2ull*1024*128);       // f16-pair packed Wh^T
  float* hbufW  = alloc(32768);                          // 2 ping x 2 d x 4 g x 16 x 256 f16
  int*   flagsI = (int*)alloc(256);                      // step sync flags

  // one dispatch: init + ALL independent packs (incl. f16 WhT, bf16 W2/ansW)
  megapack_k<<<12036, 256, 0, stream>>>(
      c0, c3ow, c4ow, aow, stck, pvecA, memb, cprev, swb, pl,
      Wh_f, Wh_b, whT, hbufW, flagsI,
      ic1w, w1p, ic2w, w2mp, i2mw, w3mp, Wi_f, wifp, Wi_b, wibp,
      image, imgP, embedW, ques, embp, t2mw, t2pp,
      W2w, w2bp, ansW, answp);

  // conv chain (MFMA); conv3 -> bf16 row-major imapB
  gemmM_k<<<dim3(8,150,1), 256, 0, stream>>>(imgP, imgP, w1p, w1p, ic1b, ic1b,
                                             X1p, X1p, 20, 32, 512, 1, 1, 16);
  gemmM_k<<<dim3(8,150,1), 256, 0, stream>>>(X1p, X1p, w2mp, w2mp, ic2b, ic2b,
                                             X2p, X2p, 16, 32, 512, 1, 0, 16);
  gemmM_k<<<dim3(8,150,1), 256, 0, stream>>>(X2p, X2p, w3mp, w3mp, i2mb, i2mb,
                                             imapB, imapB, 16, 32, 512, 2, 0, 0);
  // both embed GEMMs in one launch
  gemmM_k<<<dim3(16,30,2), 256, 0, stream>>>(embp, embp, wifp, wibp, b_f, b_b,
                                             xWfb, xWbb, 10, 64, 1024, 0, 0, 0);

  // MFMA LSTM: 32 persistent blocks, LDS weights, round-4 flag protocol
  lstmM_k<<<32, 256, 0, stream>>>(xWfb, xWbb, whT, qlen,
                                  (unsigned long long*)hbufW, flagsI, lout, qbuf);

  // tmp1all[t] = q @ W1[t] + b1 (all 9 t)
  gemm64b_k<<<dim3(8,8,9), 512, 0, stream>>>(
      qbuf, 0, 9, (const float*)nullptr, 0,
      W1, 262144, b1, 0, tmp1a, 32768, 512, 0);
  // u for t=0 (fp32 W2)
  gemm64b_k<<<dim3(8,8,1), 512, 0, stream>>>(
      tmp1a, 0, 9, cprev, 512, W2w, 0, W2b, 0, ubuf, 0, 512, 0);

  for (int t = 0; t < 9; ++t) {
    float* pvIn  = (t & 1) ? pvecB : pvecA;
    float* pvOut = (t & 1) ? pvecA : pvecB;
    kcattn3_k<<<64, 1024, 0, stream>>>(ubuf, Wmod, lout, W3, t2pp, t2mb,
                                       wmwA, impp, cprev,
                                       tmapv + (size_t)t*32768, t);
    modu_k<<<dim3(64,20), 256, 0, stream>>>(
        imapB, tmapv + (size_t)t*32768, stck, pvIn, pvOut, swb,
        c3cw, c3cb, c4cw, c4cb,
        wmwA + (size_t)t*576, pl + (size_t)t*65536,
        tmp1a + (size_t)(t < 8 ? t+1 : 0)*32768, cprev, w2bp, W2b, ubuf,
        (t < 8) ? 1 : 0);
  }

  // all 18 m67 GEMMs in ONE dispatch (off the sequential critical path)
  ansall_k<<<dim3(8,8,18), 512, 0, stream>>>(pl, tmapv, answp, ansb, m67t);

  // final mem blend, then h1 = elu([q, mem] @ out1 + b); logits = h1 @ out2 + b
  memfin_k<<<64, 512, 0, stream>>>(wmwA, m67t, memb);
  gemm64b_k<<<dim3(16,8,1), 512, 0, stream>>>(
      qbuf, 0, 9, memb, 512, o1w, 0, o1b, 0, h1b, 0, 1024, 1);
  gemm64b_k<<<dim3(1,8,1), 512, 0, stream>>>(
      h1b, 0, 10, (const float*)nullptr, 0, o2w, 0, o2b, 0, out, 0, 32, 0);
  imp_k<<<1, 256, 0, stream>>>(impp, out + 2048);
}

// Round 9
// 810.956 us; speedup vs baseline: 1.1686x; 1.0279x over previous
//
#include <hip/hip_runtime.h>
#include <hip/hip_fp16.h>
#include <math.h>

#define DEV __device__ __forceinline__

DEV float fexp(float x){ return __expf(x); }
DEV float elu_(float x){ return x > 0.f ? x : fexp(x) - 1.f; }
DEV float sigm_(float x){ return 1.f/(1.f + fexp(-x)); }
DEV float tanh_(float x){ float e = fexp(2.f*x); return 1.f - 2.f/(e + 1.f); }
DEV unsigned bf16r(float x){ unsigned u = __float_as_uint(x);
  return (u + 0x7fffu + ((u>>16)&1u)) >> 16; }
DEV float blo(unsigned u){ return __uint_as_float(u << 16); }
DEV float bhi(unsigned u){ return __uint_as_float(u & 0xffff0000u); }
DEV float bl(unsigned short u){ return __uint_as_float(((unsigned)u) << 16); }

using frag  = __attribute__((ext_vector_type(8))) short;     // 8 bf16 (4 VGPRs)
using fragh = __attribute__((ext_vector_type(8))) _Float16;  // 8 f16  (4 VGPRs)
using f32x4 = __attribute__((ext_vector_type(4))) float;     // MFMA acc

// coherent (sc0 sc1 = device-coherent path) 16B load WITH completion wait
DEV uint4 cload16w(const void* p){
  uint4 r;
  asm volatile("global_load_dwordx4 %0, %1, off sc0 sc1\n\ts_waitcnt vmcnt(0)"
               : "=v"(r) : "v"(p) : "memory");
  return r;
}
// coherent 16B load, NO wait (caller does one s_waitcnt vmcnt(0) for the batch)
DEV uint4 cload16nw(const void* p){
  uint4 r;
  asm volatile("global_load_dwordx4 %0, %1, off sc0 sc1"
               : "=v"(r) : "v"(p) : "memory");
  return r;
}

// ---------------------------------------------------------------------------
// device pack helpers
// ---------------------------------------------------------------------------
DEV void d_packB(const float* __restrict__ W, short* __restrict__ Bp,
                 int KC, int Ng, int Ksrc, int N, int trans, int idx)
{
  if (idx >= KC*Ng*64) return;
  int lane = idx & 63;
  int g    = (idx >> 6) % Ng;
  int kc   = idx / (64*Ng);
  int n = g*16 + (lane & 15);
  int kb = kc*32 + ((lane >> 4) << 3);
  unsigned o[4];
#pragma unroll
  for (int jj = 0; jj < 4; ++jj) {
    int k0 = kb + 2*jj;
    float v0 = (k0   < Ksrc) ? (trans ? W[(size_t)n*Ksrc + k0]   : W[(size_t)(k0)*N + n])   : 0.f;
    float v1 = (k0+1 < Ksrc) ? (trans ? W[(size_t)n*Ksrc + k0+1] : W[(size_t)(k0+1)*N + n]) : 0.f;
    o[jj] = bf16r(v0) | (bf16r(v1) << 16);
  }
  *(uint4*)(Bp + (size_t)idx*8) = make_uint4(o[0], o[1], o[2], o[3]);
}

DEV void d_packImg(const float* __restrict__ image, short* __restrict__ Ap, int idx)
{
  int lane = idx & 63;
  int kc   = (idx >> 6) % 20;
  int mt   = idx / 1280;
  int row = mt*16 + (lane & 15);
  int b = row / 150, p = row % 150;
  int cb = kc*32 + ((lane >> 4) << 3);
  unsigned o[4];
#pragma unroll
  for (int jj = 0; jj < 4; ++jj) {
    float v0 = image[((size_t)b*640 + cb + 2*jj    )*150 + p];
    float v1 = image[((size_t)b*640 + cb + 2*jj + 1)*150 + p];
    o[jj] = bf16r(v0) | (bf16r(v1) << 16);
  }
  *(uint4*)(Ap + (size_t)idx*8) = make_uint4(o[0], o[1], o[2], o[3]);
}

DEV void d_packEmb(const float* __restrict__ embedW, const int* __restrict__ ques,
                   short* __restrict__ Ap, int idx)
{
  int lane = idx & 63;
  int kc   = (idx >> 6) % 10;
  int mt   = idx / 640;
  int row = mt*16 + (lane & 15);
  int q = ques[row];
  int kb = kc*32 + ((lane >> 4) << 3);
  unsigned o[4];
#pragma unroll
  for (int jj = 0; jj < 4; ++jj) {
    int k0 = kb + 2*jj;
    float v0 = (k0   < 300) ? embedW[(size_t)q*300 + k0]   : 0.f;
    float v1 = (k0+1 < 300) ? embedW[(size_t)q*300 + k0+1] : 0.f;
    o[jj] = bf16r(v0) | (bf16r(v1) << 16);
  }
  *(uint4*)(Ap + (size_t)idx*8) = make_uint4(o[0], o[1], o[2], o[3]);
}

// ---------------------------------------------------------------------------
// ONE dispatch for all independent pre-stage work
// ---------------------------------------------------------------------------
__global__ __launch_bounds__(256)
void megapack_k(const float* __restrict__ c0, const float* __restrict__ c3ow,
                const float* __restrict__ c4ow, const float* __restrict__ aow,
                float* __restrict__ stack, float* __restrict__ pvecA,
                float* __restrict__ mem, float* __restrict__ cprev,
                float* __restrict__ swb, float* __restrict__ pl,
                const float* __restrict__ Whf, const float* __restrict__ Whb,
                unsigned* __restrict__ whT,
                float* __restrict__ hbufz, int* __restrict__ flagz,
                const float* __restrict__ ic1w, short* __restrict__ w1p,
                const float* __restrict__ ic2w, short* __restrict__ w2mp,
                const float* __restrict__ i2mw, short* __restrict__ w3mp,
                const float* __restrict__ Wif, short* __restrict__ wifp,
                const float* __restrict__ Wib, short* __restrict__ wibp,
                const float* __restrict__ image, short* __restrict__ imgP,
                const float* __restrict__ embedW, const int* __restrict__ ques,
                short* __restrict__ embp,
                const float* __restrict__ t2mw, unsigned* __restrict__ t2pp,
                const float* __restrict__ W2w, unsigned short* __restrict__ w2bp,
                const float* __restrict__ ansW, unsigned short* __restrict__ answp)
{
  const int bx = blockIdx.x, tid = threadIdx.x;
  if (bx < 320) {
    int idx = bx*256 + tid;
    int stride = 320*256;
    for (int i = idx; i < 64*150*8; i += stride) stack[i] = 0.f;
    for (int i = idx; i < 64*8;    i += stride) pvecA[i] = ((i & 7) == 0) ? 1.f : 0.f;
    for (int i = idx; i < 64*512;  i += stride) mem[i] = 0.f;
    for (int i = idx; i < 64*512;  i += stride) cprev[i] = c0[i & 511];
    for (int i = idx; i < 9*2*64*512; i += stride) pl[i] = 0.f;
    for (int i = idx; i < 32768;   i += stride) hbufz[i] = 0.f;  // hbuf (f16 pairs)
    if (idx < 256) flagz[idx] = 0;                               // sync flags
    if (idx < 8) {
      const float* ow = (idx < 4) ? (c3ow + idx*6)
                      : (idx < 6) ? (c4ow + (idx-4)*6)
                                  : (aow  + (idx-6)*6);
      float mx = ow[0];
      for (int m = 1; m < 6; ++m) mx = fmaxf(mx, ow[m]);
      float e[6]; float s = 0.f;
      for (int m = 0; m < 6; ++m) { e[m] = fexp(ow[m]-mx); s += e[m]; }
      for (int m = 0; m < 6; ++m) swb[idx*6+m] = e[m]/s;
    }
  } else if (bx < 1344) {
    // WhT: [d][zc 0..1023][k-pair 0..127] packed f16 pairs (transposed Wh)
    int idx = (bx-320)*256 + tid;
    int dd  = idx >> 17;
    int rem = idx & 131071;
    int kp  = rem >> 10;
    int zc  = rem & 1023;
    const float* Wh = dd ? Whb : Whf;
    __half2 hv = __floats2half2_rn(Wh[(size_t)(2*kp)*1024 + zc],
                                   Wh[(size_t)(2*kp+1)*1024 + zc]);
    whT[((size_t)dd << 17) + (zc << 7) + kp] = *(unsigned*)&hv;
  } else if (bx < 1504) {
    d_packB(ic1w, w1p, 20, 32, 640, 512, 1, (bx-1344)*256 + tid);
  } else if (bx < 1632) {
    d_packB(ic2w, w2mp, 16, 32, 512, 512, 1, (bx-1504)*256 + tid);
  } else if (bx < 1760) {
    d_packB(i2mw, w3mp, 16, 32, 512, 512, 1, (bx-1632)*256 + tid);
  } else if (bx < 1920) {
    d_packB(Wif, wifp, 10, 64, 300, 1024, 0, (bx-1760)*256 + tid);
  } else if (bx < 2080) {
    d_packB(Wib, wibp, 10, 64, 300, 1024, 0, (bx-1920)*256 + tid);
  } else if (bx < 5080) {
    d_packImg(image, imgP, (bx-2080)*256 + tid);
  } else if (bx < 5380) {
    d_packEmb(embedW, ques, embp, (bx-5080)*256 + tid);
  } else if (bx < 5892) {
    int idx = (bx-5380)*256 + tid;   // 512*256
    int k = idx >> 8, c = idx & 255;
    t2pp[idx] = bf16r(t2mw[(size_t)k*512 + c]) | (bf16r(t2mw[(size_t)k*512 + 256 + c]) << 16);
  } else if (bx < 7940) {
    int i = (bx-5892)*256 + tid;     // 524288
    w2bp[i] = (unsigned short)bf16r(W2w[i]);
  } else {
    int i = (bx-7940)*256 + tid;     // 1048576
    answp[i] = (unsigned short)bf16r(ansW[i]);
  }
}

// ---------------------------------------------------------------------------
// MFMA GEMM, dual problem sets via blockIdx.z.
// mode 0: fp32 row-major; mode 1: bf16 A-pack; mode 2: bf16 row-major
// ---------------------------------------------------------------------------
__global__ __launch_bounds__(256)
void gemmM_k(const short* __restrict__ ApA, const short* __restrict__ ApB,
             const short* __restrict__ BpA, const short* __restrict__ BpB,
             const float* __restrict__ biasA, const float* __restrict__ biasB,
             void* __restrict__ CoutA, void* __restrict__ CoutB,
             int KC, int Ng, int N, int mode, int act, int KCout)
{
  __shared__ float lds[4][16][68];
  const int z = blockIdx.z;
  const short* Ap = z ? ApB : ApA;
  const short* Bp = z ? BpB : BpA;
  const float* bias = z ? biasB : biasA;
  void* Cout = z ? CoutB : CoutA;
  const int tid = threadIdx.x, lane = tid & 63, w = tid >> 6;
  const int mt = blockIdx.y*4 + w;
  const int ncol0 = blockIdx.x*64;
  const short* Abase = Ap + (((size_t)mt*KC) << 9) + lane*8;
  const short* Bbase = Bp + (((size_t)blockIdx.x*4) << 9) + lane*8;
  f32x4 acc0 = {0.f,0.f,0.f,0.f}, acc1 = acc0, acc2 = acc0, acc3 = acc0;
#pragma unroll 2
  for (int kc = 0; kc < KC; ++kc) {
    frag a = *(const frag*)(Abase + ((size_t)kc << 9));
    const short* bk = Bbase + (((size_t)kc*Ng) << 9);
    frag b0 = *(const frag*)(bk);
    frag b1 = *(const frag*)(bk + 512);
    frag b2 = *(const frag*)(bk + 1024);
    frag b3 = *(const frag*)(bk + 1536);
    acc0 = __builtin_amdgcn_mfma_f32_16x16x32_bf16(a, b0, acc0, 0, 0, 0);
    acc1 = __builtin_amdgcn_mfma_f32_16x16x32_bf16(a, b1, acc1, 0, 0, 0);
    acc2 = __builtin_amdgcn_mfma_f32_16x16x32_bf16(a, b2, acc2, 0, 0, 0);
    acc3 = __builtin_amdgcn_mfma_f32_16x16x32_bf16(a, b3, acc3, 0, 0, 0);
  }
  {
    int colb = lane & 15, rowb = (lane >> 4)*4;
#pragma unroll
    for (int r = 0; r < 4; ++r) {
      lds[w][rowb+r][ 0+colb] = acc0[r];
      lds[w][rowb+r][16+colb] = acc1[r];
      lds[w][rowb+r][32+colb] = acc2[r];
      lds[w][rowb+r][48+colb] = acc3[r];
    }
  }
  __syncthreads();
  if (mode == 0) {
    float* C = (float*)Cout;
    int mloc = lane >> 2, q4 = lane & 3;
    size_t rowoff = (size_t)(mt*16 + mloc)*N + ncol0 + q4*16;
#pragma unroll
    for (int i = 0; i < 4; ++i) {
      float4 v = *(float4*)&lds[w][mloc][q4*16 + i*4];
      const float* bp = bias + ncol0 + q4*16 + i*4;
      v.x += bp[0]; v.y += bp[1]; v.z += bp[2]; v.w += bp[3];
      if (act) { v.x = elu_(v.x); v.y = elu_(v.y); v.z = elu_(v.z); v.w = elu_(v.w); }
      *(float4*)&C[rowoff + i*4] = v;
    }
  } else if (mode == 1) {
    short* C = (short*)Cout;
    int m = lane & 15, qb = (lane >> 4)*8;
#pragma unroll
    for (int h = 0; h < 2; ++h) {
      int nl = h*32 + qb;
      unsigned o[4];
#pragma unroll
      for (int jj = 0; jj < 4; ++jj) {
        float v0 = lds[w][m][nl + 2*jj]     + bias[ncol0 + nl + 2*jj];
        float v1 = lds[w][m][nl + 2*jj + 1] + bias[ncol0 + nl + 2*jj + 1];
        if (act) { v0 = elu_(v0); v1 = elu_(v1); }
        o[jj] = bf16r(v0) | (bf16r(v1) << 16);
      }
      *(uint4*)(C + (((size_t)mt*KCout + (ncol0 >> 5) + h) << 9) + lane*8)
          = make_uint4(o[0], o[1], o[2], o[3]);
    }
  } else {
    unsigned short* C = (unsigned short*)Cout;
    int row = lane >> 2, cb = (lane & 3)*16;
#pragma unroll
    for (int h = 0; h < 2; ++h) {
      unsigned o[4];
#pragma unroll
      for (int jj = 0; jj < 4; ++jj) {
        float v0 = lds[w][row][cb + h*8 + 2*jj]     + bias[ncol0 + cb + h*8 + 2*jj];
        float v1 = lds[w][row][cb + h*8 + 2*jj + 1] + bias[ncol0 + cb + h*8 + 2*jj + 1];
        if (act) { v0 = elu_(v0); v1 = elu_(v1); }
        o[jj] = bf16r(v0) | (bf16r(v1) << 16);
      }
      *(uint4*)&C[(size_t)(mt*16 + row)*N + ncol0 + cb + h*8]
          = make_uint4(o[0], o[1], o[2], o[3]);
    }
  }
}

// ---------------------------------------------------------------------------
// 64-row batch GEMM, K-split across waves
// ---------------------------------------------------------------------------
__global__ __launch_bounds__(512)
void gemm64b_k(const float* __restrict__ A1, long zA1, int K1log,
               const float* __restrict__ A2, int K2,
               const float* __restrict__ B, long zB,
               const float* __restrict__ bias, int zbias,
               float* __restrict__ C, long zC, int N, int act)
{
  const int K1 = 1 << K1log;
  const int Kt = K1 + K2;
  __shared__ __align__(16) float As[8][1024];
  __shared__ float part[8][8][64];
  const int tid = threadIdx.x;
  const int z = blockIdx.z;
  const int r0 = blockIdx.y*8;
  {
    const float* a1 = A1 + (size_t)z*zA1;
    const int nf4 = (8*K1) >> 2;
    for (int e4 = tid; e4 < nf4; e4 += 512) {
      int r = e4 >> (K1log-2);
      int k4 = (e4 & ((K1>>2)-1)) << 2;
      *(float4*)&As[r][k4] = *(const float4*)&a1[(size_t)(r0+r)*K1 + k4];
    }
    if (K2 > 0) {
      for (int e4 = tid; e4 < 1024; e4 += 512) {
        int r = e4 >> 7;
        int k4 = (e4 & 127) << 2;
        *(float4*)&As[r][K1+k4] = *(const float4*)&A2[(size_t)(r0+r)*512 + k4];
      }
    }
  }
  __syncthreads();
  const int lane = tid & 63, w = tid >> 6;
  const int n = blockIdx.x*64 + lane;
  const bool nv = n < N;
  const int kseg = Kt >> 3;
  const int k0 = w*kseg;
  const float* Bp = B + (size_t)z*zB + (size_t)k0*N + (nv ? n : 0);
  float acc[8] = {0,0,0,0,0,0,0,0};
#pragma unroll 8
  for (int kk = 0; kk < kseg; ++kk) {
    float bv = nv ? Bp[(size_t)kk*N] : 0.f;
    int k = k0 + kk;
#pragma unroll
    for (int r = 0; r < 8; ++r) acc[r] += As[r][k]*bv;
  }
#pragma unroll
  for (int r = 0; r < 8; ++r) part[w][r][lane] = acc[r];
  __syncthreads();
  {
    int r = tid >> 6, c = tid & 63;
    int nn = blockIdx.x*64 + c;
    if (nn < N) {
      float s = 0.f;
#pragma unroll
      for (int w2 = 0; w2 < 8; ++w2) s += part[w2][r][c];
      s += bias ? bias[(size_t)z*zbias + nn] : 0.f;
      if (act == 1) s = elu_(s);
      C[(size_t)z*zC + (size_t)(r0+r)*N + nn] = s;
    }
  }
}

// ---------------------------------------------------------------------------
// MERGED: MFMA bidirectional masked LSTM (blocks 0..31, round-4 protocol)
// + conv1 GEMM (blocks 32..1231) running concurrently on the idle 224 CUs.
// No inter-branch sync: conv1 is data-independent of the LSTM; conv blocks
// always terminate, so every LSTM block is eventually scheduled (no
// dispatch-order assumption needed for correctness).
// ---------------------------------------------------------------------------
__global__ __launch_bounds__(256)
void lstmc1_k(const float* __restrict__ xWf, const float* __restrict__ xWb,
              const unsigned* __restrict__ whT, const int* __restrict__ qlen,
              unsigned long long* __restrict__ hbuf, int* __restrict__ flags,
              float* __restrict__ lstm_out, float* __restrict__ qout,
              const short* __restrict__ c1Ap, const short* __restrict__ c1Bp,
              const float* __restrict__ c1bias, short* __restrict__ c1out)
{
  const int tid = threadIdx.x, lane = tid & 63, w = tid >> 6;
  __shared__ union {
    unsigned short Wl[65536];                 // 128 KiB (lstm weights)
    float lds[4][16][68];                     // conv epilogue staging
  } sm;

  if (blockIdx.x >= 32) {
    // ================= conv1 branch: X1p = elu(imgP @ w1p + ic1b) ==========
    const int bx2 = (int)blockIdx.x - 32;     // 0..1199
    const int mt = (bx2 >> 3)*4 + w;          // 150 y-tiles * 4 waves
    const int ncol0 = (bx2 & 7)*64;
    const short* Abase = c1Ap + (((size_t)mt*20) << 9) + lane*8;
    const short* Bbase = c1Bp + (((size_t)(bx2 & 7)*4) << 9) + lane*8;
    f32x4 acc0 = {0.f,0.f,0.f,0.f}, acc1 = acc0, acc2 = acc0, acc3 = acc0;
#pragma unroll 2
    for (int kc = 0; kc < 20; ++kc) {
      frag a = *(const frag*)(Abase + ((size_t)kc << 9));
      const short* bk = Bbase + (((size_t)kc*32) << 9);
      frag b0 = *(const frag*)(bk);
      frag b1 = *(const frag*)(bk + 512);
      frag b2 = *(const frag*)(bk + 1024);
      frag b3 = *(const frag*)(bk + 1536);
      acc0 = __builtin_amdgcn_mfma_f32_16x16x32_bf16(a, b0, acc0, 0, 0, 0);
      acc1 = __builtin_amdgcn_mfma_f32_16x16x32_bf16(a, b1, acc1, 0, 0, 0);
      acc2 = __builtin_amdgcn_mfma_f32_16x16x32_bf16(a, b2, acc2, 0, 0, 0);
      acc3 = __builtin_amdgcn_mfma_f32_16x16x32_bf16(a, b3, acc3, 0, 0, 0);
    }
    {
      int colb = lane & 15, rowb = (lane >> 4)*4;
#pragma unroll
      for (int r = 0; r < 4; ++r) {
        sm.lds[w][rowb+r][ 0+colb] = acc0[r];
        sm.lds[w][rowb+r][16+colb] = acc1[r];
        sm.lds[w][rowb+r][32+colb] = acc2[r];
        sm.lds[w][rowb+r][48+colb] = acc3[r];
      }
    }
    __syncthreads();
    {
      int m = lane & 15, qb = (lane >> 4)*8;
#pragma unroll
      for (int h = 0; h < 2; ++h) {
        int nl = h*32 + qb;
        unsigned o[4];
#pragma unroll
        for (int jj = 0; jj < 4; ++jj) {
          float v0 = elu_(sm.lds[w][m][nl + 2*jj]     + c1bias[ncol0 + nl + 2*jj]);
          float v1 = elu_(sm.lds[w][m][nl + 2*jj + 1] + c1bias[ncol0 + nl + 2*jj + 1]);
          o[jj] = bf16r(v0) | (bf16r(v1) << 16);
        }
        *(uint4*)(c1out + (((size_t)mt*16 + (ncol0 >> 5) + h) << 9) + lane*8)
            = make_uint4(o[0], o[1], o[2], o[3]);
      }
    }
    return;
  }

  // ===================== LSTM branch (round-4 protocol) ====================
  const int bx = blockIdx.x;
  const int d = bx & 1, g = (bx >> 1) & 3, n = bx >> 3;
  const int q = lane >> 4, cl = lane & 15;

#pragma unroll 4
  for (int rb = 0; rb < 32; ++rb) {
    int lcrow = rb*8 + (tid >> 5);
    int gt = lcrow >> 6, c = lcrow & 63;
    int zc = gt*256 + n*64 + c;
    uint4 v = *(const uint4*)(whT + (((size_t)d*1024 + zc) << 7) + ((tid & 31) << 2));
    int byteoff = (lcrow << 9) + ((((tid & 31) << 4)) ^ ((lcrow & 7) << 4));
    *(uint4*)((char*)sm.Wl + byteoff) = v;
  }

  const float* xW = d ? xWb : xWf;
  const int b   = g*16 + cl;                 // this lane's batch
  const int c4  = w*16 + q*4;                // local col base within slice
  const int hc4 = n*64 + c4;                 // global h-col base (4 consecutive)
  const int len = qlen[b];
  float cst[4] = {0.f,0.f,0.f,0.f}, hst[4] = {0.f,0.f,0.f,0.f};
  int* flg = flags + ((d*4 + g) << 2);       // 4 flags for this (d,g) group
  const int bofs = (cl & 7) << 4;
  __syncthreads();

  for (int ss = 0; ss < 30; ++ss) {
    const int s = d ? (29 - ss) : ss;
    const float* xr = xW + (size_t)b*30720 + (size_t)s*1024 + hc4;
    f32x4 xwv[4];
#pragma unroll
    for (int gt = 0; gt < 4; ++gt) xwv[gt] = *(const f32x4*)(xr + gt*256);

    if (ss > 0) {
      for (;;) {
        uint4 f4 = cload16w(flg);   // all 4 flags in ONE coherent 16B load
        if ((int)f4.x >= ss && (int)f4.y >= ss &&
            (int)f4.z >= ss && (int)f4.w >= ss) break;
      }
      __builtin_amdgcn_sched_barrier(0);
    }
    // B = h^T from hbuf: 8 pipelined coherent 16B loads, ONE vmcnt wait
    const char* hbr = (const char*)(hbuf + ((size_t)(((ss & 1)*2 + d)*4 + g) << 9))
                    + (cl << 9) + (q << 4);
    union { uint4 u; fragh f; } hv[8];
#pragma unroll
    for (int ks = 0; ks < 8; ++ks) hv[ks].u = cload16nw(hbr + (ks << 6));
    asm volatile("s_waitcnt vmcnt(0)" ::: "memory");
    __builtin_amdgcn_sched_barrier(0);

    f32x4 acc0 = {0.f,0.f,0.f,0.f}, acc1 = acc0, acc2 = acc0, acc3 = acc0;
#pragma unroll
    for (int ks = 0; ks < 8; ++ks) {
      const int kb = ((ks << 6) + (q << 4)) ^ bofs;
      const char* wb = (const char*)sm.Wl + ((w*16 + cl) << 9) + kb;
      fragh a0 = *(const fragh*)(wb);
      fragh a1 = *(const fragh*)(wb + (64 << 9));
      fragh a2 = *(const fragh*)(wb + (128 << 9));
      fragh a3 = *(const fragh*)(wb + (192 << 9));
      acc0 = __builtin_amdgcn_mfma_f32_16x16x32_f16(a0, hv[ks].f, acc0, 0, 0, 0);
      acc1 = __builtin_amdgcn_mfma_f32_16x16x32_f16(a1, hv[ks].f, acc1, 0, 0, 0);
      acc2 = __builtin_amdgcn_mfma_f32_16x16x32_f16(a2, hv[ks].f, acc2, 0, 0, 0);
      acc3 = __builtin_amdgcn_mfma_f32_16x16x32_f16(a3, hv[ks].f, acc3, 0, 0, 0);
    }
    const bool m = s < len;
    f32x4 lo4;
    float hvv[4];
#pragma unroll
    for (int r = 0; r < 4; ++r) {
      float iv = acc0[r] + xwv[0][r];
      float fv = acc1[r] + xwv[1][r];
      float gv = acc2[r] + xwv[2][r];
      float o_ = acc3[r] + xwv[3][r];
      float cn = sigm_(fv)*cst[r] + sigm_(iv)*tanh_(gv);
      float hn = sigm_(o_)*tanh_(cn);
      float hk = m ? hn : hst[r];
      cst[r] = m ? cn : cst[r];
      hst[r] = hk;
      hvv[r] = hk;
      lo4[r] = m ? hn : 0.f;
    }
    unsigned long long* hbw = hbuf + ((size_t)((((ss & 1) ^ 1)*2 + d)*4 + g) << 9);
    union { unsigned long long u; __half2 h2[2]; } hp;
    hp.h2[0] = __floats2half2_rn(hvv[0], hvv[1]);
    hp.h2[1] = __floats2half2_rn(hvv[2], hvv[3]);
    __hip_atomic_store(hbw + cl*64 + (hc4 >> 2), hp.u,
                       __ATOMIC_RELAXED, __HIP_MEMORY_SCOPE_AGENT);
    *(f32x4*)(lstm_out + (((size_t)b*30 + s) << 9) + (d << 8) + hc4) = lo4;
    asm volatile("s_waitcnt vmcnt(0)" ::: "memory");
    __syncthreads();
    if (tid == 0)
      __hip_atomic_store(&flg[n], ss + 1, __ATOMIC_RELAXED, __HIP_MEMORY_SCOPE_AGENT);
  }
  *(f32x4*)(qout + ((size_t)b << 9) + (d << 8) + hc4) =
      f32x4{hst[0], hst[1], hst[2], hst[3]};
}

// ---------------------------------------------------------------------------
// fused kc + attn + tmap — 1024 threads (round-4 version, reads precomputed u)
// ---------------------------------------------------------------------------
__global__ __launch_bounds__(1024)
void kcattn3_k(const float* __restrict__ u, const float* __restrict__ Wmod,
               const float* __restrict__ lstm_out, const float* __restrict__ W3,
               const unsigned* __restrict__ t2pp, const float* __restrict__ t2mb,
               float* __restrict__ woutAll, float* __restrict__ imp_part,
               float* __restrict__ cout, float* __restrict__ tmapv, int t)
{
  int b = blockIdx.x;
  int tid = threadIdx.x;
  int lane = tid & 63, wave = tid >> 6;   // 16 waves
  __shared__ float ush[512];
  __shared__ float sC[512];
  __shared__ float cpart[512];
  __shared__ float tpart[4][512];
  __shared__ float wl[9];
  __shared__ float sc[32], at[32];
  if (tid < 512) ush[tid] = u[b*512 + tid];
  __syncthreads();
  // attention scores (16 waves cover s = wave, wave+16)
  for (int s = wave; s < 30; s += 16) {
    float acc = 0.f;
    const float* lo = lstm_out + ((size_t)b*30 + s)*512;
#pragma unroll
    for (int h = lane; h < 512; h += 64) acc += lo[h]*ush[h]*W3[h];
#pragma unroll
    for (int off = 32; off; off >>= 1) acc += __shfl_down(acc, off);
    if (lane == 0) sc[s] = acc;
  }
  // kernel-choice logits (waves 0..8, one m each)
  if (wave < 9) {
    float acc = 0.f;
#pragma unroll
    for (int k = lane; k < 512; k += 64) acc += ush[k]*Wmod[k*9+wave];
#pragma unroll
    for (int off = 32; off; off >>= 1) acc += __shfl_down(acc, off);
    if (lane == 0) wl[wave] = acc;
  }
  __syncthreads();
  if (tid == 0) {
    float mx = wl[0];
    for (int m = 1; m < 9; ++m) mx = fmaxf(mx, wl[m]);
    float s = 0.f;
    for (int m = 0; m < 9; ++m) s += fexp(wl[m]-mx);
    float ls = logf(s);
    float ent = 0.f;
    for (int m = 0; m < 9; ++m) {
      float l = wl[m]-mx-ls;
      float w = fexp(l);
      woutAll[t*576 + b*9 + m] = w;
      ent -= w*l;
    }
    imp_part[t*64+b] = ent;
  }
  if (wave == 1) {
    float v = (lane < 30) ? sc[lane] : -3.4e38f;
    float mx = v;
#pragma unroll
    for (int off = 32; off; off >>= 1) mx = fmaxf(mx, __shfl_xor(mx, off));
    float e = (lane < 30) ? fexp(v-mx) : 0.f;
    float ssum = e;
#pragma unroll
    for (int off = 32; off; off >>= 1) ssum += __shfl_xor(ssum, off);
    if (lane < 30) at[lane] = e/ssum;
  }
  __syncthreads();
  // context: 2-way s-split per h
  {
    int h = tid & 511, seg = tid >> 9;
    float acc = 0.f;
    int s0 = seg ? 15 : 0, s1 = seg ? 30 : 15;
    for (int s = s0; s < s1; ++s) acc += at[s]*lstm_out[((size_t)b*30 + s)*512 + h];
    if (seg) cpart[h] = acc;
    __syncthreads();
    if (!seg) {
      float tot = acc + cpart[h];
      cout[b*512+h] = tot;
      sC[h] = tot;
    }
  }
  __syncthreads();
  // tmap = c @ t2m + b  (pair-packed bf16; 4-way k-split)
  {
    int c2 = tid & 255, ks = tid >> 8;   // ks in 0..3
    float a0 = 0.f, a1 = 0.f;
    const unsigned* tp = t2pp + c2;
#pragma unroll 8
    for (int k = ks*128; k < ks*128 + 128; ++k) {
      float cv = sC[k];
      unsigned wv2 = tp[(size_t)k*256];
      a0 += cv*blo(wv2);
      a1 += cv*bhi(wv2);
    }
    tpart[ks][c2]       = a0;
    tpart[ks][256 + c2] = a1;
  }
  __syncthreads();
  if (tid < 512) {
    float v = tpart[0][tid] + tpart[1][tid] + tpart[2][tid] + tpart[3][tid];
    tmapv[b*512 + tid] = v + t2mb[tid];
  }
}

// ---------------------------------------------------------------------------
// fused modules + pooled partials + stack update + pvec ping-pong
// PLUS (blockIdx.y==19): next-t u-GEMM, 64 blocks, LDS-staged A.
// grid (64, 20).
// ---------------------------------------------------------------------------
__global__ __launch_bounds__(256)
void modu_k(const unsigned short* __restrict__ imapB, const float* __restrict__ tmapv,
            float* __restrict__ stack, const float* __restrict__ pvecIn,
            float* __restrict__ pvecOut,
            const float* __restrict__ swb, const float* __restrict__ c3w,
            const float* __restrict__ c3b, const float* __restrict__ c4w,
            const float* __restrict__ c4b, const float* __restrict__ wmod,
            float* __restrict__ plt,
            const float* __restrict__ tmp1n, const float* __restrict__ cprevB,
            const unsigned short* __restrict__ w2bp, const float* __restrict__ W2b,
            float* __restrict__ ubuf, int do_u)
{
  __shared__ union {
    struct { float sT[512]; float pv[8], pd[8], wm[9]; float wpart[4][2][512]; } m;
    struct { __align__(16) float As[8][1024]; float part[4][8][64]; } u;
  } sm;
  int pb = blockIdx.y;
  int lane = threadIdx.x & 63, wave = threadIdx.x >> 6;
  if (pb == 19) {
    // ---- u(t+1) = [tmp1n | cprev] @ W2(bf16) + W2b, A staged in LDS ----
    if (!do_u) return;
    const int x = blockIdx.x;
    const int r0 = (x >> 3) * 8, nc0 = (x & 7) * 64;
    for (int e4 = threadIdx.x; e4 < 2048; e4 += 256) {
      int r = e4 >> 8;
      int k4 = (e4 & 255) << 2;
      float4 v = (k4 < 512)
          ? *(const float4*)&tmp1n [(size_t)(r0+r)*512 + k4]
          : *(const float4*)&cprevB[(size_t)(r0+r)*512 + (k4 - 512)];
      *(float4*)&sm.u.As[r][k4] = v;
    }
    __syncthreads();
    const int k0 = wave * 256;
    const unsigned short* Bp = w2bp + (size_t)k0*512 + nc0 + lane;
    float acc[8] = {0,0,0,0,0,0,0,0};
#pragma unroll 4
    for (int kk = 0; kk < 256; ++kk) {
      float bv = bl(Bp[(size_t)kk*512]);
#pragma unroll
      for (int r = 0; r < 8; ++r) acc[r] += sm.u.As[r][k0+kk] * bv;
    }
#pragma unroll
    for (int r = 0; r < 8; ++r) sm.u.part[wave][r][lane] = acc[r];
    __syncthreads();
    {
      int r = threadIdx.x >> 6, c = lane;
#pragma unroll
      for (int p2 = 0; p2 < 2; ++p2) {
        int rr = r + p2*4;
        float s2 = sm.u.part[0][rr][c] + sm.u.part[1][rr][c]
                 + sm.u.part[2][rr][c] + sm.u.part[3][rr][c];
        ubuf[(size_t)(r0 + rr)*512 + nc0 + c] = s2 + W2b[nc0 + c];
      }
    }
    return;
  }
  int b = blockIdx.x;
  for (int j = threadIdx.x; j < 512; j += 256) sm.m.sT[j] = tmapv[b*512 + j];
  if (threadIdx.x < 8) sm.m.pv[threadIdx.x] = pvecIn[b*8+threadIdx.x];
  if (threadIdx.x >= 64 && threadIdx.x < 73) sm.m.wm[threadIdx.x-64] = wmod[b*9 + threadIdx.x-64];
  __syncthreads();
  if (threadIdx.x < 8) {
    int l = threadIdx.x;
    sm.m.pd[l] = (l < 7 ? sm.m.pv[l+1] : 0.f) + (l == 0 ? sm.m.pv[0] : 0.f);
  }
  __syncthreads();
  if (pb == 0 && threadIdx.x < 8) {
    int l = threadIdx.x;
    float WP = sm.m.wm[0]+sm.m.wm[1]+sm.m.wm[2]+sm.m.wm[3] + sm.m.wm[6] + sm.m.wm[8];
    float WD = sm.m.wm[4]+sm.m.wm[5] + sm.m.wm[7];
    pvecOut[b*8+l] = WP*sm.m.pv[l] + WD*sm.m.pd[l];
  }

  float W[8][6];
#pragma unroll
  for (int m = 0; m < 8; ++m)
#pragma unroll
    for (int i = 0; i < 6; ++i) W[m][i] = swb[m*6+i];
  float W03 = sm.m.wm[0]+sm.m.wm[1]+sm.m.wm[2]+sm.m.wm[3];
  float W45 = sm.m.wm[4]+sm.m.wm[5];

  float acc6[8], acc7[8];
#pragma unroll
  for (int i = 0; i < 8; ++i) { acc6[i] = 0.f; acc7[i] = 0.f; }

  for (int pi = 0; pi < 2; ++pi) {
    int p = pb*8 + wave*2 + pi;
    if (p < 150) {
      const float* st = stack + ((size_t)b*150 + p)*8;
      float a = 0.f, av2 = 0.f;
#pragma unroll
      for (int l = 0; l < 8; ++l) { float v = st[l]; a += v*sm.m.pv[l]; av2 += v*sm.m.pd[l]; }
      float part[6] = {0,0,0,0,0,0};
#pragma unroll 2
      for (int i = 0; i < 8; ++i) {
        int d = i*64 + lane;
        float x = bl(imapB[((size_t)b*150 + p)*512 + d]);
        float t = sm.m.sT[d];
#pragma unroll
        for (int m = 0; m < 4; ++m) {
          float c1 = W[m][0]*t + W[m][1] + W[m][4] + (W[m][2] + W[m][3]*t)*a;
          float c0 = W[m][1]*t + W[m][5]*t*a;
          part[m] += elu_(c1*x + c0) * c3w[m*512+d];
        }
#pragma unroll
        for (int m = 0; m < 2; ++m) {
          float c1 = W[4+m][0]*t + W[4+m][1] + W[4+m][2]*a + W[4+m][3]*av2
                   + W[4+m][4]*a*av2 + W[4+m][5]*t*(a+av2);
          part[4+m] += elu_(c1*x + W[4+m][1]*t) * c4w[m*512+d];
        }
        float c16 = W[6][0]*t + W[6][1] + W[6][4] + (W[6][2] + W[6][3]*t)*a;
        float c06 = W[6][1]*t + W[6][5]*t*a;
        acc6[i] += elu_(c16*x + c06);
        float c17 = W[7][0]*t + W[7][1] + W[7][2]*a + W[7][3]*av2
                  + W[7][4]*a*av2 + W[7][5]*t*(a+av2);
        acc7[i] += elu_(c17*x + W[7][1]*t);
      }
#pragma unroll
      for (int m = 0; m < 6; ++m) {
#pragma unroll
        for (int off = 32; off; off >>= 1) part[m] += __shfl_down(part[m], off);
        part[m] = __shfl(part[m], 0);
      }
      float r3  = sm.m.wm[0]*(part[0]+c3b[0]) + sm.m.wm[1]*(part[1]+c3b[1])
                + sm.m.wm[2]*(part[2]+c3b[2]) + sm.m.wm[3]*(part[3]+c3b[3]);
      float r45 = sm.m.wm[4]*(part[4]+c4b[0]) + sm.m.wm[5]*(part[5]+c4b[1]);
      if (lane < 8) {
        int l = lane;
        size_t idx = ((size_t)b*150 + p)*8 + l;
        stack[idx] = stack[idx]*(1.f - W03*sm.m.pv[l] - W45*sm.m.pd[l])
                   + sm.m.pv[l]*r3 + sm.m.pd[l]*r45;
      }
    }
  }
#pragma unroll
  for (int i = 0; i < 8; ++i) {
    sm.m.wpart[wave][0][i*64+lane] = acc6[i];
    sm.m.wpart[wave][1][i*64+lane] = acc7[i];
  }
  __syncthreads();
  for (int e = threadIdx.x; e < 1024; e += 256) {
    int which = e >> 9, d = e & 511;
    float s = sm.m.wpart[0][which][d] + sm.m.wpart[1][which][d]
            + sm.m.wpart[2][which][d] + sm.m.wpart[3][which][d];
    atomicAdd(&plt[(size_t)which*32768 + b*512 + d], s * (1.f/150.f));
  }
}

// ---------------------------------------------------------------------------
// batched m67 GEMMs for ALL t: grid (8 colchunks, 8 rowchunks, 18).
// ---------------------------------------------------------------------------
__global__ __launch_bounds__(512)
void ansall_k(const float* __restrict__ plt, const float* __restrict__ tmapv,
              const unsigned short* __restrict__ answp, const float* __restrict__ ansb,
              float* __restrict__ m67o)
{
  const int z = blockIdx.z;          // 0..17
  const int t = z >> 1, zz = z & 1;
  __shared__ __align__(16) float As[8][1024];
  __shared__ float part[8][8][64];
  const int tid = threadIdx.x;
  const int r0 = blockIdx.y*8;
  const int nc0 = blockIdx.x*64;
  const int lane = tid & 63, w = tid >> 6;

  for (int e4 = tid; e4 < 1024; e4 += 512) {
    int r = e4 >> 7, k4 = (e4 & 127) << 2;
    *(float4*)&As[r][k4]     = *(const float4*)&plt[(size_t)z*32768 + (size_t)(r0+r)*512 + k4];
    *(float4*)&As[r][512+k4] = *(const float4*)&tmapv[(size_t)t*32768 + (size_t)(r0+r)*512 + k4];
  }
  __syncthreads();
  {
    const unsigned short* Bp = answp + (size_t)zz*524288
                             + (size_t)(w*128)*512 + nc0 + lane;
    float acc[8] = {0,0,0,0,0,0,0,0};
    int k0 = w*128;
#pragma unroll 8
    for (int kk = 0; kk < 128; ++kk) {
      float bv = bl(Bp[(size_t)kk*512]);
#pragma unroll
      for (int r = 0; r < 8; ++r) acc[r] += As[r][k0+kk]*bv;
    }
#pragma unroll
    for (int r = 0; r < 8; ++r) part[w][r][lane] = acc[r];
  }
  __syncthreads();
  {
    int r = tid >> 6, c = tid & 63;
    float s = 0.f;
#pragma unroll
    for (int w2 = 0; w2 < 8; ++w2) s += part[w2][r][c];
    m67o[(size_t)z*32768 + (size_t)(r0+r)*512 + nc0 + c] = s + ansb[zz*512 + nc0 + c];
  }
}

// ---------------------------------------------------------------------------
// final mem: mem_8 = sum_t coef_t*(w6_t*m6_t + w7_t*m7_t)
// ---------------------------------------------------------------------------
__global__ __launch_bounds__(512)
void memfin_k(const float* __restrict__ woutAll, const float* __restrict__ m67t,
              float* __restrict__ memb)
{
  int b = blockIdx.x;
  int tid = threadIdx.x;
  __shared__ float w6s[9], w7s[9], coef[9];
  if (tid < 9)       w6s[tid] = woutAll[tid*576 + b*9 + 6];
  else if (tid < 18) w7s[tid-9] = woutAll[(tid-9)*576 + b*9 + 7];
  __syncthreads();
  if (tid == 0) {
    float c = 1.f;
    for (int t = 8; t >= 0; --t) { coef[t] = c; c *= (1.f - w6s[t] - w7s[t]); }
  }
  __syncthreads();
  float acc = 0.f;
#pragma unroll
  for (int t = 0; t < 9; ++t) {
    float m6 = m67t[(((size_t)t*2 + 0)*64 + b)*512 + tid];
    float m7 = m67t[(((size_t)t*2 + 1)*64 + b)*512 + tid];
    acc += coef[t]*(w6s[t]*m6 + w7s[t]*m7);
  }
  memb[b*512 + tid] = acc;
}

// ---------------------------------------------------------------------------
__global__ __launch_bounds__(256)
void imp_k(const float* __restrict__ part, float* __restrict__ out)
{
  int lane = threadIdx.x & 63, wave = threadIdx.x >> 6;
  float acc = 0.f;
  for (int i = threadIdx.x; i < 576; i += 256) acc += part[i];
#pragma unroll
  for (int off = 32; off; off >>= 1) acc += __shfl_down(acc, off);
  __shared__ float red[4];
  if (lane == 0) red[wave] = acc;
  __syncthreads();
  if (threadIdx.x == 0) out[0] = red[0]+red[1]+red[2]+red[3];
}

// ---------------------------------------------------------------------------
extern "C" void kernel_launch(void* const* d_in, const int* in_sizes, int n_in,
                              void* d_out, int out_size, void* d_ws, size_t ws_size,
                              hipStream_t stream)
{
  (void)in_sizes; (void)n_in; (void)out_size; (void)ws_size;
  const float* image = (const float*)d_in[0];
  const int*   ques  = (const int*)d_in[1];
  const int*   qlen  = (const int*)d_in[2];
  const float* embedW= (const float*)d_in[3];
  const float* Wi_f  = (const float*)d_in[4];
  const float* Wh_f  = (const float*)d_in[5];
  const float* b_f   = (const float*)d_in[6];
  const float* Wi_b  = (const float*)d_in[7];
  const float* Wh_b  = (const float*)d_in[8];
  const float* b_b   = (const float*)d_in[9];
  const float* W1    = (const float*)d_in[10];
  const float* b1    = (const float*)d_in[11];
  const float* W2w   = (const float*)d_in[12];
  const float* W2b   = (const float*)d_in[13];
  const float* W3    = (const float*)d_in[14];
  const float* c0    = (const float*)d_in[15];
  const float* Wmod  = (const float*)d_in[16];
  const float* ic1w  = (const float*)d_in[17];
  const float* ic1b  = (const float*)d_in[18];
  const float* ic2w  = (const float*)d_in[19];
  const float* ic2b  = (const float*)d_in[20];
  const float* i2mw  = (const float*)d_in[21];
  const float* i2mb  = (const float*)d_in[22];
  const float* t2mw  = (const float*)d_in[23];
  const float* t2mb  = (const float*)d_in[24];
  const float* c3ow  = (const float*)d_in[25];
  const float* c3cw  = (const float*)d_in[26];
  const float* c3cb  = (const float*)d_in[27];
  const float* c4ow  = (const float*)d_in[28];
  const float* c4cw  = (const float*)d_in[29];
  const float* c4cb  = (const float*)d_in[30];
  const float* aow   = (const float*)d_in[31];
  const float* ansW  = (const float*)d_in[32];
  const float* ansb  = (const float*)d_in[33];
  const float* o1w   = (const float*)d_in[34];
  const float* o1b   = (const float*)d_in[35];
  const float* o2w   = (const float*)d_in[36];
  const float* o2b   = (const float*)d_in[37];
  float* out = (float*)d_out;
  float* ws  = (float*)d_ws;

  size_t off = 0;
  auto alloc = [&](size_t n){ float* p = ws + off; off += n; return p; };
  short* imgP  = (short*)alloc(600ull*20*64*8/2);
  short* X1p   = (short*)alloc(600ull*16*64*8/2);
  short* X2p   = (short*)alloc(600ull*16*64*8/2);
  short* w1p   = (short*)alloc(20*32*64*8/2);
  short* w2mp  = (short*)alloc(16*32*64*8/2);
  short* w3mp  = (short*)alloc(16*32*64*8/2);
  short* wifp  = (short*)alloc(10*64*64*8/2);
  short* wibp  = (short*)alloc(10*64*64*8/2);
  short* embp  = (short*)alloc(120ull*10*64*8/2);
  unsigned short* imapB = (unsigned short*)alloc(9600ull*512/2);
  unsigned* t2pp = (unsigned*)alloc(512*256);
  unsigned short* w2bp  = (unsigned short*)alloc(524288/2);
  unsigned short* answp = (unsigned short*)alloc(1048576/2);
  float* xWfb  = alloc(64ull*30*1024);
  float* xWbb  = alloc(64ull*30*1024);
  float* lout  = alloc(64ull*30*512);
  float* qbuf  = alloc(64*512);
  float* stck  = alloc(64*150*8);
  float* pvecA = alloc(64*8);
  float* pvecB = alloc(64*8);
  float* memb  = alloc(64*512);
  float* cprev = alloc(64*512);
  float* tmp1a = alloc(9ull*64*512);
  float* ubuf  = alloc(64*512);
  float* wmwA  = alloc(9*64*9);
  float* impp  = alloc(9*64);
  float* swb   = alloc(48);
  float* pl    = alloc(9ull*2*64*512);
  float* m67t  = alloc(9ull*2*64*512);
  float* tmapv = alloc(9ull*64*512);
  float* h1b   = alloc(64*1024);
  unsigned* whT = (unsigned*)alloc(2ull*1024*128);       // f16-pair packed Wh^T
  float* hbufW  = alloc(32768);                          // 2 ping x 2 d x 4 g x 16 x 256 f16
  int*   flagsI = (int*)alloc(256);                      // step sync flags

  // one dispatch: init + ALL independent packs (incl. f16 WhT, bf16 W2/ansW)
  megapack_k<<<12036, 256, 0, stream>>>(
      c0, c3ow, c4ow, aow, stck, pvecA, memb, cprev, swb, pl,
      Wh_f, Wh_b, whT, hbufW, flagsI,
      ic1w, w1p, ic2w, w2mp, i2mw, w3mp, Wi_f, wifp, Wi_b, wibp,
      image, imgP, embedW, ques, embp, t2mw, t2pp,
      W2w, w2bp, ansW, answp);

  // both embed GEMMs first (LSTM depends on xW)
  gemmM_k<<<dim3(16,30,2), 256, 0, stream>>>(embp, embp, wifp, wibp, b_f, b_b,
                                             xWfb, xWbb, 10, 64, 1024, 0, 0, 0);

  // MERGED: LSTM (32 blocks) + conv1 (1200 blocks) — conv1 hides under LSTM
  lstmc1_k<<<1232, 256, 0, stream>>>(xWfb, xWbb, whT, qlen,
                                     (unsigned long long*)hbufW, flagsI,
                                     lout, qbuf,
                                     imgP, w1p, ic1b, X1p);

  // conv2, conv3 (depend on conv1)
  gemmM_k<<<dim3(8,150,1), 256, 0, stream>>>(X1p, X1p, w2mp, w2mp, ic2b, ic2b,
                                             X2p, X2p, 16, 32, 512, 1, 0, 16);
  gemmM_k<<<dim3(8,150,1), 256, 0, stream>>>(X2p, X2p, w3mp, w3mp, i2mb, i2mb,
                                             imapB, imapB, 16, 32, 512, 2, 0, 0);

  // tmp1all[t] = q @ W1[t] + b1 (all 9 t)
  gemm64b_k<<<dim3(8,8,9), 512, 0, stream>>>(
      qbuf, 0, 9, (const float*)nullptr, 0,
      W1, 262144, b1, 0, tmp1a, 32768, 512, 0);
  // u for t=0 (fp32 W2)
  gemm64b_k<<<dim3(8,8,1), 512, 0, stream>>>(
      tmp1a, 0, 9, cprev, 512, W2w, 0, W2b, 0, ubuf, 0, 512, 0);

  for (int t = 0; t < 9; ++t) {
    float* pvIn  = (t & 1) ? pvecB : pvecA;
    float* pvOut = (t & 1) ? pvecA : pvecB;
    kcattn3_k<<<64, 1024, 0, stream>>>(ubuf, Wmod, lout, W3, t2pp, t2mb,
                                       wmwA, impp, cprev,
                                       tmapv + (size_t)t*32768, t);
    modu_k<<<dim3(64,20), 256, 0, stream>>>(
        imapB, tmapv + (size_t)t*32768, stck, pvIn, pvOut, swb,
        c3cw, c3cb, c4cw, c4cb,
        wmwA + (size_t)t*576, pl + (size_t)t*65536,
        tmp1a + (size_t)(t < 8 ? t+1 : 0)*32768, cprev, w2bp, W2b, ubuf,
        (t < 8) ? 1 : 0);
  }

  // all 18 m67 GEMMs in ONE dispatch (off the sequential critical path)
  ansall_k<<<dim3(8,8,18), 512, 0, stream>>>(pl, tmapv, answp, ansb, m67t);

  // final mem blend, then h1 = elu([q, mem] @ out1 + b); logits = h1 @ out2 + b
  memfin_k<<<64, 512, 0, stream>>>(wmwA, m67t, memb);
  gemm64b_k<<<dim3(16,8,1), 512, 0, stream>>>(
      qbuf, 0, 9, memb, 512, o1w, 0, o1b, 0, h1b, 0, 1024, 1);
  gemm64b_k<<<dim3(1,8,1), 512, 0, stream>>>(
      h1b, 0, 10, (const float*)nullptr, 0, o2w, 0, o2b, 0, out, 0, 32, 0);
  imp_k<<<1, 256, 0, stream>>>(impp, out + 2048);
}

// Round 12
// 786.986 us; speedup vs baseline: 1.2042x; 1.0305x over previous
//
#include <hip/hip_runtime.h>
#include <hip/hip_fp16.h>
#include <math.h>

#define DEV __device__ __forceinline__

DEV float fexp(float x){ return __expf(x); }
DEV float elu_(float x){ return x > 0.f ? x : fexp(x) - 1.f; }
DEV float sigm_(float x){ return 1.f/(1.f + fexp(-x)); }
DEV float tanh_(float x){ float e = fexp(2.f*x); return 1.f - 2.f/(e + 1.f); }
DEV unsigned bf16r(float x){ unsigned u = __float_as_uint(x);
  return (u + 0x7fffu + ((u>>16)&1u)) >> 16; }
DEV float blo(unsigned u){ return __uint_as_float(u << 16); }
DEV float bhi(unsigned u){ return __uint_as_float(u & 0xffff0000u); }
DEV float bl(unsigned short u){ return __uint_as_float(((unsigned)u) << 16); }

using frag  = __attribute__((ext_vector_type(8))) short;     // 8 bf16 (4 VGPRs)
using fragh = __attribute__((ext_vector_type(8))) _Float16;  // 8 f16  (4 VGPRs)
using f32x4 = __attribute__((ext_vector_type(4))) float;     // MFMA acc

// coherent (sc0 sc1 = device-coherent path) 16B load WITH completion wait
DEV uint4 cload16w(const void* p){
  uint4 r;
  asm volatile("global_load_dwordx4 %0, %1, off sc0 sc1\n\ts_waitcnt vmcnt(0)"
               : "=v"(r) : "v"(p) : "memory");
  return r;
}
// coherent 16B load, NO wait (caller does one s_waitcnt vmcnt(0) for the batch)
DEV uint4 cload16nw(const void* p){
  uint4 r;
  asm volatile("global_load_dwordx4 %0, %1, off sc0 sc1"
               : "=v"(r) : "v"(p) : "memory");
  return r;
}
// coherent 4B store (device-coherent path, pipelined)
DEV void cstore4(void* p, float v){
  asm volatile("global_store_dword %0, %1, off sc0 sc1"
               :: "v"(p), "v"(v) : "memory");
}

// ---------------------------------------------------------------------------
// device pack helpers
// ---------------------------------------------------------------------------
DEV void d_packB(const float* __restrict__ W, short* __restrict__ Bp,
                 int KC, int Ng, int Ksrc, int N, int trans, int idx)
{
  if (idx >= KC*Ng*64) return;
  int lane = idx & 63;
  int g    = (idx >> 6) % Ng;
  int kc   = idx / (64*Ng);
  int n = g*16 + (lane & 15);
  int kb = kc*32 + ((lane >> 4) << 3);
  unsigned o[4];
#pragma unroll
  for (int jj = 0; jj < 4; ++jj) {
    int k0 = kb + 2*jj;
    float v0 = (k0   < Ksrc) ? (trans ? W[(size_t)n*Ksrc + k0]   : W[(size_t)(k0)*N + n])   : 0.f;
    float v1 = (k0+1 < Ksrc) ? (trans ? W[(size_t)n*Ksrc + k0+1] : W[(size_t)(k0+1)*N + n]) : 0.f;
    o[jj] = bf16r(v0) | (bf16r(v1) << 16);
  }
  *(uint4*)(Bp + (size_t)idx*8) = make_uint4(o[0], o[1], o[2], o[3]);
}

DEV void d_packImg(const float* __restrict__ image, short* __restrict__ Ap, int idx)
{
  int lane = idx & 63;
  int kc   = (idx >> 6) % 20;
  int mt   = idx / 1280;
  int row = mt*16 + (lane & 15);
  int b = row / 150, p = row % 150;
  int cb = kc*32 + ((lane >> 4) << 3);
  unsigned o[4];
#pragma unroll
  for (int jj = 0; jj < 4; ++jj) {
    float v0 = image[((size_t)b*640 + cb + 2*jj    )*150 + p];
    float v1 = image[((size_t)b*640 + cb + 2*jj + 1)*150 + p];
    o[jj] = bf16r(v0) | (bf16r(v1) << 16);
  }
  *(uint4*)(Ap + (size_t)idx*8) = make_uint4(o[0], o[1], o[2], o[3]);
}

DEV void d_packEmb(const float* __restrict__ embedW, const int* __restrict__ ques,
                   short* __restrict__ Ap, int idx)
{
  int lane = idx & 63;
  int kc   = (idx >> 6) % 10;
  int mt   = idx / 640;
  int row = mt*16 + (lane & 15);
  int q = ques[row];
  int kb = kc*32 + ((lane >> 4) << 3);
  unsigned o[4];
#pragma unroll
  for (int jj = 0; jj < 4; ++jj) {
    int k0 = kb + 2*jj;
    float v0 = (k0   < 300) ? embedW[(size_t)q*300 + k0]   : 0.f;
    float v1 = (k0+1 < 300) ? embedW[(size_t)q*300 + k0+1] : 0.f;
    o[jj] = bf16r(v0) | (bf16r(v1) << 16);
  }
  *(uint4*)(Ap + (size_t)idx*8) = make_uint4(o[0], o[1], o[2], o[3]);
}

// ---------------------------------------------------------------------------
// ONE dispatch for all independent pre-stage work
// ---------------------------------------------------------------------------
__global__ __launch_bounds__(256)
void megapack_k(const float* __restrict__ c0, const float* __restrict__ c3ow,
                const float* __restrict__ c4ow, const float* __restrict__ aow,
                float* __restrict__ stack, float* __restrict__ pvecA,
                float* __restrict__ mem, float* __restrict__ cprev,
                float* __restrict__ swb, float* __restrict__ pl,
                const float* __restrict__ Whf, const float* __restrict__ Whb,
                unsigned* __restrict__ whT,
                float* __restrict__ hbufz, int* __restrict__ flagz,
                const float* __restrict__ ic1w, short* __restrict__ w1p,
                const float* __restrict__ ic2w, short* __restrict__ w2mp,
                const float* __restrict__ i2mw, short* __restrict__ w3mp,
                const float* __restrict__ Wif, short* __restrict__ wifp,
                const float* __restrict__ Wib, short* __restrict__ wibp,
                const float* __restrict__ image, short* __restrict__ imgP,
                const float* __restrict__ embedW, const int* __restrict__ ques,
                short* __restrict__ embp,
                const float* __restrict__ t2mw, unsigned* __restrict__ t2pp,
                const float* __restrict__ W2w, unsigned short* __restrict__ w2bp,
                const float* __restrict__ ansW, unsigned short* __restrict__ answp)
{
  const int bx = blockIdx.x, tid = threadIdx.x;
  if (bx < 320) {
    int idx = bx*256 + tid;
    int stride = 320*256;
    for (int i = idx; i < 64*150*8; i += stride) stack[i] = 0.f;
    for (int i = idx; i < 64*8;    i += stride) pvecA[i] = ((i & 7) == 0) ? 1.f : 0.f;
    for (int i = idx; i < 64*512;  i += stride) mem[i] = 0.f;
    for (int i = idx; i < 64*512;  i += stride) cprev[i] = c0[i & 511];
    for (int i = idx; i < 9*2*64*512; i += stride) pl[i] = 0.f;
    for (int i = idx; i < 32768;   i += stride) hbufz[i] = 0.f;  // hbuf (f16 pairs)
    if (idx < 256) flagz[idx] = 0;                               // sync flags
    if (idx < 8) {
      const float* ow = (idx < 4) ? (c3ow + idx*6)
                      : (idx < 6) ? (c4ow + (idx-4)*6)
                                  : (aow  + (idx-6)*6);
      float mx = ow[0];
      for (int m = 1; m < 6; ++m) mx = fmaxf(mx, ow[m]);
      float e[6]; float s = 0.f;
      for (int m = 0; m < 6; ++m) { e[m] = fexp(ow[m]-mx); s += e[m]; }
      for (int m = 0; m < 6; ++m) swb[idx*6+m] = e[m]/s;
    }
  } else if (bx < 1344) {
    // WhT: [d][zc 0..1023][k-pair 0..127] packed f16 pairs (transposed Wh)
    int idx = (bx-320)*256 + tid;
    int dd  = idx >> 17;
    int rem = idx & 131071;
    int kp  = rem >> 10;
    int zc  = rem & 1023;
    const float* Wh = dd ? Whb : Whf;
    __half2 hv = __floats2half2_rn(Wh[(size_t)(2*kp)*1024 + zc],
                                   Wh[(size_t)(2*kp+1)*1024 + zc]);
    whT[((size_t)dd << 17) + (zc << 7) + kp] = *(unsigned*)&hv;
  } else if (bx < 1504) {
    d_packB(ic1w, w1p, 20, 32, 640, 512, 1, (bx-1344)*256 + tid);
  } else if (bx < 1632) {
    d_packB(ic2w, w2mp, 16, 32, 512, 512, 1, (bx-1504)*256 + tid);
  } else if (bx < 1760) {
    d_packB(i2mw, w3mp, 16, 32, 512, 512, 1, (bx-1632)*256 + tid);
  } else if (bx < 1920) {
    d_packB(Wif, wifp, 10, 64, 300, 1024, 0, (bx-1760)*256 + tid);
  } else if (bx < 2080) {
    d_packB(Wib, wibp, 10, 64, 300, 1024, 0, (bx-1920)*256 + tid);
  } else if (bx < 5080) {
    d_packImg(image, imgP, (bx-2080)*256 + tid);
  } else if (bx < 5380) {
    d_packEmb(embedW, ques, embp, (bx-5080)*256 + tid);
  } else if (bx < 5892) {
    int idx = (bx-5380)*256 + tid;   // 512*256
    int k = idx >> 8, c = idx & 255;
    t2pp[idx] = bf16r(t2mw[(size_t)k*512 + c]) | (bf16r(t2mw[(size_t)k*512 + 256 + c]) << 16);
  } else if (bx < 7940) {
    int i = (bx-5892)*256 + tid;     // 524288
    w2bp[i] = (unsigned short)bf16r(W2w[i]);
  } else {
    int i = (bx-7940)*256 + tid;     // 1048576
    answp[i] = (unsigned short)bf16r(ansW[i]);
  }
}

// ---------------------------------------------------------------------------
// MFMA GEMM, dual problem sets via blockIdx.z.
// mode 0: fp32 row-major; mode 1: bf16 A-pack; mode 2: bf16 row-major
// ---------------------------------------------------------------------------
__global__ __launch_bounds__(256)
void gemmM_k(const short* __restrict__ ApA, const short* __restrict__ ApB,
             const short* __restrict__ BpA, const short* __restrict__ BpB,
             const float* __restrict__ biasA, const float* __restrict__ biasB,
             void* __restrict__ CoutA, void* __restrict__ CoutB,
             int KC, int Ng, int N, int mode, int act, int KCout)
{
  __shared__ float lds[4][16][68];
  const int z = blockIdx.z;
  const short* Ap = z ? ApB : ApA;
  const short* Bp = z ? BpB : BpA;
  const float* bias = z ? biasB : biasA;
  void* Cout = z ? CoutB : CoutA;
  const int tid = threadIdx.x, lane = tid & 63, w = tid >> 6;
  const int mt = blockIdx.y*4 + w;
  const int ncol0 = blockIdx.x*64;
  const short* Abase = Ap + (((size_t)mt*KC) << 9) + lane*8;
  const short* Bbase = Bp + (((size_t)blockIdx.x*4) << 9) + lane*8;
  f32x4 acc0 = {0.f,0.f,0.f,0.f}, acc1 = acc0, acc2 = acc0, acc3 = acc0;
#pragma unroll 2
  for (int kc = 0; kc < KC; ++kc) {
    frag a = *(const frag*)(Abase + ((size_t)kc << 9));
    const short* bk = Bbase + (((size_t)kc*Ng) << 9);
    frag b0 = *(const frag*)(bk);
    frag b1 = *(const frag*)(bk + 512);
    frag b2 = *(const frag*)(bk + 1024);
    frag b3 = *(const frag*)(bk + 1536);
    acc0 = __builtin_amdgcn_mfma_f32_16x16x32_bf16(a, b0, acc0, 0, 0, 0);
    acc1 = __builtin_amdgcn_mfma_f32_16x16x32_bf16(a, b1, acc1, 0, 0, 0);
    acc2 = __builtin_amdgcn_mfma_f32_16x16x32_bf16(a, b2, acc2, 0, 0, 0);
    acc3 = __builtin_amdgcn_mfma_f32_16x16x32_bf16(a, b3, acc3, 0, 0, 0);
  }
  {
    int colb = lane & 15, rowb = (lane >> 4)*4;
#pragma unroll
    for (int r = 0; r < 4; ++r) {
      lds[w][rowb+r][ 0+colb] = acc0[r];
      lds[w][rowb+r][16+colb] = acc1[r];
      lds[w][rowb+r][32+colb] = acc2[r];
      lds[w][rowb+r][48+colb] = acc3[r];
    }
  }
  __syncthreads();
  if (mode == 0) {
    float* C = (float*)Cout;
    int mloc = lane >> 2, q4 = lane & 3;
    size_t rowoff = (size_t)(mt*16 + mloc)*N + ncol0 + q4*16;
#pragma unroll
    for (int i = 0; i < 4; ++i) {
      float4 v = *(float4*)&lds[w][mloc][q4*16 + i*4];
      const float* bp = bias + ncol0 + q4*16 + i*4;
      v.x += bp[0]; v.y += bp[1]; v.z += bp[2]; v.w += bp[3];
      if (act) { v.x = elu_(v.x); v.y = elu_(v.y); v.z = elu_(v.z); v.w = elu_(v.w); }
      *(float4*)&C[rowoff + i*4] = v;
    }
  } else if (mode == 1) {
    short* C = (short*)Cout;
    int m = lane & 15, qb = (lane >> 4)*8;
#pragma unroll
    for (int h = 0; h < 2; ++h) {
      int nl = h*32 + qb;
      unsigned o[4];
#pragma unroll
      for (int jj = 0; jj < 4; ++jj) {
        float v0 = lds[w][m][nl + 2*jj]     + bias[ncol0 + nl + 2*jj];
        float v1 = lds[w][m][nl + 2*jj + 1] + bias[ncol0 + nl + 2*jj + 1];
        if (act) { v0 = elu_(v0); v1 = elu_(v1); }
        o[jj] = bf16r(v0) | (bf16r(v1) << 16);
      }
      *(uint4*)(C + (((size_t)mt*KCout + (ncol0 >> 5) + h) << 9) + lane*8)
          = make_uint4(o[0], o[1], o[2], o[3]);
    }
  } else {
    unsigned short* C = (unsigned short*)Cout;
    int row = lane >> 2, cb = (lane & 3)*16;
#pragma unroll
    for (int h = 0; h < 2; ++h) {
      unsigned o[4];
#pragma unroll
      for (int jj = 0; jj < 4; ++jj) {
        float v0 = lds[w][row][cb + h*8 + 2*jj]     + bias[ncol0 + cb + h*8 + 2*jj];
        float v1 = lds[w][row][cb + h*8 + 2*jj + 1] + bias[ncol0 + cb + h*8 + 2*jj + 1];
        if (act) { v0 = elu_(v0); v1 = elu_(v1); }
        o[jj] = bf16r(v0) | (bf16r(v1) << 16);
      }
      *(uint4*)&C[(size_t)(mt*16 + row)*N + ncol0 + cb + h*8]
          = make_uint4(o[0], o[1], o[2], o[3]);
    }
  }
}

// ---------------------------------------------------------------------------
// 64-row batch GEMM, K-split across waves
// ---------------------------------------------------------------------------
__global__ __launch_bounds__(512)
void gemm64b_k(const float* __restrict__ A1, long zA1, int K1log,
               const float* __restrict__ A2, int K2,
               const float* __restrict__ B, long zB,
               const float* __restrict__ bias, int zbias,
               float* __restrict__ C, long zC, int N, int act)
{
  const int K1 = 1 << K1log;
  const int Kt = K1 + K2;
  __shared__ __align__(16) float As[8][1024];
  __shared__ float part[8][8][64];
  const int tid = threadIdx.x;
  const int z = blockIdx.z;
  const int r0 = blockIdx.y*8;
  {
    const float* a1 = A1 + (size_t)z*zA1;
    const int nf4 = (8*K1) >> 2;
    for (int e4 = tid; e4 < nf4; e4 += 512) {
      int r = e4 >> (K1log-2);
      int k4 = (e4 & ((K1>>2)-1)) << 2;
      *(float4*)&As[r][k4] = *(const float4*)&a1[(size_t)(r0+r)*K1 + k4];
    }
    if (K2 > 0) {
      for (int e4 = tid; e4 < 1024; e4 += 512) {
        int r = e4 >> 7;
        int k4 = (e4 & 127) << 2;
        *(float4*)&As[r][K1+k4] = *(const float4*)&A2[(size_t)(r0+r)*512 + k4];
      }
    }
  }
  __syncthreads();
  const int lane = tid & 63, w = tid >> 6;
  const int n = blockIdx.x*64 + lane;
  const bool nv = n < N;
  const int kseg = Kt >> 3;
  const int k0 = w*kseg;
  const float* Bp = B + (size_t)z*zB + (size_t)k0*N + (nv ? n : 0);
  float acc[8] = {0,0,0,0,0,0,0,0};
#pragma unroll 8
  for (int kk = 0; kk < kseg; ++kk) {
    float bv = nv ? Bp[(size_t)kk*N] : 0.f;
    int k = k0 + kk;
#pragma unroll
    for (int r = 0; r < 8; ++r) acc[r] += As[r][k]*bv;
  }
#pragma unroll
  for (int r = 0; r < 8; ++r) part[w][r][lane] = acc[r];
  __syncthreads();
  {
    int r = tid >> 6, c = tid & 63;
    int nn = blockIdx.x*64 + c;
    if (nn < N) {
      float s = 0.f;
#pragma unroll
      for (int w2 = 0; w2 < 8; ++w2) s += part[w2][r][c];
      s += bias ? bias[(size_t)z*zbias + nn] : 0.f;
      if (act == 1) s = elu_(s);
      C[(size_t)z*zC + (size_t)(r0+r)*N + nn] = s;
    }
  }
}

// ---------------------------------------------------------------------------
// MERGED: MFMA bidirectional masked LSTM (blocks 0..31, round-4 protocol)
// + conv1 GEMM (blocks 32..1231) running concurrently on the idle 224 CUs.
// ---------------------------------------------------------------------------
__global__ __launch_bounds__(256)
void lstmc1_k(const float* __restrict__ xWf, const float* __restrict__ xWb,
              const unsigned* __restrict__ whT, const int* __restrict__ qlen,
              unsigned long long* __restrict__ hbuf, int* __restrict__ flags,
              float* __restrict__ lstm_out, float* __restrict__ qout,
              const short* __restrict__ c1Ap, const short* __restrict__ c1Bp,
              const float* __restrict__ c1bias, short* __restrict__ c1out)
{
  const int tid = threadIdx.x, lane = tid & 63, w = tid >> 6;
  __shared__ union {
    unsigned short Wl[65536];                 // 128 KiB (lstm weights)
    float lds[4][16][68];                     // conv epilogue staging
  } sm;

  if (blockIdx.x >= 32) {
    // ================= conv1 branch: X1p = elu(imgP @ w1p + ic1b) ==========
    const int bx2 = (int)blockIdx.x - 32;     // 0..1199
    const int mt = (bx2 >> 3)*4 + w;          // 150 y-tiles * 4 waves
    const int ncol0 = (bx2 & 7)*64;
    const short* Abase = c1Ap + (((size_t)mt*20) << 9) + lane*8;
    const short* Bbase = c1Bp + (((size_t)(bx2 & 7)*4) << 9) + lane*8;
    f32x4 acc0 = {0.f,0.f,0.f,0.f}, acc1 = acc0, acc2 = acc0, acc3 = acc0;
#pragma unroll 2
    for (int kc = 0; kc < 20; ++kc) {
      frag a = *(const frag*)(Abase + ((size_t)kc << 9));
      const short* bk = Bbase + (((size_t)kc*32) << 9);
      frag b0 = *(const frag*)(bk);
      frag b1 = *(const frag*)(bk + 512);
      frag b2 = *(const frag*)(bk + 1024);
      frag b3 = *(const frag*)(bk + 1536);
      acc0 = __builtin_amdgcn_mfma_f32_16x16x32_bf16(a, b0, acc0, 0, 0, 0);
      acc1 = __builtin_amdgcn_mfma_f32_16x16x32_bf16(a, b1, acc1, 0, 0, 0);
      acc2 = __builtin_amdgcn_mfma_f32_16x16x32_bf16(a, b2, acc2, 0, 0, 0);
      acc3 = __builtin_amdgcn_mfma_f32_16x16x32_bf16(a, b3, acc3, 0, 0, 0);
    }
    {
      int colb = lane & 15, rowb = (lane >> 4)*4;
#pragma unroll
      for (int r = 0; r < 4; ++r) {
        sm.lds[w][rowb+r][ 0+colb] = acc0[r];
        sm.lds[w][rowb+r][16+colb] = acc1[r];
        sm.lds[w][rowb+r][32+colb] = acc2[r];
        sm.lds[w][rowb+r][48+colb] = acc3[r];
      }
    }
    __syncthreads();
    {
      int m = lane & 15, qb = (lane >> 4)*8;
#pragma unroll
      for (int h = 0; h < 2; ++h) {
        int nl = h*32 + qb;
        unsigned o[4];
#pragma unroll
        for (int jj = 0; jj < 4; ++jj) {
          float v0 = elu_(sm.lds[w][m][nl + 2*jj]     + c1bias[ncol0 + nl + 2*jj]);
          float v1 = elu_(sm.lds[w][m][nl + 2*jj + 1] + c1bias[ncol0 + nl + 2*jj + 1]);
          o[jj] = bf16r(v0) | (bf16r(v1) << 16);
        }
        *(uint4*)(c1out + (((size_t)mt*16 + (ncol0 >> 5) + h) << 9) + lane*8)
            = make_uint4(o[0], o[1], o[2], o[3]);
      }
    }
    return;
  }

  // ===================== LSTM branch (round-4 protocol) ====================
  const int bx = blockIdx.x;
  const int d = bx & 1, g = (bx >> 1) & 3, n = bx >> 3;
  const int q = lane >> 4, cl = lane & 15;

#pragma unroll 4
  for (int rb = 0; rb < 32; ++rb) {
    int lcrow = rb*8 + (tid >> 5);
    int gt = lcrow >> 6, c = lcrow & 63;
    int zc = gt*256 + n*64 + c;
    uint4 v = *(const uint4*)(whT + (((size_t)d*1024 + zc) << 7) + ((tid & 31) << 2));
    int byteoff = (lcrow << 9) + ((((tid & 31) << 4)) ^ ((lcrow & 7) << 4));
    *(uint4*)((char*)sm.Wl + byteoff) = v;
  }

  const float* xW = d ? xWb : xWf;
  const int b   = g*16 + cl;                 // this lane's batch
  const int c4  = w*16 + q*4;                // local col base within slice
  const int hc4 = n*64 + c4;                 // global h-col base (4 consecutive)
  const int len = qlen[b];
  float cst[4] = {0.f,0.f,0.f,0.f}, hst[4] = {0.f,0.f,0.f,0.f};
  int* flg = flags + ((d*4 + g) << 2);       // 4 flags for this (d,g) group
  const int bofs = (cl & 7) << 4;
  __syncthreads();

  for (int ss = 0; ss < 30; ++ss) {
    const int s = d ? (29 - ss) : ss;
    const float* xr = xW + (size_t)b*30720 + (size_t)s*1024 + hc4;
    f32x4 xwv[4];
#pragma unroll
    for (int gt = 0; gt < 4; ++gt) xwv[gt] = *(const f32x4*)(xr + gt*256);

    if (ss > 0) {
      for (;;) {
        uint4 f4 = cload16w(flg);   // all 4 flags in ONE coherent 16B load
        if ((int)f4.x >= ss && (int)f4.y >= ss &&
            (int)f4.z >= ss && (int)f4.w >= ss) break;
      }
      __builtin_amdgcn_sched_barrier(0);
    }
    // B = h^T from hbuf: 8 pipelined coherent 16B loads, ONE vmcnt wait
    const char* hbr = (const char*)(hbuf + ((size_t)(((ss & 1)*2 + d)*4 + g) << 9))
                    + (cl << 9) + (q << 4);
    union { uint4 u; fragh f; } hv[8];
#pragma unroll
    for (int ks = 0; ks < 8; ++ks) hv[ks].u = cload16nw(hbr + (ks << 6));
    asm volatile("s_waitcnt vmcnt(0)" ::: "memory");
    __builtin_amdgcn_sched_barrier(0);

    f32x4 acc0 = {0.f,0.f,0.f,0.f}, acc1 = acc0, acc2 = acc0, acc3 = acc0;
#pragma unroll
    for (int ks = 0; ks < 8; ++ks) {
      const int kb = ((ks << 6) + (q << 4)) ^ bofs;
      const char* wb = (const char*)sm.Wl + ((w*16 + cl) << 9) + kb;
      fragh a0 = *(const fragh*)(wb);
      fragh a1 = *(const fragh*)(wb + (64 << 9));
      fragh a2 = *(const fragh*)(wb + (128 << 9));
      fragh a3 = *(const fragh*)(wb + (192 << 9));
      acc0 = __builtin_amdgcn_mfma_f32_16x16x32_f16(a0, hv[ks].f, acc0, 0, 0, 0);
      acc1 = __builtin_amdgcn_mfma_f32_16x16x32_f16(a1, hv[ks].f, acc1, 0, 0, 0);
      acc2 = __builtin_amdgcn_mfma_f32_16x16x32_f16(a2, hv[ks].f, acc2, 0, 0, 0);
      acc3 = __builtin_amdgcn_mfma_f32_16x16x32_f16(a3, hv[ks].f, acc3, 0, 0, 0);
    }
    const bool m = s < len;
    f32x4 lo4;
    float hvv[4];
#pragma unroll
    for (int r = 0; r < 4; ++r) {
      float iv = acc0[r] + xwv[0][r];
      float fv = acc1[r] + xwv[1][r];
      float gv = acc2[r] + xwv[2][r];
      float o_ = acc3[r] + xwv[3][r];
      float cn = sigm_(fv)*cst[r] + sigm_(iv)*tanh_(gv);
      float hn = sigm_(o_)*tanh_(cn);
      float hk = m ? hn : hst[r];
      cst[r] = m ? cn : cst[r];
      hst[r] = hk;
      hvv[r] = hk;
      lo4[r] = m ? hn : 0.f;
    }
    unsigned long long* hbw = hbuf + ((size_t)((((ss & 1) ^ 1)*2 + d)*4 + g) << 9);
    union { unsigned long long u; __half2 h2[2]; } hp;
    hp.h2[0] = __floats2half2_rn(hvv[0], hvv[1]);
    hp.h2[1] = __floats2half2_rn(hvv[2], hvv[3]);
    __hip_atomic_store(hbw + cl*64 + (hc4 >> 2), hp.u,
                       __ATOMIC_RELAXED, __HIP_MEMORY_SCOPE_AGENT);
    *(f32x4*)(lstm_out + (((size_t)b*30 + s) << 9) + (d << 8) + hc4) = lo4;
    asm volatile("s_waitcnt vmcnt(0)" ::: "memory");
    __syncthreads();
    if (tid == 0)
      __hip_atomic_store(&flg[n], ss + 1, __ATOMIC_RELAXED, __HIP_MEMORY_SCOPE_AGENT);
  }
  *(f32x4*)(qout + ((size_t)b << 9) + (d << 8) + hc4) =
      f32x4{hst[0], hst[1], hst[2], hst[3]};
}

// ---------------------------------------------------------------------------
// MERGED per-t step: 448 blocks x 1024 threads.
//  blocks [0,64):    kcattn(t)  (coherent cout store, then flag[b]=t+1)
//  blocks [64,128):  u(t+1) GEMM (spins on flags for its 8 rows)
//  blocks [128,448): modules(t-1) (independent)
// Deadlock-free: <=64 spinners, >=256-block residency, all other blocks
// terminate unconditionally -> kcattn blocks always get scheduled.
// ---------------------------------------------------------------------------
__global__ __launch_bounds__(1024)
void step_k(const float* __restrict__ u, const float* __restrict__ Wmod,
            const float* __restrict__ lstm_out, const float* __restrict__ W3,
            const unsigned* __restrict__ t2pp, const float* __restrict__ t2mb,
            float* __restrict__ woutAll, float* __restrict__ imp_part,
            float* __restrict__ cprev, float* __restrict__ tmapv_k, int t,
            const float* __restrict__ tmp1n, const unsigned short* __restrict__ w2bp,
            const float* __restrict__ W2b, float* __restrict__ ubuf,
            int* __restrict__ flags2, int do_u,
            const unsigned short* __restrict__ imapB, const float* __restrict__ tmapv_m,
            float* __restrict__ stack, const float* __restrict__ pvecIn,
            float* __restrict__ pvecOut, const float* __restrict__ swb,
            const float* __restrict__ c3w, const float* __restrict__ c3b,
            const float* __restrict__ c4w, const float* __restrict__ c4b,
            const float* __restrict__ wm_m, float* __restrict__ plt, int do_mod)
{
  const int tid = threadIdx.x;
  const int lane = tid & 63, wave = tid >> 6;   // 16 waves
  __shared__ union {
    struct {  // kcattn
      float ush[512]; float sC[512]; float cpart[512]; float tpart[4][512];
      float wl[9]; float sc[32], at[32];
    } k;
    struct {  // u GEMM
      __align__(16) float As[8][1024]; float part[16][8][64];
    } uu;
    struct {  // modules
      float sT[512]; float pv[8], pd[8], wm[9]; float wpart[16][2][512];
    } m;
  } sm;

  if (blockIdx.x < 64) {
    // ======================= kcattn(t), b = blockIdx.x =====================
    if (t >= 9) return;
    int b = blockIdx.x;
    if (tid < 512) sm.k.ush[tid] = u[b*512 + tid];
    __syncthreads();
    for (int s = wave; s < 30; s += 16) {
      float acc = 0.f;
      const float* lo = lstm_out + ((size_t)b*30 + s)*512;
#pragma unroll
      for (int h = lane; h < 512; h += 64) acc += lo[h]*sm.k.ush[h]*W3[h];
#pragma unroll
      for (int off = 32; off; off >>= 1) acc += __shfl_down(acc, off);
      if (lane == 0) sm.k.sc[s] = acc;
    }
    if (wave < 9) {
      float acc = 0.f;
#pragma unroll
      for (int k = lane; k < 512; k += 64) acc += sm.k.ush[k]*Wmod[k*9+wave];
#pragma unroll
      for (int off = 32; off; off >>= 1) acc += __shfl_down(acc, off);
      if (lane == 0) sm.k.wl[wave] = acc;
    }
    __syncthreads();
    if (tid == 0) {
      float mx = sm.k.wl[0];
      for (int m = 1; m < 9; ++m) mx = fmaxf(mx, sm.k.wl[m]);
      float s = 0.f;
      for (int m = 0; m < 9; ++m) s += fexp(sm.k.wl[m]-mx);
      float ls = logf(s);
      float ent = 0.f;
      for (int m = 0; m < 9; ++m) {
        float l = sm.k.wl[m]-mx-ls;
        float w = fexp(l);
        woutAll[t*576 + b*9 + m] = w;
        ent -= w*l;
      }
      imp_part[t*64+b] = ent;
    }
    if (wave == 1) {
      float v = (lane < 30) ? sm.k.sc[lane] : -3.4e38f;
      float mx = v;
#pragma unroll
      for (int off = 32; off; off >>= 1) mx = fmaxf(mx, __shfl_xor(mx, off));
      float e = (lane < 30) ? fexp(v-mx) : 0.f;
      float ssum = e;
#pragma unroll
      for (int off = 32; off; off >>= 1) ssum += __shfl_xor(ssum, off);
      if (lane < 30) sm.k.at[lane] = e/ssum;
    }
    __syncthreads();
    // context: 2-way s-split per h; cout written COHERENTLY (u-blocks read it)
    {
      int h = tid & 511, seg = tid >> 9;
      float acc = 0.f;
      int s0 = seg ? 15 : 0, s1 = seg ? 30 : 15;
      for (int s = s0; s < s1; ++s) acc += sm.k.at[s]*lstm_out[((size_t)b*30 + s)*512 + h];
      if (seg) sm.k.cpart[h] = acc;
      __syncthreads();
      if (!seg) {
        float tot = acc + sm.k.cpart[h];
        cstore4(&cprev[b*512+h], tot);
        sm.k.sC[h] = tot;
      }
    }
    // release cout: drain + barrier + flag
    asm volatile("s_waitcnt vmcnt(0)" ::: "memory");
    __syncthreads();
    if (tid == 0)
      __hip_atomic_store(&flags2[b], t + 1, __ATOMIC_RELAXED, __HIP_MEMORY_SCOPE_AGENT);
    // tmap = c @ t2m + b  (pair-packed bf16; 4-way k-split)
    {
      int c2 = tid & 255, ks = tid >> 8;
      float a0 = 0.f, a1 = 0.f;
      const unsigned* tp = t2pp + c2;
#pragma unroll 8
      for (int k = ks*128; k < ks*128 + 128; ++k) {
        float cv = sm.k.sC[k];
        unsigned wv2 = tp[(size_t)k*256];
        a0 += cv*blo(wv2);
        a1 += cv*bhi(wv2);
      }
      sm.k.tpart[ks][c2]       = a0;
      sm.k.tpart[ks][256 + c2] = a1;
    }
    __syncthreads();
    if (tid < 512) {
      float v = sm.k.tpart[0][tid] + sm.k.tpart[1][tid]
              + sm.k.tpart[2][tid] + sm.k.tpart[3][tid];
      tmapv_k[b*512 + tid] = v + t2mb[tid];
    }
    return;
  }

  if (blockIdx.x < 128) {
    // =============== u(t+1) = [tmp1n | c(t)] @ W2(bf16) + W2b ==============
    if (!do_u) return;
    const int x = (int)blockIdx.x - 64;
    const int r0 = (x >> 3) * 8, nc0 = (x & 7) * 64;
    // stage tmp1n (plain; ready from previous dispatch)
    {
      int r = tid >> 7, k4 = (tid & 127) << 2;
      *(float4*)&sm.uu.As[r][k4] = *(const float4*)&tmp1n[(size_t)(r0+r)*512 + k4];
    }
    // wait for kcattn(t) of rows r0..r0+7 (co-resident by capacity: safe)
    if (tid == 0) {
      for (;;) {
        uint4 f0 = cload16w(flags2 + r0);
        uint4 f1 = cload16w(flags2 + r0 + 4);
        if ((int)f0.x > t && (int)f0.y > t && (int)f0.z > t && (int)f0.w > t &&
            (int)f1.x > t && (int)f1.y > t && (int)f1.z > t && (int)f1.w > t) break;
      }
    }
    __syncthreads();
    // coherent load of c(t) rows
    {
      int r = tid >> 7, c4 = (tid & 127) << 2;
      union { uint4 u4; float4 f4; } v;
      v.u4 = cload16nw(&cprev[(size_t)(r0+r)*512 + c4]);
      asm volatile("s_waitcnt vmcnt(0)" ::: "memory");
      *(float4*)&sm.uu.As[r][512 + c4] = v.f4;
    }
    __syncthreads();
    const int k0 = wave * 64;
    const unsigned short* Bp = w2bp + (size_t)k0*512 + nc0 + lane;
    float acc[8] = {0,0,0,0,0,0,0,0};
#pragma unroll 4
    for (int kk = 0; kk < 64; ++kk) {
      float bv = bl(Bp[(size_t)kk*512]);
#pragma unroll
      for (int r = 0; r < 8; ++r) acc[r] += sm.uu.As[r][k0+kk] * bv;
    }
#pragma unroll
    for (int r = 0; r < 8; ++r) sm.uu.part[wave][r][lane] = acc[r];
    __syncthreads();
    if (tid < 512) {
      int r = tid >> 6, c = tid & 63;
      float s2 = 0.f;
#pragma unroll
      for (int w2 = 0; w2 < 16; ++w2) s2 += sm.uu.part[w2][r][c];
      ubuf[(size_t)(r0 + r)*512 + nc0 + c] = s2 + W2b[nc0 + c];
    }
    return;
  }

  // ===================== modules(t-1): 320 blocks ==========================
  if (!do_mod) return;
  const int mb = (int)blockIdx.x - 128;
  const int b = mb & 63, pb = mb >> 6;        // pb in 0..4
  if (tid < 512) sm.m.sT[tid] = tmapv_m[b*512 + tid];
  if (tid >= 512 && tid < 520) sm.m.pv[tid-512] = pvecIn[b*8 + (tid-512)];
  if (tid >= 576 && tid < 585) sm.m.wm[tid-576] = wm_m[b*9 + (tid-576)];
  __syncthreads();
  if (tid < 8) {
    int l = tid;
    sm.m.pd[l] = (l < 7 ? sm.m.pv[l+1] : 0.f) + (l == 0 ? sm.m.pv[0] : 0.f);
  }
  __syncthreads();
  if (pb == 0 && tid < 8) {
    int l = tid;
    float WP = sm.m.wm[0]+sm.m.wm[1]+sm.m.wm[2]+sm.m.wm[3] + sm.m.wm[6] + sm.m.wm[8];
    float WD = sm.m.wm[4]+sm.m.wm[5] + sm.m.wm[7];
    pvecOut[b*8+l] = WP*sm.m.pv[l] + WD*sm.m.pd[l];
  }

  float W[8][6];
#pragma unroll
  for (int m = 0; m < 8; ++m)
#pragma unroll
    for (int i = 0; i < 6; ++i) W[m][i] = swb[m*6+i];
  float W03 = sm.m.wm[0]+sm.m.wm[1]+sm.m.wm[2]+sm.m.wm[3];
  float W45 = sm.m.wm[4]+sm.m.wm[5];

  float acc6[8], acc7[8];
#pragma unroll
  for (int i = 0; i < 8; ++i) { acc6[i] = 0.f; acc7[i] = 0.f; }

  for (int pi = 0; pi < 2; ++pi) {
    int p = pb*32 + wave*2 + pi;
    if (p < 150) {
      const float* st = stack + ((size_t)b*150 + p)*8;
      float a = 0.f, av2 = 0.f;
#pragma unroll
      for (int l = 0; l < 8; ++l) { float v = st[l]; a += v*sm.m.pv[l]; av2 += v*sm.m.pd[l]; }
      float part[6] = {0,0,0,0,0,0};
#pragma unroll 2
      for (int i = 0; i < 8; ++i) {
        int d = i*64 + lane;
        float x = bl(imapB[((size_t)b*150 + p)*512 + d]);
        float t2 = sm.m.sT[d];
#pragma unroll
        for (int m = 0; m < 4; ++m) {
          float c1 = W[m][0]*t2 + W[m][1] + W[m][4] + (W[m][2] + W[m][3]*t2)*a;
          float c0 = W[m][1]*t2 + W[m][5]*t2*a;
          part[m] += elu_(c1*x + c0) * c3w[m*512+d];
        }
#pragma unroll
        for (int m = 0; m < 2; ++m) {
          float c1 = W[4+m][0]*t2 + W[4+m][1] + W[4+m][2]*a + W[4+m][3]*av2
                   + W[4+m][4]*a*av2 + W[4+m][5]*t2*(a+av2);
          part[4+m] += elu_(c1*x + W[4+m][1]*t2) * c4w[m*512+d];
        }
        float c16 = W[6][0]*t2 + W[6][1] + W[6][4] + (W[6][2] + W[6][3]*t2)*a;
        float c06 = W[6][1]*t2 + W[6][5]*t2*a;
        acc6[i] += elu_(c16*x + c06);
        float c17 = W[7][0]*t2 + W[7][1] + W[7][2]*a + W[7][3]*av2
                  + W[7][4]*a*av2 + W[7][5]*t2*(a+av2);
        acc7[i] += elu_(c17*x + W[7][1]*t2);
      }
#pragma unroll
      for (int m = 0; m < 6; ++m) {
#pragma unroll
        for (int off = 32; off; off >>= 1) part[m] += __shfl_down(part[m], off);
        part[m] = __shfl(part[m], 0);
      }
      float r3  = sm.m.wm[0]*(part[0]+c3b[0]) + sm.m.wm[1]*(part[1]+c3b[1])
                + sm.m.wm[2]*(part[2]+c3b[2]) + sm.m.wm[3]*(part[3]+c3b[3]);
      float r45 = sm.m.wm[4]*(part[4]+c4b[0]) + sm.m.wm[5]*(part[5]+c4b[1]);
      if (lane < 8) {
        int l = lane;
        size_t idx = ((size_t)b*150 + p)*8 + l;
        stack[idx] = stack[idx]*(1.f - W03*sm.m.pv[l] - W45*sm.m.pd[l])
                   + sm.m.pv[l]*r3 + sm.m.pd[l]*r45;
      }
    }
  }
#pragma unroll
  for (int i = 0; i < 8; ++i) {
    sm.m.wpart[wave][0][i*64+lane] = acc6[i];
    sm.m.wpart[wave][1][i*64+lane] = acc7[i];
  }
  __syncthreads();
  {
    int which = tid >> 9, d = tid & 511;
    float s = 0.f;
#pragma unroll
    for (int w2 = 0; w2 < 16; ++w2) s += sm.m.wpart[w2][which][d];
    atomicAdd(&plt[(size_t)which*32768 + b*512 + d], s * (1.f/150.f));
  }
}

// ---------------------------------------------------------------------------
// batched m67 GEMMs for ALL t: grid (8 colchunks, 8 rowchunks, 18).
// ---------------------------------------------------------------------------
__global__ __launch_bounds__(512)
void ansall_k(const float* __restrict__ plt, const float* __restrict__ tmapv,
              const unsigned short* __restrict__ answp, const float* __restrict__ ansb,
              float* __restrict__ m67o)
{
  const int z = blockIdx.z;          // 0..17
  const int t = z >> 1, zz = z & 1;
  __shared__ __align__(16) float As[8][1024];
  __shared__ float part[8][8][64];
  const int tid = threadIdx.x;
  const int r0 = blockIdx.y*8;
  const int nc0 = blockIdx.x*64;
  const int lane = tid & 63, w = tid >> 6;

  for (int e4 = tid; e4 < 1024; e4 += 512) {
    int r = e4 >> 7, k4 = (e4 & 127) << 2;
    *(float4*)&As[r][k4]     = *(const float4*)&plt[(size_t)z*32768 + (size_t)(r0+r)*512 + k4];
    *(float4*)&As[r][512+k4] = *(const float4*)&tmapv[(size_t)t*32768 + (size_t)(r0+r)*512 + k4];
  }
  __syncthreads();
  {
    const unsigned short* Bp = answp + (size_t)zz*524288
                             + (size_t)(w*128)*512 + nc0 + lane;
    float acc[8] = {0,0,0,0,0,0,0,0};
    int k0 = w*128;
#pragma unroll 8
    for (int kk = 0; kk < 128; ++kk) {
      float bv = bl(Bp[(size_t)kk*512]);
#pragma unroll
      for (int r = 0; r < 8; ++r) acc[r] += As[r][k0+kk]*bv;
    }
#pragma unroll
    for (int r = 0; r < 8; ++r) part[w][r][lane] = acc[r];
  }
  __syncthreads();
  {
    int r = tid >> 6, c = tid & 63;
    float s = 0.f;
#pragma unroll
    for (int w2 = 0; w2 < 8; ++w2) s += part[w2][r][c];
    m67o[(size_t)z*32768 + (size_t)(r0+r)*512 + nc0 + c] = s + ansb[zz*512 + nc0 + c];
  }
}

// ---------------------------------------------------------------------------
// final mem: mem_8 = sum_t coef_t*(w6_t*m6_t + w7_t*m7_t)
// ---------------------------------------------------------------------------
__global__ __launch_bounds__(512)
void memfin_k(const float* __restrict__ woutAll, const float* __restrict__ m67t,
              float* __restrict__ memb)
{
  int b = blockIdx.x;
  int tid = threadIdx.x;
  __shared__ float w6s[9], w7s[9], coef[9];
  if (tid < 9)       w6s[tid] = woutAll[tid*576 + b*9 + 6];
  else if (tid < 18) w7s[tid-9] = woutAll[(tid-9)*576 + b*9 + 7];
  __syncthreads();
  if (tid == 0) {
    float c = 1.f;
    for (int t = 8; t >= 0; --t) { coef[t] = c; c *= (1.f - w6s[t] - w7s[t]); }
  }
  __syncthreads();
  float acc = 0.f;
#pragma unroll
  for (int t = 0; t < 9; ++t) {
    float m6 = m67t[(((size_t)t*2 + 0)*64 + b)*512 + tid];
    float m7 = m67t[(((size_t)t*2 + 1)*64 + b)*512 + tid];
    acc += coef[t]*(w6s[t]*m6 + w7s[t]*m7);
  }
  memb[b*512 + tid] = acc;
}

// ---------------------------------------------------------------------------
__global__ __launch_bounds__(256)
void imp_k(const float* __restrict__ part, float* __restrict__ out)
{
  int lane = threadIdx.x & 63, wave = threadIdx.x >> 6;
  float acc = 0.f;
  for (int i = threadIdx.x; i < 576; i += 256) acc += part[i];
#pragma unroll
  for (int off = 32; off; off >>= 1) acc += __shfl_down(acc, off);
  __shared__ float red[4];
  if (lane == 0) red[wave] = acc;
  __syncthreads();
  if (threadIdx.x == 0) out[0] = red[0]+red[1]+red[2]+red[3];
}

// ---------------------------------------------------------------------------
extern "C" void kernel_launch(void* const* d_in, const int* in_sizes, int n_in,
                              void* d_out, int out_size, void* d_ws, size_t ws_size,
                              hipStream_t stream)
{
  (void)in_sizes; (void)n_in; (void)out_size; (void)ws_size;
  const float* image = (const float*)d_in[0];
  const int*   ques  = (const int*)d_in[1];
  const int*   qlen  = (const int*)d_in[2];
  const float* embedW= (const float*)d_in[3];
  const float* Wi_f  = (const float*)d_in[4];
  const float* Wh_f  = (const float*)d_in[5];
  const float* b_f   = (const float*)d_in[6];
  const float* Wi_b  = (const float*)d_in[7];
  const float* Wh_b  = (const float*)d_in[8];
  const float* b_b   = (const float*)d_in[9];
  const float* W1    = (const float*)d_in[10];
  const float* b1    = (const float*)d_in[11];
  const float* W2w   = (const float*)d_in[12];
  const float* W2b   = (const float*)d_in[13];
  const float* W3    = (const float*)d_in[14];
  const float* c0    = (const float*)d_in[15];
  const float* Wmod  = (const float*)d_in[16];
  const float* ic1w  = (const float*)d_in[17];
  const float* ic1b  = (const float*)d_in[18];
  const float* ic2w  = (const float*)d_in[19];
  const float* ic2b  = (const float*)d_in[20];
  const float* i2mw  = (const float*)d_in[21];
  const float* i2mb  = (const float*)d_in[22];
  const float* t2mw  = (const float*)d_in[23];
  const float* t2mb  = (const float*)d_in[24];
  const float* c3ow  = (const float*)d_in[25];
  const float* c3cw  = (const float*)d_in[26];
  const float* c3cb  = (const float*)d_in[27];
  const float* c4ow  = (const float*)d_in[28];
  const float* c4cw  = (const float*)d_in[29];
  const float* c4cb  = (const float*)d_in[30];
  const float* aow   = (const float*)d_in[31];
  const float* ansW  = (const float*)d_in[32];
  const float* ansb  = (const float*)d_in[33];
  const float* o1w   = (const float*)d_in[34];
  const float* o1b   = (const float*)d_in[35];
  const float* o2w   = (const float*)d_in[36];
  const float* o2b   = (const float*)d_in[37];
  float* out = (float*)d_out;
  float* ws  = (float*)d_ws;

  size_t off = 0;
  auto alloc = [&](size_t n){ float* p = ws + off; off += n; return p; };
  short* imgP  = (short*)alloc(600ull*20*64*8/2);
  short* X1p   = (short*)alloc(600ull*16*64*8/2);
  short* X2p   = (short*)alloc(600ull*16*64*8/2);
  short* w1p   = (short*)alloc(20*32*64*8/2);
  short* w2mp  = (short*)alloc(16*32*64*8/2);
  short* w3mp  = (short*)alloc(16*32*64*8/2);
  short* wifp  = (short*)alloc(10*64*64*8/2);
  short* wibp  = (short*)alloc(10*64*64*8/2);
  short* embp  = (short*)alloc(120ull*10*64*8/2);
  unsigned short* imapB = (unsigned short*)alloc(9600ull*512/2);
  unsigned* t2pp = (unsigned*)alloc(512*256);
  unsigned short* w2bp  = (unsigned short*)alloc(524288/2);
  unsigned short* answp = (unsigned short*)alloc(1048576/2);
  float* xWfb  = alloc(64ull*30*1024);
  float* xWbb  = alloc(64ull*30*1024);
  float* lout  = alloc(64ull*30*512);
  float* qbuf  = alloc(64*512);
  float* stck  = alloc(64*150*8);
  float* pvecA = alloc(64*8);
  float* pvecB = alloc(64*8);
  float* memb  = alloc(64*512);
  float* cprev = alloc(64*512);
  float* tmp1a = alloc(9ull*64*512);
  float* ubuf  = alloc(64*512);
  float* wmwA  = alloc(9*64*9);
  float* impp  = alloc(9*64);
  float* swb   = alloc(48);
  float* pl    = alloc(9ull*2*64*512);
  float* m67t  = alloc(9ull*2*64*512);
  float* tmapv = alloc(9ull*64*512);
  float* h1b   = alloc(64*1024);
  unsigned* whT = (unsigned*)alloc(2ull*1024*128);       // f16-pair packed Wh^T
  float* hbufW  = alloc(32768);                          // 2 ping x 2 d x 4 g x 16 x 256 f16
  int*   flagsI = (int*)alloc(256);                      // sync flags (lstm:0-31, step:64-127)
  int*   flags2 = flagsI + 64;

  // one dispatch: init + ALL independent packs (incl. f16 WhT, bf16 W2/ansW)
  megapack_k<<<12036, 256, 0, stream>>>(
      c0, c3ow, c4ow, aow, stck, pvecA, memb, cprev, swb, pl,
      Wh_f, Wh_b, whT, hbufW, flagsI,
      ic1w, w1p, ic2w, w2mp, i2mw, w3mp, Wi_f, wifp, Wi_b, wibp,
      image, imgP, embedW, ques, embp, t2mw, t2pp,
      W2w, w2bp, ansW, answp);

  // both embed GEMMs first (LSTM depends on xW)
  gemmM_k<<<dim3(16,30,2), 256, 0, stream>>>(embp, embp, wifp, wibp, b_f, b_b,
                                             xWfb, xWbb, 10, 64, 1024, 0, 0, 0);

  // MERGED: LSTM (32 blocks) + conv1 (1200 blocks)
  lstmc1_k<<<1232, 256, 0, stream>>>(xWfb, xWbb, whT, qlen,
                                     (unsigned long long*)hbufW, flagsI,
                                     lout, qbuf,
                                     imgP, w1p, ic1b, X1p);

  // conv2, conv3 (depend on conv1)
  gemmM_k<<<dim3(8,150,1), 256, 0, stream>>>(X1p, X1p, w2mp, w2mp, ic2b, ic2b,
                                             X2p, X2p, 16, 32, 512, 1, 0, 16);
  gemmM_k<<<dim3(8,150,1), 256, 0, stream>>>(X2p, X2p, w3mp, w3mp, i2mb, i2mb,
                                             imapB, imapB, 16, 32, 512, 2, 0, 0);

  // tmp1all[t] = q @ W1[t] + b1 (all 9 t)
  gemm64b_k<<<dim3(8,8,9), 512, 0, stream>>>(
      qbuf, 0, 9, (const float*)nullptr, 0,
      W1, 262144, b1, 0, tmp1a, 32768, 512, 0);
  // u for t=0 (fp32 W2)
  gemm64b_k<<<dim3(8,8,1), 512, 0, stream>>>(
      tmp1a, 0, 9, cprev, 512, W2w, 0, W2b, 0, ubuf, 0, 512, 0);

  // t-loop: D(t) = kcattn(t) + u(t+1) + modules(t-1); tail t=9 = modules(8)
  for (int t = 0; t <= 9; ++t) {
    int tm = t - 1;
    int tmc = (tm < 0) ? 0 : tm;
    float* pvIn  = (tmc & 1) ? pvecB : pvecA;
    float* pvOut = (tmc & 1) ? pvecA : pvecB;
    step_k<<<448, 1024, 0, stream>>>(
        ubuf, Wmod, lout, W3, t2pp, t2mb, wmwA, impp,
        cprev, tmapv + (size_t)(t < 9 ? t : 0)*32768, t,
        tmp1a + (size_t)(t < 8 ? t+1 : 0)*32768, w2bp, W2b, ubuf,
        flags2, (t < 8) ? 1 : 0,
        imapB, tmapv + (size_t)tmc*32768, stck, pvIn, pvOut, swb,
        c3cw, c3cb, c4cw, c4cb,
        wmwA + (size_t)tmc*576, pl + (size_t)tmc*65536,
        (t > 0) ? 1 : 0);
  }

  // all 18 m67 GEMMs in ONE dispatch (off the sequential critical path)
  ansall_k<<<dim3(8,8,18), 512, 0, stream>>>(pl, tmapv, answp, ansb, m67t);

  // final mem blend, then h1 = elu([q, mem] @ out1 + b); logits = h1 @ out2 + b
  memfin_k<<<64, 512, 0, stream>>>(wmwA, m67t, memb);
  gemm64b_k<<<dim3(16,8,1), 512, 0, stream>>>(
      qbuf, 0, 9, memb, 512, o1w, 0, o1b, 0, h1b, 0, 1024, 1);
  gemm64b_k<<<dim3(1,8,1), 512, 0, stream>>>(
      h1b, 0, 10, (const float*)nullptr, 0, o2w, 0, o2b, 0, out, 0, 32, 0);
  imp_k<<<1, 256, 0, stream>>>(impp, out + 2048);
}

// Round 13
// 784.546 us; speedup vs baseline: 1.2080x; 1.0031x over previous
//
#include <hip/hip_runtime.h>
#include <hip/hip_fp16.h>
#include <math.h>

#define DEV __device__ __forceinline__

DEV float fexp(float x){ return __expf(x); }
DEV float elu_(float x){ return x > 0.f ? x : fexp(x) - 1.f; }
DEV float sigm_(float x){ return 1.f/(1.f + fexp(-x)); }
DEV float tanh_(float x){ float e = fexp(2.f*x); return 1.f - 2.f/(e + 1.f); }
DEV unsigned bf16r(float x){ unsigned u = __float_as_uint(x);
  return (u + 0x7fffu + ((u>>16)&1u)) >> 16; }
DEV float blo(unsigned u){ return __uint_as_float(u << 16); }
DEV float bhi(unsigned u){ return __uint_as_float(u & 0xffff0000u); }
DEV float bl(unsigned short u){ return __uint_as_float(((unsigned)u) << 16); }

using frag  = __attribute__((ext_vector_type(8))) short;     // 8 bf16 (4 VGPRs)
using fragh = __attribute__((ext_vector_type(8))) _Float16;  // 8 f16  (4 VGPRs)
using f32x4 = __attribute__((ext_vector_type(4))) float;     // MFMA acc

// coherent (sc0 sc1 = device-coherent path) 16B load WITH completion wait
DEV uint4 cload16w(const void* p){
  uint4 r;
  asm volatile("global_load_dwordx4 %0, %1, off sc0 sc1\n\ts_waitcnt vmcnt(0)"
               : "=v"(r) : "v"(p) : "memory");
  return r;
}
// coherent 16B load, NO wait (caller does one s_waitcnt vmcnt(0) for the batch)
DEV uint4 cload16nw(const void* p){
  uint4 r;
  asm volatile("global_load_dwordx4 %0, %1, off sc0 sc1"
               : "=v"(r) : "v"(p) : "memory");
  return r;
}
// coherent 4B store (device-coherent path, pipelined)
DEV void cstore4(void* p, float v){
  asm volatile("global_store_dword %0, %1, off sc0 sc1"
               :: "v"(p), "v"(v) : "memory");
}

// ---------------------------------------------------------------------------
// device pack helpers
// ---------------------------------------------------------------------------
DEV void d_packB(const float* __restrict__ W, short* __restrict__ Bp,
                 int KC, int Ng, int Ksrc, int N, int trans, int idx)
{
  if (idx >= KC*Ng*64) return;
  int lane = idx & 63;
  int g    = (idx >> 6) % Ng;
  int kc   = idx / (64*Ng);
  int n = g*16 + (lane & 15);
  int kb = kc*32 + ((lane >> 4) << 3);
  unsigned o[4];
#pragma unroll
  for (int jj = 0; jj < 4; ++jj) {
    int k0 = kb + 2*jj;
    float v0 = (k0   < Ksrc) ? (trans ? W[(size_t)n*Ksrc + k0]   : W[(size_t)(k0)*N + n])   : 0.f;
    float v1 = (k0+1 < Ksrc) ? (trans ? W[(size_t)n*Ksrc + k0+1] : W[(size_t)(k0+1)*N + n]) : 0.f;
    o[jj] = bf16r(v0) | (bf16r(v1) << 16);
  }
  *(uint4*)(Bp + (size_t)idx*8) = make_uint4(o[0], o[1], o[2], o[3]);
}

DEV void d_packImg(const float* __restrict__ image, short* __restrict__ Ap, int idx)
{
  int lane = idx & 63;
  int kc   = (idx >> 6) % 20;
  int mt   = idx / 1280;
  int row = mt*16 + (lane & 15);
  int b = row / 150, p = row % 150;
  int cb = kc*32 + ((lane >> 4) << 3);
  unsigned o[4];
#pragma unroll
  for (int jj = 0; jj < 4; ++jj) {
    float v0 = image[((size_t)b*640 + cb + 2*jj    )*150 + p];
    float v1 = image[((size_t)b*640 + cb + 2*jj + 1)*150 + p];
    o[jj] = bf16r(v0) | (bf16r(v1) << 16);
  }
  *(uint4*)(Ap + (size_t)idx*8) = make_uint4(o[0], o[1], o[2], o[3]);
}

DEV void d_packEmb(const float* __restrict__ embedW, const int* __restrict__ ques,
                   short* __restrict__ Ap, int idx)
{
  int lane = idx & 63;
  int kc   = (idx >> 6) % 10;
  int mt   = idx / 640;
  int row = mt*16 + (lane & 15);
  int q = ques[row];
  int kb = kc*32 + ((lane >> 4) << 3);
  unsigned o[4];
#pragma unroll
  for (int jj = 0; jj < 4; ++jj) {
    int k0 = kb + 2*jj;
    float v0 = (k0   < 300) ? embedW[(size_t)q*300 + k0]   : 0.f;
    float v1 = (k0+1 < 300) ? embedW[(size_t)q*300 + k0+1] : 0.f;
    o[jj] = bf16r(v0) | (bf16r(v1) << 16);
  }
  *(uint4*)(Ap + (size_t)idx*8) = make_uint4(o[0], o[1], o[2], o[3]);
}

// ---------------------------------------------------------------------------
// ONE dispatch for all independent pre-stage work
// ---------------------------------------------------------------------------
__global__ __launch_bounds__(256)
void megapack_k(const float* __restrict__ c0, const float* __restrict__ c3ow,
                const float* __restrict__ c4ow, const float* __restrict__ aow,
                float* __restrict__ stack, float* __restrict__ pvecA,
                float* __restrict__ mem, float* __restrict__ cprev,
                float* __restrict__ swb, float* __restrict__ pl,
                const float* __restrict__ Whf, const float* __restrict__ Whb,
                unsigned* __restrict__ whT,
                float* __restrict__ hbufz, int* __restrict__ flagz,
                const float* __restrict__ ic1w, short* __restrict__ w1p,
                const float* __restrict__ ic2w, short* __restrict__ w2mp,
                const float* __restrict__ i2mw, short* __restrict__ w3mp,
                const float* __restrict__ Wif, short* __restrict__ wifp,
                const float* __restrict__ Wib, short* __restrict__ wibp,
                const float* __restrict__ image, short* __restrict__ imgP,
                const float* __restrict__ embedW, const int* __restrict__ ques,
                short* __restrict__ embp,
                const float* __restrict__ t2mw, unsigned* __restrict__ t2pp,
                const float* __restrict__ W2w, unsigned short* __restrict__ w2bp,
                const float* __restrict__ ansW, unsigned short* __restrict__ answp)
{
  const int bx = blockIdx.x, tid = threadIdx.x;
  if (bx < 320) {
    int idx = bx*256 + tid;
    int stride = 320*256;
    for (int i = idx; i < 64*150*8; i += stride) stack[i] = 0.f;
    for (int i = idx; i < 64*8;    i += stride) pvecA[i] = ((i & 7) == 0) ? 1.f : 0.f;
    for (int i = idx; i < 64*512;  i += stride) mem[i] = 0.f;
    for (int i = idx; i < 64*512;  i += stride) cprev[i] = c0[i & 511];
    for (int i = idx; i < 9*2*64*512; i += stride) pl[i] = 0.f;
    for (int i = idx; i < 32768;   i += stride) hbufz[i] = 0.f;  // hbuf (f16 pairs)
    if (idx < 256) flagz[idx] = 0;                               // sync flags
    if (idx < 8) {
      const float* ow = (idx < 4) ? (c3ow + idx*6)
                      : (idx < 6) ? (c4ow + (idx-4)*6)
                                  : (aow  + (idx-6)*6);
      float mx = ow[0];
      for (int m = 1; m < 6; ++m) mx = fmaxf(mx, ow[m]);
      float e[6]; float s = 0.f;
      for (int m = 0; m < 6; ++m) { e[m] = fexp(ow[m]-mx); s += e[m]; }
      for (int m = 0; m < 6; ++m) swb[idx*6+m] = e[m]/s;
    }
  } else if (bx < 1344) {
    // WhT: [d][zc 0..1023][k-pair 0..127] packed f16 pairs (transposed Wh)
    int idx = (bx-320)*256 + tid;
    int dd  = idx >> 17;
    int rem = idx & 131071;
    int kp  = rem >> 10;
    int zc  = rem & 1023;
    const float* Wh = dd ? Whb : Whf;
    __half2 hv = __floats2half2_rn(Wh[(size_t)(2*kp)*1024 + zc],
                                   Wh[(size_t)(2*kp+1)*1024 + zc]);
    whT[((size_t)dd << 17) + (zc << 7) + kp] = *(unsigned*)&hv;
  } else if (bx < 1504) {
    d_packB(ic1w, w1p, 20, 32, 640, 512, 1, (bx-1344)*256 + tid);
  } else if (bx < 1632) {
    d_packB(ic2w, w2mp, 16, 32, 512, 512, 1, (bx-1504)*256 + tid);
  } else if (bx < 1760) {
    d_packB(i2mw, w3mp, 16, 32, 512, 512, 1, (bx-1632)*256 + tid);
  } else if (bx < 1920) {
    d_packB(Wif, wifp, 10, 64, 300, 1024, 0, (bx-1760)*256 + tid);
  } else if (bx < 2080) {
    d_packB(Wib, wibp, 10, 64, 300, 1024, 0, (bx-1920)*256 + tid);
  } else if (bx < 5080) {
    d_packImg(image, imgP, (bx-2080)*256 + tid);
  } else if (bx < 5380) {
    d_packEmb(embedW, ques, embp, (bx-5080)*256 + tid);
  } else if (bx < 5892) {
    int idx = (bx-5380)*256 + tid;   // 512*256
    int k = idx >> 8, c = idx & 255;
    t2pp[idx] = bf16r(t2mw[(size_t)k*512 + c]) | (bf16r(t2mw[(size_t)k*512 + 256 + c]) << 16);
  } else if (bx < 7940) {
    int i = (bx-5892)*256 + tid;     // 524288
    w2bp[i] = (unsigned short)bf16r(W2w[i]);
  } else {
    int i = (bx-7940)*256 + tid;     // 1048576
    answp[i] = (unsigned short)bf16r(ansW[i]);
  }
}

// ---------------------------------------------------------------------------
// MFMA GEMM, dual problem sets via blockIdx.z.
// mode 0: fp32 row-major; mode 1: bf16 A-pack; mode 2: bf16 row-major
// ---------------------------------------------------------------------------
__global__ __launch_bounds__(256)
void gemmM_k(const short* __restrict__ ApA, const short* __restrict__ ApB,
             const short* __restrict__ BpA, const short* __restrict__ BpB,
             const float* __restrict__ biasA, const float* __restrict__ biasB,
             void* __restrict__ CoutA, void* __restrict__ CoutB,
             int KC, int Ng, int N, int mode, int act, int KCout)
{
  __shared__ float lds[4][16][68];
  const int z = blockIdx.z;
  const short* Ap = z ? ApB : ApA;
  const short* Bp = z ? BpB : BpA;
  const float* bias = z ? biasB : biasA;
  void* Cout = z ? CoutB : CoutA;
  const int tid = threadIdx.x, lane = tid & 63, w = tid >> 6;
  const int mt = blockIdx.y*4 + w;
  const int ncol0 = blockIdx.x*64;
  const short* Abase = Ap + (((size_t)mt*KC) << 9) + lane*8;
  const short* Bbase = Bp + (((size_t)blockIdx.x*4) << 9) + lane*8;
  f32x4 acc0 = {0.f,0.f,0.f,0.f}, acc1 = acc0, acc2 = acc0, acc3 = acc0;
#pragma unroll 2
  for (int kc = 0; kc < KC; ++kc) {
    frag a = *(const frag*)(Abase + ((size_t)kc << 9));
    const short* bk = Bbase + (((size_t)kc*Ng) << 9);
    frag b0 = *(const frag*)(bk);
    frag b1 = *(const frag*)(bk + 512);
    frag b2 = *(const frag*)(bk + 1024);
    frag b3 = *(const frag*)(bk + 1536);
    acc0 = __builtin_amdgcn_mfma_f32_16x16x32_bf16(a, b0, acc0, 0, 0, 0);
    acc1 = __builtin_amdgcn_mfma_f32_16x16x32_bf16(a, b1, acc1, 0, 0, 0);
    acc2 = __builtin_amdgcn_mfma_f32_16x16x32_bf16(a, b2, acc2, 0, 0, 0);
    acc3 = __builtin_amdgcn_mfma_f32_16x16x32_bf16(a, b3, acc3, 0, 0, 0);
  }
  {
    int colb = lane & 15, rowb = (lane >> 4)*4;
#pragma unroll
    for (int r = 0; r < 4; ++r) {
      lds[w][rowb+r][ 0+colb] = acc0[r];
      lds[w][rowb+r][16+colb] = acc1[r];
      lds[w][rowb+r][32+colb] = acc2[r];
      lds[w][rowb+r][48+colb] = acc3[r];
    }
  }
  __syncthreads();
  if (mode == 0) {
    float* C = (float*)Cout;
    int mloc = lane >> 2, q4 = lane & 3;
    size_t rowoff = (size_t)(mt*16 + mloc)*N + ncol0 + q4*16;
#pragma unroll
    for (int i = 0; i < 4; ++i) {
      float4 v = *(float4*)&lds[w][mloc][q4*16 + i*4];
      const float* bp = bias + ncol0 + q4*16 + i*4;
      v.x += bp[0]; v.y += bp[1]; v.z += bp[2]; v.w += bp[3];
      if (act) { v.x = elu_(v.x); v.y = elu_(v.y); v.z = elu_(v.z); v.w = elu_(v.w); }
      *(float4*)&C[rowoff + i*4] = v;
    }
  } else if (mode == 1) {
    short* C = (short*)Cout;
    int m = lane & 15, qb = (lane >> 4)*8;
#pragma unroll
    for (int h = 0; h < 2; ++h) {
      int nl = h*32 + qb;
      unsigned o[4];
#pragma unroll
      for (int jj = 0; jj < 4; ++jj) {
        float v0 = lds[w][m][nl + 2*jj]     + bias[ncol0 + nl + 2*jj];
        float v1 = lds[w][m][nl + 2*jj + 1] + bias[ncol0 + nl + 2*jj + 1];
        if (act) { v0 = elu_(v0); v1 = elu_(v1); }
        o[jj] = bf16r(v0) | (bf16r(v1) << 16);
      }
      *(uint4*)(C + (((size_t)mt*KCout + (ncol0 >> 5) + h) << 9) + lane*8)
          = make_uint4(o[0], o[1], o[2], o[3]);
    }
  } else {
    unsigned short* C = (unsigned short*)Cout;
    int row = lane >> 2, cb = (lane & 3)*16;
#pragma unroll
    for (int h = 0; h < 2; ++h) {
      unsigned o[4];
#pragma unroll
      for (int jj = 0; jj < 4; ++jj) {
        float v0 = lds[w][row][cb + h*8 + 2*jj]     + bias[ncol0 + cb + h*8 + 2*jj];
        float v1 = lds[w][row][cb + h*8 + 2*jj + 1] + bias[ncol0 + cb + h*8 + 2*jj + 1];
        if (act) { v0 = elu_(v0); v1 = elu_(v1); }
        o[jj] = bf16r(v0) | (bf16r(v1) << 16);
      }
      *(uint4*)&C[(size_t)(mt*16 + row)*N + ncol0 + cb + h*8]
          = make_uint4(o[0], o[1], o[2], o[3]);
    }
  }
}

// ---------------------------------------------------------------------------
// 64-row batch GEMM, K-split across waves
// ---------------------------------------------------------------------------
__global__ __launch_bounds__(512)
void gemm64b_k(const float* __restrict__ A1, long zA1, int K1log,
               const float* __restrict__ A2, int K2,
               const float* __restrict__ B, long zB,
               const float* __restrict__ bias, int zbias,
               float* __restrict__ C, long zC, int N, int act)
{
  const int K1 = 1 << K1log;
  const int Kt = K1 + K2;
  __shared__ __align__(16) float As[8][1024];
  __shared__ float part[8][8][64];
  const int tid = threadIdx.x;
  const int z = blockIdx.z;
  const int r0 = blockIdx.y*8;
  {
    const float* a1 = A1 + (size_t)z*zA1;
    const int nf4 = (8*K1) >> 2;
    for (int e4 = tid; e4 < nf4; e4 += 512) {
      int r = e4 >> (K1log-2);
      int k4 = (e4 & ((K1>>2)-1)) << 2;
      *(float4*)&As[r][k4] = *(const float4*)&a1[(size_t)(r0+r)*K1 + k4];
    }
    if (K2 > 0) {
      for (int e4 = tid; e4 < 1024; e4 += 512) {
        int r = e4 >> 7;
        int k4 = (e4 & 127) << 2;
        *(float4*)&As[r][K1+k4] = *(const float4*)&A2[(size_t)(r0+r)*512 + k4];
      }
    }
  }
  __syncthreads();
  const int lane = tid & 63, w = tid >> 6;
  const int n = blockIdx.x*64 + lane;
  const bool nv = n < N;
  const int kseg = Kt >> 3;
  const int k0 = w*kseg;
  const float* Bp = B + (size_t)z*zB + (size_t)k0*N + (nv ? n : 0);
  float acc[8] = {0,0,0,0,0,0,0,0};
#pragma unroll 8
  for (int kk = 0; kk < kseg; ++kk) {
    float bv = nv ? Bp[(size_t)kk*N] : 0.f;
    int k = k0 + kk;
#pragma unroll
    for (int r = 0; r < 8; ++r) acc[r] += As[r][k]*bv;
  }
#pragma unroll
  for (int r = 0; r < 8; ++r) part[w][r][lane] = acc[r];
  __syncthreads();
  {
    int r = tid >> 6, c = tid & 63;
    int nn = blockIdx.x*64 + c;
    if (nn < N) {
      float s = 0.f;
#pragma unroll
      for (int w2 = 0; w2 < 8; ++w2) s += part[w2][r][c];
      s += bias ? bias[(size_t)z*zbias + nn] : 0.f;
      if (act == 1) s = elu_(s);
      C[(size_t)z*zC + (size_t)(r0+r)*N + nn] = s;
    }
  }
}

// ---------------------------------------------------------------------------
// MERGED: MFMA bidirectional masked LSTM (blocks 0..31, round-4 protocol)
// + conv1 GEMM (blocks 32..1231) running concurrently on the idle 224 CUs.
// ---------------------------------------------------------------------------
__global__ __launch_bounds__(256)
void lstmc1_k(const float* __restrict__ xWf, const float* __restrict__ xWb,
              const unsigned* __restrict__ whT, const int* __restrict__ qlen,
              unsigned long long* __restrict__ hbuf, int* __restrict__ flags,
              float* __restrict__ lstm_out, float* __restrict__ qout,
              const short* __restrict__ c1Ap, const short* __restrict__ c1Bp,
              const float* __restrict__ c1bias, short* __restrict__ c1out)
{
  const int tid = threadIdx.x, lane = tid & 63, w = tid >> 6;
  __shared__ union {
    unsigned short Wl[65536];                 // 128 KiB (lstm weights)
    float lds[4][16][68];                     // conv epilogue staging
  } sm;

  if (blockIdx.x >= 32) {
    // ================= conv1 branch: X1p = elu(imgP @ w1p + ic1b) ==========
    const int bx2 = (int)blockIdx.x - 32;     // 0..1199
    const int mt = (bx2 >> 3)*4 + w;          // 150 y-tiles * 4 waves
    const int ncol0 = (bx2 & 7)*64;
    const short* Abase = c1Ap + (((size_t)mt*20) << 9) + lane*8;
    const short* Bbase = c1Bp + (((size_t)(bx2 & 7)*4) << 9) + lane*8;
    f32x4 acc0 = {0.f,0.f,0.f,0.f}, acc1 = acc0, acc2 = acc0, acc3 = acc0;
#pragma unroll 2
    for (int kc = 0; kc < 20; ++kc) {
      frag a = *(const frag*)(Abase + ((size_t)kc << 9));
      const short* bk = Bbase + (((size_t)kc*32) << 9);
      frag b0 = *(const frag*)(bk);
      frag b1 = *(const frag*)(bk + 512);
      frag b2 = *(const frag*)(bk + 1024);
      frag b3 = *(const frag*)(bk + 1536);
      acc0 = __builtin_amdgcn_mfma_f32_16x16x32_bf16(a, b0, acc0, 0, 0, 0);
      acc1 = __builtin_amdgcn_mfma_f32_16x16x32_bf16(a, b1, acc1, 0, 0, 0);
      acc2 = __builtin_amdgcn_mfma_f32_16x16x32_bf16(a, b2, acc2, 0, 0, 0);
      acc3 = __builtin_amdgcn_mfma_f32_16x16x32_bf16(a, b3, acc3, 0, 0, 0);
    }
    {
      int colb = lane & 15, rowb = (lane >> 4)*4;
#pragma unroll
      for (int r = 0; r < 4; ++r) {
        sm.lds[w][rowb+r][ 0+colb] = acc0[r];
        sm.lds[w][rowb+r][16+colb] = acc1[r];
        sm.lds[w][rowb+r][32+colb] = acc2[r];
        sm.lds[w][rowb+r][48+colb] = acc3[r];
      }
    }
    __syncthreads();
    {
      int m = lane & 15, qb = (lane >> 4)*8;
#pragma unroll
      for (int h = 0; h < 2; ++h) {
        int nl = h*32 + qb;
        unsigned o[4];
#pragma unroll
        for (int jj = 0; jj < 4; ++jj) {
          float v0 = elu_(sm.lds[w][m][nl + 2*jj]     + c1bias[ncol0 + nl + 2*jj]);
          float v1 = elu_(sm.lds[w][m][nl + 2*jj + 1] + c1bias[ncol0 + nl + 2*jj + 1]);
          o[jj] = bf16r(v0) | (bf16r(v1) << 16);
        }
        *(uint4*)(c1out + (((size_t)mt*16 + (ncol0 >> 5) + h) << 9) + lane*8)
            = make_uint4(o[0], o[1], o[2], o[3]);
      }
    }
    return;
  }

  // ===================== LSTM branch (round-4 protocol) ====================
  const int bx = blockIdx.x;
  const int d = bx & 1, g = (bx >> 1) & 3, n = bx >> 3;
  const int q = lane >> 4, cl = lane & 15;

#pragma unroll 4
  for (int rb = 0; rb < 32; ++rb) {
    int lcrow = rb*8 + (tid >> 5);
    int gt = lcrow >> 6, c = lcrow & 63;
    int zc = gt*256 + n*64 + c;
    uint4 v = *(const uint4*)(whT + (((size_t)d*1024 + zc) << 7) + ((tid & 31) << 2));
    int byteoff = (lcrow << 9) + ((((tid & 31) << 4)) ^ ((lcrow & 7) << 4));
    *(uint4*)((char*)sm.Wl + byteoff) = v;
  }

  const float* xW = d ? xWb : xWf;
  const int b   = g*16 + cl;                 // this lane's batch
  const int c4  = w*16 + q*4;                // local col base within slice
  const int hc4 = n*64 + c4;                 // global h-col base (4 consecutive)
  const int len = qlen[b];
  float cst[4] = {0.f,0.f,0.f,0.f}, hst[4] = {0.f,0.f,0.f,0.f};
  int* flg = flags + ((d*4 + g) << 2);       // 4 flags for this (d,g) group
  const int bofs = (cl & 7) << 4;
  __syncthreads();

  for (int ss = 0; ss < 30; ++ss) {
    const int s = d ? (29 - ss) : ss;
    const float* xr = xW + (size_t)b*30720 + (size_t)s*1024 + hc4;
    f32x4 xwv[4];
#pragma unroll
    for (int gt = 0; gt < 4; ++gt) xwv[gt] = *(const f32x4*)(xr + gt*256);

    if (ss > 0) {
      for (;;) {
        uint4 f4 = cload16w(flg);   // all 4 flags in ONE coherent 16B load
        if ((int)f4.x >= ss && (int)f4.y >= ss &&
            (int)f4.z >= ss && (int)f4.w >= ss) break;
      }
      __builtin_amdgcn_sched_barrier(0);
    }
    // B = h^T from hbuf: 8 pipelined coherent 16B loads, ONE vmcnt wait
    const char* hbr = (const char*)(hbuf + ((size_t)(((ss & 1)*2 + d)*4 + g) << 9))
                    + (cl << 9) + (q << 4);
    union { uint4 u; fragh f; } hv[8];
#pragma unroll
    for (int ks = 0; ks < 8; ++ks) hv[ks].u = cload16nw(hbr + (ks << 6));
    asm volatile("s_waitcnt vmcnt(0)" ::: "memory");
    __builtin_amdgcn_sched_barrier(0);

    f32x4 acc0 = {0.f,0.f,0.f,0.f}, acc1 = acc0, acc2 = acc0, acc3 = acc0;
#pragma unroll
    for (int ks = 0; ks < 8; ++ks) {
      const int kb = ((ks << 6) + (q << 4)) ^ bofs;
      const char* wb = (const char*)sm.Wl + ((w*16 + cl) << 9) + kb;
      fragh a0 = *(const fragh*)(wb);
      fragh a1 = *(const fragh*)(wb + (64 << 9));
      fragh a2 = *(const fragh*)(wb + (128 << 9));
      fragh a3 = *(const fragh*)(wb + (192 << 9));
      acc0 = __builtin_amdgcn_mfma_f32_16x16x32_f16(a0, hv[ks].f, acc0, 0, 0, 0);
      acc1 = __builtin_amdgcn_mfma_f32_16x16x32_f16(a1, hv[ks].f, acc1, 0, 0, 0);
      acc2 = __builtin_amdgcn_mfma_f32_16x16x32_f16(a2, hv[ks].f, acc2, 0, 0, 0);
      acc3 = __builtin_amdgcn_mfma_f32_16x16x32_f16(a3, hv[ks].f, acc3, 0, 0, 0);
    }
    const bool m = s < len;
    f32x4 lo4;
    float hvv[4];
#pragma unroll
    for (int r = 0; r < 4; ++r) {
      float iv = acc0[r] + xwv[0][r];
      float fv = acc1[r] + xwv[1][r];
      float gv = acc2[r] + xwv[2][r];
      float o_ = acc3[r] + xwv[3][r];
      float cn = sigm_(fv)*cst[r] + sigm_(iv)*tanh_(gv);
      float hn = sigm_(o_)*tanh_(cn);
      float hk = m ? hn : hst[r];
      cst[r] = m ? cn : cst[r];
      hst[r] = hk;
      hvv[r] = hk;
      lo4[r] = m ? hn : 0.f;
    }
    unsigned long long* hbw = hbuf + ((size_t)((((ss & 1) ^ 1)*2 + d)*4 + g) << 9);
    union { unsigned long long u; __half2 h2[2]; } hp;
    hp.h2[0] = __floats2half2_rn(hvv[0], hvv[1]);
    hp.h2[1] = __floats2half2_rn(hvv[2], hvv[3]);
    __hip_atomic_store(hbw + cl*64 + (hc4 >> 2), hp.u,
                       __ATOMIC_RELAXED, __HIP_MEMORY_SCOPE_AGENT);
    *(f32x4*)(lstm_out + (((size_t)b*30 + s) << 9) + (d << 8) + hc4) = lo4;
    asm volatile("s_waitcnt vmcnt(0)" ::: "memory");
    __syncthreads();
    if (tid == 0)
      __hip_atomic_store(&flg[n], ss + 1, __ATOMIC_RELAXED, __HIP_MEMORY_SCOPE_AGENT);
  }
  *(f32x4*)(qout + ((size_t)b << 9) + (d << 8) + hc4) =
      f32x4{hst[0], hst[1], hst[2], hst[3]};
}

// ---------------------------------------------------------------------------
// MERGED per-t step: 512 blocks x 1024 threads.
//  blocks [0,64):    kcattn(t)
//  blocks [64,128):  u(t+1) GEMM (spins on flags)
//  blocks [128,448): modules(t-1)
//  blocks [448,512): ansall slices for tz = t-2 (z = tz*2, tz*2+1)
// Deadlock-free: only u-blocks (64) spin; all other blocks terminate
// unconditionally, so kcattn blocks always get scheduled at any occupancy.
// ---------------------------------------------------------------------------
__global__ __launch_bounds__(1024)
void step_k(const float* __restrict__ u, const float* __restrict__ Wmod,
            const float* __restrict__ lstm_out, const float* __restrict__ W3,
            const unsigned* __restrict__ t2pp, const float* __restrict__ t2mb,
            float* __restrict__ woutAll, float* __restrict__ imp_part,
            float* __restrict__ cprev, float* __restrict__ tmapv_k, int t,
            const float* __restrict__ tmp1n, const unsigned short* __restrict__ w2bp,
            const float* __restrict__ W2b, float* __restrict__ ubuf,
            int* __restrict__ flags2, int do_u,
            const unsigned short* __restrict__ imapB, const float* __restrict__ tmapv_m,
            float* __restrict__ stack, const float* __restrict__ pvecIn,
            float* __restrict__ pvecOut, const float* __restrict__ swb,
            const float* __restrict__ c3w, const float* __restrict__ c3b,
            const float* __restrict__ c4w, const float* __restrict__ c4b,
            const float* __restrict__ wm_m, float* __restrict__ plt, int do_mod,
            const float* __restrict__ plt_a, const float* __restrict__ tmapv_a,
            const unsigned short* __restrict__ answp, const float* __restrict__ ansb,
            float* __restrict__ m67o_a)
{
  const int tid = threadIdx.x;
  const int lane = tid & 63, wave = tid >> 6;   // 16 waves
  __shared__ union {
    struct {  // kcattn
      float ush[512]; float sC[512]; float cpart[512]; float tpart[4][512];
      float wl[9]; float sc[32], at[32];
    } k;
    struct {  // u GEMM
      __align__(16) float As[8][1024]; float part[16][8][64];
    } uu;
    struct {  // modules
      float sT[512]; float pv[8], pd[8], wm[9]; float wpart[16][2][512];
    } m;
    struct {  // ansall
      __align__(16) float As[8][1024]; float part[16][8][64];
    } a;
  } sm;

  if (blockIdx.x < 64) {
    // ======================= kcattn(t), b = blockIdx.x =====================
    if (t >= 9) return;
    int b = blockIdx.x;
    if (tid < 512) sm.k.ush[tid] = u[b*512 + tid];
    __syncthreads();
    for (int s = wave; s < 30; s += 16) {
      float acc = 0.f;
      const float* lo = lstm_out + ((size_t)b*30 + s)*512;
#pragma unroll
      for (int h = lane; h < 512; h += 64) acc += lo[h]*sm.k.ush[h]*W3[h];
#pragma unroll
      for (int off = 32; off; off >>= 1) acc += __shfl_down(acc, off);
      if (lane == 0) sm.k.sc[s] = acc;
    }
    if (wave < 9) {
      float acc = 0.f;
#pragma unroll
      for (int k = lane; k < 512; k += 64) acc += sm.k.ush[k]*Wmod[k*9+wave];
#pragma unroll
      for (int off = 32; off; off >>= 1) acc += __shfl_down(acc, off);
      if (lane == 0) sm.k.wl[wave] = acc;
    }
    __syncthreads();
    if (tid == 0) {
      float mx = sm.k.wl[0];
      for (int m = 1; m < 9; ++m) mx = fmaxf(mx, sm.k.wl[m]);
      float s = 0.f;
      for (int m = 0; m < 9; ++m) s += fexp(sm.k.wl[m]-mx);
      float ls = logf(s);
      float ent = 0.f;
      for (int m = 0; m < 9; ++m) {
        float l = sm.k.wl[m]-mx-ls;
        float w = fexp(l);
        woutAll[t*576 + b*9 + m] = w;
        ent -= w*l;
      }
      imp_part[t*64+b] = ent;
    }
    if (wave == 1) {
      float v = (lane < 30) ? sm.k.sc[lane] : -3.4e38f;
      float mx = v;
#pragma unroll
      for (int off = 32; off; off >>= 1) mx = fmaxf(mx, __shfl_xor(mx, off));
      float e = (lane < 30) ? fexp(v-mx) : 0.f;
      float ssum = e;
#pragma unroll
      for (int off = 32; off; off >>= 1) ssum += __shfl_xor(ssum, off);
      if (lane < 30) sm.k.at[lane] = e/ssum;
    }
    __syncthreads();
    // context: 2-way s-split per h; cout written COHERENTLY (u-blocks read it)
    {
      int h = tid & 511, seg = tid >> 9;
      float acc = 0.f;
      int s0 = seg ? 15 : 0, s1 = seg ? 30 : 15;
      for (int s = s0; s < s1; ++s) acc += sm.k.at[s]*lstm_out[((size_t)b*30 + s)*512 + h];
      if (seg) sm.k.cpart[h] = acc;
      __syncthreads();
      if (!seg) {
        float tot = acc + sm.k.cpart[h];
        cstore4(&cprev[b*512+h], tot);
        sm.k.sC[h] = tot;
      }
    }
    // release cout: drain + barrier + flag
    asm volatile("s_waitcnt vmcnt(0)" ::: "memory");
    __syncthreads();
    if (tid == 0)
      __hip_atomic_store(&flags2[b], t + 1, __ATOMIC_RELAXED, __HIP_MEMORY_SCOPE_AGENT);
    // tmap = c @ t2m + b  (pair-packed bf16; 4-way k-split)
    {
      int c2 = tid & 255, ks = tid >> 8;
      float a0 = 0.f, a1 = 0.f;
      const unsigned* tp = t2pp + c2;
#pragma unroll 8
      for (int k = ks*128; k < ks*128 + 128; ++k) {
        float cv = sm.k.sC[k];
        unsigned wv2 = tp[(size_t)k*256];
        a0 += cv*blo(wv2);
        a1 += cv*bhi(wv2);
      }
      sm.k.tpart[ks][c2]       = a0;
      sm.k.tpart[ks][256 + c2] = a1;
    }
    __syncthreads();
    if (tid < 512) {
      float v = sm.k.tpart[0][tid] + sm.k.tpart[1][tid]
              + sm.k.tpart[2][tid] + sm.k.tpart[3][tid];
      tmapv_k[b*512 + tid] = v + t2mb[tid];
    }
    return;
  }

  if (blockIdx.x < 128) {
    // =============== u(t+1) = [tmp1n | c(t)] @ W2(bf16) + W2b ==============
    if (!do_u) return;
    const int x = (int)blockIdx.x - 64;
    const int r0 = (x >> 3) * 8, nc0 = (x & 7) * 64;
    // stage tmp1n (plain; ready from previous dispatch)
    {
      int r = tid >> 7, k4 = (tid & 127) << 2;
      *(float4*)&sm.uu.As[r][k4] = *(const float4*)&tmp1n[(size_t)(r0+r)*512 + k4];
    }
    // wait for kcattn(t) of rows r0..r0+7 (only spinners in the dispatch)
    if (tid == 0) {
      for (;;) {
        uint4 f0 = cload16w(flags2 + r0);
        uint4 f1 = cload16w(flags2 + r0 + 4);
        if ((int)f0.x > t && (int)f0.y > t && (int)f0.z > t && (int)f0.w > t &&
            (int)f1.x > t && (int)f1.y > t && (int)f1.z > t && (int)f1.w > t) break;
      }
    }
    __syncthreads();
    // coherent load of c(t) rows
    {
      int r = tid >> 7, c4 = (tid & 127) << 2;
      union { uint4 u4; float4 f4; } v;
      v.u4 = cload16nw(&cprev[(size_t)(r0+r)*512 + c4]);
      asm volatile("s_waitcnt vmcnt(0)" ::: "memory");
      *(float4*)&sm.uu.As[r][512 + c4] = v.f4;
    }
    __syncthreads();
    const int k0 = wave * 64;
    const unsigned short* Bp = w2bp + (size_t)k0*512 + nc0 + lane;
    float acc[8] = {0,0,0,0,0,0,0,0};
#pragma unroll 4
    for (int kk = 0; kk < 64; ++kk) {
      float bv = bl(Bp[(size_t)kk*512]);
#pragma unroll
      for (int r = 0; r < 8; ++r) acc[r] += sm.uu.As[r][k0+kk] * bv;
    }
#pragma unroll
    for (int r = 0; r < 8; ++r) sm.uu.part[wave][r][lane] = acc[r];
    __syncthreads();
    if (tid < 512) {
      int r = tid >> 6, c = tid & 63;
      float s2 = 0.f;
#pragma unroll
      for (int w2 = 0; w2 < 16; ++w2) s2 += sm.uu.part[w2][r][c];
      ubuf[(size_t)(r0 + r)*512 + nc0 + c] = s2 + W2b[nc0 + c];
    }
    return;
  }

  if (blockIdx.x < 448) {
    // ===================== modules(t-1): 320 blocks ========================
    if (!do_mod) return;
    const int mb = (int)blockIdx.x - 128;
    const int b = mb & 63, pb = mb >> 6;        // pb in 0..4
    if (tid < 512) sm.m.sT[tid] = tmapv_m[b*512 + tid];
    if (tid >= 512 && tid < 520) sm.m.pv[tid-512] = pvecIn[b*8 + (tid-512)];
    if (tid >= 576 && tid < 585) sm.m.wm[tid-576] = wm_m[b*9 + (tid-576)];
    __syncthreads();
    if (tid < 8) {
      int l = tid;
      sm.m.pd[l] = (l < 7 ? sm.m.pv[l+1] : 0.f) + (l == 0 ? sm.m.pv[0] : 0.f);
    }
    __syncthreads();
    if (pb == 0 && tid < 8) {
      int l = tid;
      float WP = sm.m.wm[0]+sm.m.wm[1]+sm.m.wm[2]+sm.m.wm[3] + sm.m.wm[6] + sm.m.wm[8];
      float WD = sm.m.wm[4]+sm.m.wm[5] + sm.m.wm[7];
      pvecOut[b*8+l] = WP*sm.m.pv[l] + WD*sm.m.pd[l];
    }

    float W[8][6];
#pragma unroll
    for (int m = 0; m < 8; ++m)
#pragma unroll
      for (int i = 0; i < 6; ++i) W[m][i] = swb[m*6+i];
    float W03 = sm.m.wm[0]+sm.m.wm[1]+sm.m.wm[2]+sm.m.wm[3];
    float W45 = sm.m.wm[4]+sm.m.wm[5];

    float acc6[8], acc7[8];
#pragma unroll
    for (int i = 0; i < 8; ++i) { acc6[i] = 0.f; acc7[i] = 0.f; }

    for (int pi = 0; pi < 2; ++pi) {
      int p = pb*32 + wave*2 + pi;
      if (p < 150) {
        const float* st = stack + ((size_t)b*150 + p)*8;
        float a = 0.f, av2 = 0.f;
#pragma unroll
        for (int l = 0; l < 8; ++l) { float v = st[l]; a += v*sm.m.pv[l]; av2 += v*sm.m.pd[l]; }
        float part[6] = {0,0,0,0,0,0};
#pragma unroll 2
        for (int i = 0; i < 8; ++i) {
          int d = i*64 + lane;
          float x = bl(imapB[((size_t)b*150 + p)*512 + d]);
          float t2 = sm.m.sT[d];
#pragma unroll
          for (int m = 0; m < 4; ++m) {
            float c1 = W[m][0]*t2 + W[m][1] + W[m][4] + (W[m][2] + W[m][3]*t2)*a;
            float c0 = W[m][1]*t2 + W[m][5]*t2*a;
            part[m] += elu_(c1*x + c0) * c3w[m*512+d];
          }
#pragma unroll
          for (int m = 0; m < 2; ++m) {
            float c1 = W[4+m][0]*t2 + W[4+m][1] + W[4+m][2]*a + W[4+m][3]*av2
                     + W[4+m][4]*a*av2 + W[4+m][5]*t2*(a+av2);
            part[4+m] += elu_(c1*x + W[4+m][1]*t2) * c4w[m*512+d];
          }
          float c16 = W[6][0]*t2 + W[6][1] + W[6][4] + (W[6][2] + W[6][3]*t2)*a;
          float c06 = W[6][1]*t2 + W[6][5]*t2*a;
          acc6[i] += elu_(c16*x + c06);
          float c17 = W[7][0]*t2 + W[7][1] + W[7][2]*a + W[7][3]*av2
                    + W[7][4]*a*av2 + W[7][5]*t2*(a+av2);
          acc7[i] += elu_(c17*x + W[7][1]*t2);
        }
#pragma unroll
        for (int m = 0; m < 6; ++m) {
#pragma unroll
          for (int off = 32; off; off >>= 1) part[m] += __shfl_down(part[m], off);
          part[m] = __shfl(part[m], 0);
        }
        float r3  = sm.m.wm[0]*(part[0]+c3b[0]) + sm.m.wm[1]*(part[1]+c3b[1])
                  + sm.m.wm[2]*(part[2]+c3b[2]) + sm.m.wm[3]*(part[3]+c3b[3]);
        float r45 = sm.m.wm[4]*(part[4]+c4b[0]) + sm.m.wm[5]*(part[5]+c4b[1]);
        if (lane < 8) {
          int l = lane;
          size_t idx = ((size_t)b*150 + p)*8 + l;
          stack[idx] = stack[idx]*(1.f - W03*sm.m.pv[l] - W45*sm.m.pd[l])
                     + sm.m.pv[l]*r3 + sm.m.pd[l]*r45;
        }
      }
    }
#pragma unroll
    for (int i = 0; i < 8; ++i) {
      sm.m.wpart[wave][0][i*64+lane] = acc6[i];
      sm.m.wpart[wave][1][i*64+lane] = acc7[i];
    }
    __syncthreads();
    {
      int which = tid >> 9, d = tid & 511;
      float s = 0.f;
#pragma unroll
      for (int w2 = 0; w2 < 16; ++w2) s += sm.m.wpart[w2][which][d];
      atomicAdd(&plt[(size_t)which*32768 + b*512 + d], s * (1.f/150.f));
    }
    return;
  }

  // ===================== ansall(t-2): 64 blocks, 2 z-passes ================
  {
    const int tz = t - 2;
    if (tz < 0 || tz > 7) return;
    const int bx2 = (int)blockIdx.x - 448;    // 0..63
    const int r0 = (bx2 >> 3)*8, nc0 = (bx2 & 7)*64;
#pragma unroll
    for (int zz = 0; zz < 2; ++zz) {
      const int z = tz*2 + zz;
      for (int e4 = tid; e4 < 2048; e4 += 1024) {
        int r = e4 >> 8, k4 = (e4 & 255) << 2;
        float4 v = (k4 < 512)
            ? *(const float4*)&plt_a[(size_t)z*32768 + (size_t)(r0+r)*512 + k4]
            : *(const float4*)&tmapv_a[(size_t)tz*32768 + (size_t)(r0+r)*512 + (k4-512)];
        *(float4*)&sm.a.As[r][k4] = v;
      }
      __syncthreads();
      {
        const unsigned short* Bp = answp + (size_t)zz*524288
                                 + (size_t)(wave*64)*512 + nc0 + lane;
        float acc[8] = {0,0,0,0,0,0,0,0};
        int k0 = wave*64;
#pragma unroll 4
        for (int kk = 0; kk < 64; ++kk) {
          float bv = bl(Bp[(size_t)kk*512]);
#pragma unroll
          for (int r = 0; r < 8; ++r) acc[r] += sm.a.As[r][k0+kk]*bv;
        }
#pragma unroll
        for (int r = 0; r < 8; ++r) sm.a.part[wave][r][lane] = acc[r];
      }
      __syncthreads();
      if (tid < 512) {
        int r = tid >> 6, c = tid & 63;
        float s = 0.f;
#pragma unroll
        for (int w2 = 0; w2 < 16; ++w2) s += sm.a.part[w2][r][c];
        m67o_a[(size_t)z*32768 + (size_t)(r0+r)*512 + nc0 + c] = s + ansb[zz*512 + nc0 + c];
      }
      __syncthreads();
    }
  }
}

// ---------------------------------------------------------------------------
// batched m67 GEMMs: grid (8 colchunks, 8 rowchunks, NZ), z += zbase
// ---------------------------------------------------------------------------
__global__ __launch_bounds__(512)
void ansall_k(const float* __restrict__ plt, const float* __restrict__ tmapv,
              const unsigned short* __restrict__ answp, const float* __restrict__ ansb,
              float* __restrict__ m67o, int zbase)
{
  const int z = blockIdx.z + zbase;
  const int t = z >> 1, zz = z & 1;
  __shared__ __align__(16) float As[8][1024];
  __shared__ float part[8][8][64];
  const int tid = threadIdx.x;
  const int r0 = blockIdx.y*8;
  const int nc0 = blockIdx.x*64;
  const int lane = tid & 63, w = tid >> 6;

  for (int e4 = tid; e4 < 1024; e4 += 512) {
    int r = e4 >> 7, k4 = (e4 & 127) << 2;
    *(float4*)&As[r][k4]     = *(const float4*)&plt[(size_t)z*32768 + (size_t)(r0+r)*512 + k4];
    *(float4*)&As[r][512+k4] = *(const float4*)&tmapv[(size_t)t*32768 + (size_t)(r0+r)*512 + k4];
  }
  __syncthreads();
  {
    const unsigned short* Bp = answp + (size_t)zz*524288
                             + (size_t)(w*128)*512 + nc0 + lane;
    float acc[8] = {0,0,0,0,0,0,0,0};
    int k0 = w*128;
#pragma unroll 8
    for (int kk = 0; kk < 128; ++kk) {
      float bv = bl(Bp[(size_t)kk*512]);
#pragma unroll
      for (int r = 0; r < 8; ++r) acc[r] += As[r][k0+kk]*bv;
    }
#pragma unroll
    for (int r = 0; r < 8; ++r) part[w][r][lane] = acc[r];
  }
  __syncthreads();
  {
    int r = tid >> 6, c = tid & 63;
    float s = 0.f;
#pragma unroll
    for (int w2 = 0; w2 < 8; ++w2) s += part[w2][r][c];
    m67o[(size_t)z*32768 + (size_t)(r0+r)*512 + nc0 + c] = s + ansb[zz*512 + nc0 + c];
  }
}

// ---------------------------------------------------------------------------
// final mem + (block 0) imp-loss reduction
// ---------------------------------------------------------------------------
__global__ __launch_bounds__(512)
void memfin_k(const float* __restrict__ woutAll, const float* __restrict__ m67t,
              float* __restrict__ memb, const float* __restrict__ impp,
              float* __restrict__ impout)
{
  int b = blockIdx.x;
  int tid = threadIdx.x;
  __shared__ float w6s[9], w7s[9], coef[9];
  __shared__ float red[8];
  if (tid < 9)       w6s[tid] = woutAll[tid*576 + b*9 + 6];
  else if (tid < 18) w7s[tid-9] = woutAll[(tid-9)*576 + b*9 + 7];
  __syncthreads();
  if (tid == 0) {
    float c = 1.f;
    for (int t = 8; t >= 0; --t) { coef[t] = c; c *= (1.f - w6s[t] - w7s[t]); }
  }
  __syncthreads();
  float acc = 0.f;
#pragma unroll
  for (int t = 0; t < 9; ++t) {
    float m6 = m67t[(((size_t)t*2 + 0)*64 + b)*512 + tid];
    float m7 = m67t[(((size_t)t*2 + 1)*64 + b)*512 + tid];
    acc += coef[t]*(w6s[t]*m6 + w7s[t]*m7);
  }
  memb[b*512 + tid] = acc;
  if (b == 0) {
    __syncthreads();
    int lane = tid & 63, wave = tid >> 6;
    float a2 = 0.f;
    for (int i = tid; i < 576; i += 512) a2 += impp[i];
#pragma unroll
    for (int off = 32; off; off >>= 1) a2 += __shfl_down(a2, off);
    if (lane == 0) red[wave] = a2;
    __syncthreads();
    if (tid == 0) {
      float s = 0.f;
      for (int w2 = 0; w2 < 8; ++w2) s += red[w2];
      impout[0] = s;
    }
  }
}

// ---------------------------------------------------------------------------
extern "C" void kernel_launch(void* const* d_in, const int* in_sizes, int n_in,
                              void* d_out, int out_size, void* d_ws, size_t ws_size,
                              hipStream_t stream)
{
  (void)in_sizes; (void)n_in; (void)out_size; (void)ws_size;
  const float* image = (const float*)d_in[0];
  const int*   ques  = (const int*)d_in[1];
  const int*   qlen  = (const int*)d_in[2];
  const float* embedW= (const float*)d_in[3];
  const float* Wi_f  = (const float*)d_in[4];
  const float* Wh_f  = (const float*)d_in[5];
  const float* b_f   = (const float*)d_in[6];
  const float* Wi_b  = (const float*)d_in[7];
  const float* Wh_b  = (const float*)d_in[8];
  const float* b_b   = (const float*)d_in[9];
  const float* W1    = (const float*)d_in[10];
  const float* b1    = (const float*)d_in[11];
  const float* W2w   = (const float*)d_in[12];
  const float* W2b   = (const float*)d_in[13];
  const float* W3    = (const float*)d_in[14];
  const float* c0    = (const float*)d_in[15];
  const float* Wmod  = (const float*)d_in[16];
  const float* ic1w  = (const float*)d_in[17];
  const float* ic1b  = (const float*)d_in[18];
  const float* ic2w  = (const float*)d_in[19];
  const float* ic2b  = (const float*)d_in[20];
  const float* i2mw  = (const float*)d_in[21];
  const float* i2mb  = (const float*)d_in[22];
  const float* t2mw  = (const float*)d_in[23];
  const float* t2mb  = (const float*)d_in[24];
  const float* c3ow  = (const float*)d_in[25];
  const float* c3cw  = (const float*)d_in[26];
  const float* c3cb  = (const float*)d_in[27];
  const float* c4ow  = (const float*)d_in[28];
  const float* c4cw  = (const float*)d_in[29];
  const float* c4cb  = (const float*)d_in[30];
  const float* aow   = (const float*)d_in[31];
  const float* ansW  = (const float*)d_in[32];
  const float* ansb  = (const float*)d_in[33];
  const float* o1w   = (const float*)d_in[34];
  const float* o1b   = (const float*)d_in[35];
  const float* o2w   = (const float*)d_in[36];
  const float* o2b   = (const float*)d_in[37];
  float* out = (float*)d_out;
  float* ws  = (float*)d_ws;

  size_t off = 0;
  auto alloc = [&](size_t n){ float* p = ws + off; off += n; return p; };
  short* imgP  = (short*)alloc(600ull*20*64*8/2);
  short* X1p   = (short*)alloc(600ull*16*64*8/2);
  short* X2p   = (short*)alloc(600ull*16*64*8/2);
  short* w1p   = (short*)alloc(20*32*64*8/2);
  short* w2mp  = (short*)alloc(16*32*64*8/2);
  short* w3mp  = (short*)alloc(16*32*64*8/2);
  short* wifp  = (short*)alloc(10*64*64*8/2);
  short* wibp  = (short*)alloc(10*64*64*8/2);
  short* embp  = (short*)alloc(120ull*10*64*8/2);
  unsigned short* imapB = (unsigned short*)alloc(9600ull*512/2);
  unsigned* t2pp = (unsigned*)alloc(512*256);
  unsigned short* w2bp  = (unsigned short*)alloc(524288/2);
  unsigned short* answp = (unsigned short*)alloc(1048576/2);
  float* xWfb  = alloc(64ull*30*1024);
  float* xWbb  = alloc(64ull*30*1024);
  float* lout  = alloc(64ull*30*512);
  float* qbuf  = alloc(64*512);
  float* stck  = alloc(64*150*8);
  float* pvecA = alloc(64*8);
  float* pvecB = alloc(64*8);
  float* memb  = alloc(64*512);
  float* cprev = alloc(64*512);
  float* tmp1a = alloc(9ull*64*512);
  float* ubuf  = alloc(64*512);
  float* wmwA  = alloc(9*64*9);
  float* impp  = alloc(9*64);
  float* swb   = alloc(48);
  float* pl    = alloc(9ull*2*64*512);
  float* m67t  = alloc(9ull*2*64*512);
  float* tmapv = alloc(9ull*64*512);
  float* h1b   = alloc(64*1024);
  unsigned* whT = (unsigned*)alloc(2ull*1024*128);       // f16-pair packed Wh^T
  float* hbufW  = alloc(32768);                          // 2 ping x 2 d x 4 g x 16 x 256 f16
  int*   flagsI = (int*)alloc(256);                      // sync flags (lstm:0-31, step:64-127)
  int*   flags2 = flagsI + 64;

  // one dispatch: init + ALL independent packs (incl. f16 WhT, bf16 W2/ansW)
  megapack_k<<<12036, 256, 0, stream>>>(
      c0, c3ow, c4ow, aow, stck, pvecA, memb, cprev, swb, pl,
      Wh_f, Wh_b, whT, hbufW, flagsI,
      ic1w, w1p, ic2w, w2mp, i2mw, w3mp, Wi_f, wifp, Wi_b, wibp,
      image, imgP, embedW, ques, embp, t2mw, t2pp,
      W2w, w2bp, ansW, answp);

  // both embed GEMMs first (LSTM depends on xW)
  gemmM_k<<<dim3(16,30,2), 256, 0, stream>>>(embp, embp, wifp, wibp, b_f, b_b,
                                             xWfb, xWbb, 10, 64, 1024, 0, 0, 0);

  // MERGED: LSTM (32 blocks) + conv1 (1200 blocks)
  lstmc1_k<<<1232, 256, 0, stream>>>(xWfb, xWbb, whT, qlen,
                                     (unsigned long long*)hbufW, flagsI,
                                     lout, qbuf,
                                     imgP, w1p, ic1b, X1p);

  // conv2, conv3 (depend on conv1)
  gemmM_k<<<dim3(8,150,1), 256, 0, stream>>>(X1p, X1p, w2mp, w2mp, ic2b, ic2b,
                                             X2p, X2p, 16, 32, 512, 1, 0, 16);
  gemmM_k<<<dim3(8,150,1), 256, 0, stream>>>(X2p, X2p, w3mp, w3mp, i2mb, i2mb,
                                             imapB, imapB, 16, 32, 512, 2, 0, 0);

  // tmp1all[t] = q @ W1[t] + b1 (all 9 t)
  gemm64b_k<<<dim3(8,8,9), 512, 0, stream>>>(
      qbuf, 0, 9, (const float*)nullptr, 0,
      W1, 262144, b1, 0, tmp1a, 32768, 512, 0);
  // u for t=0 (fp32 W2)
  gemm64b_k<<<dim3(8,8,1), 512, 0, stream>>>(
      tmp1a, 0, 9, cprev, 512, W2w, 0, W2b, 0, ubuf, 0, 512, 0);

  // t-loop: D(t) = kcattn(t) + u(t+1) + modules(t-1) + ansall(t-2)
  for (int t = 0; t <= 9; ++t) {
    int tm = t - 1;
    int tmc = (tm < 0) ? 0 : tm;
    float* pvIn  = (tmc & 1) ? pvecB : pvecA;
    float* pvOut = (tmc & 1) ? pvecA : pvecB;
    step_k<<<512, 1024, 0, stream>>>(
        ubuf, Wmod, lout, W3, t2pp, t2mb, wmwA, impp,
        cprev, tmapv + (size_t)(t < 9 ? t : 0)*32768, t,
        tmp1a + (size_t)(t < 8 ? t+1 : 0)*32768, w2bp, W2b, ubuf,
        flags2, (t < 8) ? 1 : 0,
        imapB, tmapv + (size_t)tmc*32768, stck, pvIn, pvOut, swb,
        c3cw, c3cb, c4cw, c4cb,
        wmwA + (size_t)tmc*576, pl + (size_t)tmc*65536,
        (t > 0) ? 1 : 0,
        pl, tmapv, answp, ansb, m67t);
  }

  // remaining m67 slices (t=8 -> z=16,17)
  ansall_k<<<dim3(8,8,2), 512, 0, stream>>>(pl, tmapv, answp, ansb, m67t, 16);

  // final mem blend (+imp), then h1 = elu([q,mem]@out1+b); logits = h1@out2+b
  memfin_k<<<64, 512, 0, stream>>>(wmwA, m67t, memb, impp, out + 2048);
  gemm64b_k<<<dim3(16,8,1), 512, 0, stream>>>(
      qbuf, 0, 9, memb, 512, o1w, 0, o1b, 0, h1b, 0, 1024, 1);
  gemm64b_k<<<dim3(1,8,1), 512, 0, stream>>>(
      h1b, 0, 10, (const float*)nullptr, 0, o2w, 0, o2b, 0, out, 0, 32, 0);
}